// Round 8
// baseline (660.326 us; speedup 1.0000x reference)
//
#include <hip/hip_runtime.h>
#include <hip/hip_bf16.h>
#include <math.h>

// Problem constants: N=100000, E=600000, D=128, H=4, F=32, L=3

__device__ __forceinline__ float leaky02(float x) {
    return x >= 0.f ? x : 0.2f * x;
}

// ---------------------------------------------------------------------------
// CSR build
__global__ __launch_bounds__(256) void deg_init_kernel(int* __restrict__ deg, int N)
{
    int i = blockIdx.x * 256 + threadIdx.x;
    if (i < N) deg[i] = 1;  // self loop
}

__global__ __launch_bounds__(256) void deg_count_kernel(
    const int* __restrict__ dst, int* __restrict__ deg, int E)
{
    int i = blockIdx.x * 256 + threadIdx.x;
    if (i < E) atomicAdd(&deg[dst[i]], 1);
}

#define SCAN_TILE 1024

__global__ __launch_bounds__(256) void scanA_kernel(
    const int* __restrict__ deg, int* __restrict__ bsum, int N)
{
    __shared__ int ws[4];
    int b = blockIdx.x, t = threadIdx.x;
    int base = b * SCAN_TILE + t * 4;
    int s = 0;
#pragma unroll
    for (int k = 0; k < 4; ++k) {
        int i = base + k;
        if (i < N) s += deg[i];
    }
#pragma unroll
    for (int m = 32; m >= 1; m >>= 1) s += __shfl_xor(s, m, 64);
    if ((t & 63) == 0) ws[t >> 6] = s;
    __syncthreads();
    if (t == 0) bsum[b] = ws[0] + ws[1] + ws[2] + ws[3];
}

__global__ __launch_bounds__(1024) void scanB_kernel(
    int* __restrict__ bsum, int* __restrict__ bpre, int* __restrict__ rowp,
    int NB, int N)
{
    __shared__ int sh[1024];
    int t = threadIdx.x;
    int v = (t < NB) ? bsum[t] : 0;
    sh[t] = v;
    __syncthreads();
    for (int off = 1; off < 1024; off <<= 1) {
        int u = (t >= off) ? sh[t - off] : 0;
        __syncthreads();
        sh[t] += u;
        __syncthreads();
    }
    if (t < NB) bpre[t] = sh[t] - v;          // exclusive prefix
    if (t == 1023) rowp[N] = sh[1023];        // total
}

__global__ __launch_bounds__(256) void scanC_kernel(
    const int* __restrict__ deg, const int* __restrict__ bpre,
    int* __restrict__ rowp, int* __restrict__ cur, int N)
{
    __shared__ int sh[256];
    int b = blockIdx.x, t = threadIdx.x;
    int base = b * SCAN_TILE + t * 4;
    int v[4];
#pragma unroll
    for (int k = 0; k < 4; ++k) {
        int i = base + k;
        v[k] = (i < N) ? deg[i] : 0;
    }
    int tsum = v[0] + v[1] + v[2] + v[3];
    sh[t] = tsum;
    __syncthreads();
    for (int off = 1; off < 256; off <<= 1) {
        int u = (t >= off) ? sh[t - off] : 0;
        __syncthreads();
        sh[t] += u;
        __syncthreads();
    }
    int pre = bpre[b] + sh[t] - tsum;
#pragma unroll
    for (int k = 0; k < 4; ++k) {
        int i = base + k;
        if (i < N) { rowp[i] = pre; cur[i] = pre; }
        pre += v[k];
    }
}

__global__ __launch_bounds__(256) void scatter_kernel(
    const int* __restrict__ src, const int* __restrict__ dst,
    int* __restrict__ cur, int* __restrict__ col, int E, int N)
{
    int i = blockIdx.x * 256 + threadIdx.x;
    if (i < E) {
        int p = atomicAdd(&cur[dst[i]], 1);
        col[p] = src[i];
    } else if (i < E + N) {
        int v = i - E;
        int p = atomicAdd(&cur[v], 1);
        col[p] = v;  // self loop
    }
}

// ---------------------------------------------------------------------------
// Layer-0 rank-1 precompute
__global__ __launch_bounds__(128) void rank1_prep_kernel(
    const float* __restrict__ lW, const float* __restrict__ lb,
    const float* __restrict__ W0, const float* __restrict__ al,
    const float* __restrict__ ar, float* __restrict__ c1,
    float* __restrict__ c2, float* __restrict__ prm)
{
    int j = threadIdx.x;
    float s1 = 0.f, s2 = 0.f;
    for (int d = 0; d < 128; ++d) {
        float wv = W0[j * 128 + d];
        s1 += lW[d] * wv;
        s2 += lb[d] * wv;
    }
    c1[j] = s1; c2[j] = s2;
    __shared__ float sh1[128], sh2[128], sh3[128], sh4[128];
    sh1[j] = s1 * al[j]; sh2[j] = s2 * al[j];
    sh3[j] = s1 * ar[j]; sh4[j] = s2 * ar[j];
    __syncthreads();
    if (j < 4) {
        float p = 0.f, q = 0.f, r = 0.f, s = 0.f;
        for (int f = 0; f < 32; ++f) {
            p += sh1[j * 32 + f]; q += sh2[j * 32 + f];
            r += sh3[j * 32 + f]; s += sh4[j * 32 + f];
        }
        prm[j] = p; prm[4 + j] = q; prm[8 + j] = r; prm[12 + j] = s;
    }
}

// h0[n,j] = w[n]*c1[j] + c2[j]; el0[n,h] = w[n]*pl[h]+ql[h]; er0 likewise.
__global__ __launch_bounds__(256) void rank1_apply_kernel(
    const float* __restrict__ w, const float* __restrict__ c1,
    const float* __restrict__ c2, const float* __restrict__ prm,
    float* __restrict__ h, float* __restrict__ el, float* __restrict__ er, int N)
{
    int i = blockIdx.x * 256 + threadIdx.x;
    int n = i >> 5, k = i & 31;
    if (n >= N) return;
    float wn = w[n];
    float4 a = *reinterpret_cast<const float4*>(&c1[k * 4]);
    float4 b = *reinterpret_cast<const float4*>(&c2[k * 4]);
    float4 o = make_float4(wn * a.x + b.x, wn * a.y + b.y,
                           wn * a.z + b.z, wn * a.w + b.w);
    *reinterpret_cast<float4*>(&h[(size_t)n * 128 + k * 4]) = o;
    if (k == 0) {
        float4 pl = *reinterpret_cast<const float4*>(&prm[0]);
        float4 ql = *reinterpret_cast<const float4*>(&prm[4]);
        float4 pr = *reinterpret_cast<const float4*>(&prm[8]);
        float4 qr = *reinterpret_cast<const float4*>(&prm[12]);
        float4 e1 = make_float4(wn * pl.x + ql.x, wn * pl.y + ql.y,
                                wn * pl.z + ql.z, wn * pl.w + ql.w);
        float4 e2 = make_float4(wn * pr.x + qr.x, wn * pr.y + qr.y,
                                wn * pr.z + qr.z, wn * pr.w + qr.w);
        *reinterpret_cast<float4*>(&el[(size_t)n * 4]) = e1;
        *reinterpret_cast<float4*>(&er[(size_t)n * 4]) = e2;
    }
}

// ---------------------------------------------------------------------------
// GEMM + fused el/er (layers 1,2): h[n,j] = sum_d leaky0.01(x[n,d])*W[j,d]
// 64x128 tile, BK=32, 256 threads. All LDS ops are 16B-aligned b128 with
// even bank distribution (8 dwords/bank = b128 hardware minimum):
//  - xs [64 rows][32 d] row-major unpadded: writes bank-even, reads broadcast.
//  - wsh [128 cols][32 d] XOR-swizzled: W[j][4*d4..+3] lives at column unit
//    (d4 ^ (j&7)). Writes bank-even; reads bank-even because each thread's
//    4 cols are STRIDED (tx, tx+32, tx+64, tx+96) so col&7 = tx&7 spans 0..7
//    across the wave.
// Thread (tx=tid&31, ty=tid>>5): rows ty*8..+7, cols {tx+32c}. Since cols are
// strided by 32, col c IS head c -> el/er reduce over the 32 tx lanes.
__global__ __launch_bounds__(256) void gemm_fused_kernel(
    const float* __restrict__ x, const float* __restrict__ W,
    const float* __restrict__ al, const float* __restrict__ ar,
    float* __restrict__ h, float* __restrict__ el, float* __restrict__ er,
    int N)
{
    __shared__ float xs[64 * 32];    // 8 KB
    __shared__ float wsh[128 * 32];  // 16 KB
    const int tid = threadIdx.x;
    const int t8 = tid & 7;          // staging: d4 unit (col offset t8*4)
    const int lr = tid >> 3;         // staging row 0..31
    const int lr7 = lr & 7;
    const int tx = tid & 31;
    const int ty = tid >> 5;
    const int m0 = blockIdx.x * 64;
    const int swz = tx & 7;

    float acc[8][4];
#pragma unroll
    for (int r = 0; r < 8; ++r)
#pragma unroll
        for (int c = 0; c < 4; ++c) acc[r][c] = 0.f;

    for (int k0 = 0; k0 < 128; k0 += 32) {
        // stage x tile (64 rows x 32 d), leaky(0.01), row-major
#pragma unroll
        for (int p = 0; p < 2; ++p) {
            int row = m0 + lr + p * 32;
            float4 v = make_float4(0.f, 0.f, 0.f, 0.f);
            if (row < N) v = *reinterpret_cast<const float4*>(&x[(size_t)row * 128 + k0 + t8 * 4]);
            v.x = v.x >= 0.f ? v.x : 0.01f * v.x;
            v.y = v.y >= 0.f ? v.y : 0.01f * v.y;
            v.z = v.z >= 0.f ? v.z : 0.01f * v.z;
            v.w = v.w >= 0.f ? v.w : 0.01f * v.w;
            *reinterpret_cast<float4*>(&xs[(lr + p * 32) * 32 + t8 * 4]) = v;
        }
        // stage W tile (128 cols x 32 d), xor-swizzled
#pragma unroll
        for (int p = 0; p < 4; ++p) {
            int j = lr + p * 32;
            float4 v = *reinterpret_cast<const float4*>(&W[(size_t)j * 128 + k0 + t8 * 4]);
            *reinterpret_cast<float4*>(&wsh[j * 32 + 4 * (t8 ^ lr7)]) = v;
        }
        __syncthreads();

#pragma unroll
        for (int d4 = 0; d4 < 8; ++d4) {
            float4 b[4];
#pragma unroll
            for (int c = 0; c < 4; ++c) {
                int colj = tx + 32 * c;
                b[c] = *reinterpret_cast<const float4*>(&wsh[colj * 32 + 4 * (d4 ^ swz)]);
            }
#pragma unroll
            for (int r = 0; r < 8; ++r) {
                const float4 a = *reinterpret_cast<const float4*>(&xs[(ty * 8 + r) * 32 + d4 * 4]);
#pragma unroll
                for (int c = 0; c < 4; ++c) {
                    acc[r][c] += a.x * b[c].x + a.y * b[c].y
                               + a.z * b[c].z + a.w * b[c].w;
                }
            }
        }
        __syncthreads();
    }

    // epilogue: store h + fused el/er (col c == head c, feature index tx)
    const float al0 = al[tx], al1 = al[32 + tx], al2 = al[64 + tx], al3 = al[96 + tx];
    const float ar0 = ar[tx], ar1 = ar[32 + tx], ar2 = ar[64 + tx], ar3 = ar[96 + tx];
#pragma unroll
    for (int r = 0; r < 8; ++r) {
        int row = m0 + ty * 8 + r;
        bool ok = row < N;
        if (ok) {
            h[(size_t)row * 128 + tx]      = acc[r][0];
            h[(size_t)row * 128 + 32 + tx] = acc[r][1];
            h[(size_t)row * 128 + 64 + tx] = acc[r][2];
            h[(size_t)row * 128 + 96 + tx] = acc[r][3];
        }
        float e0 = acc[r][0] * al0, e1 = acc[r][1] * al1;
        float e2 = acc[r][2] * al2, e3 = acc[r][3] * al3;
        float f0 = acc[r][0] * ar0, f1 = acc[r][1] * ar1;
        float f2 = acc[r][2] * ar2, f3 = acc[r][3] * ar3;
#pragma unroll
        for (int d = 1; d <= 16; d <<= 1) {
            e0 += __shfl_xor(e0, d, 64); e1 += __shfl_xor(e1, d, 64);
            e2 += __shfl_xor(e2, d, 64); e3 += __shfl_xor(e3, d, 64);
            f0 += __shfl_xor(f0, d, 64); f1 += __shfl_xor(f1, d, 64);
            f2 += __shfl_xor(f2, d, 64); f3 += __shfl_xor(f3, d, 64);
        }
        if (ok && tx == 0) {
            el[(size_t)row * 4 + 0] = e0; el[(size_t)row * 4 + 1] = e1;
            el[(size_t)row * 4 + 2] = e2; el[(size_t)row * 4 + 3] = e3;
            er[(size_t)row * 4 + 0] = f0; er[(size_t)row * 4 + 1] = f1;
            er[(size_t)row * 4 + 2] = f2; er[(size_t)row * 4 + 3] = f3;
        }
    }
}

// ---------------------------------------------------------------------------
// Fused softmax-stats + gather + (optional) prediction epilogue.
// One wave per node (head-quartered Phase A, direct-load Phase B).
__global__ __launch_bounds__(256) void agg_fused_kernel(
    const float* __restrict__ h, const float* __restrict__ el,
    const float* __restrict__ er, const int* __restrict__ rowp,
    const int* __restrict__ col, const float* __restrict__ bias,
    float* __restrict__ xout, const float* __restrict__ pW,
    const float* __restrict__ pb, float* __restrict__ logits,
    int N, int last)
{
    int v = blockIdx.x * 4 + (threadIdx.x >> 6);
    int lane = threadIdx.x & 63;
    if (v >= N) return;
    const int r0 = rowp[v], r1 = rowp[v + 1];
    const int deg = r1 - r0;

    // ---- Phase A: per-head online softmax stats
    const int qh  = lane >> 4;
    const int j16 = lane & 15;
    const float erq = er[(size_t)v * 4 + qh];

    float m_l = -INFINITY, s_l = 0.f;
    for (int jj = j16; jj < deg; jj += 16) {
        int u = col[r0 + jj];
        float e = leaky02(el[(size_t)u * 4 + qh] + erq);
        if (e > m_l) { s_l = s_l * __expf(m_l - e) + 1.f; m_l = e; }
        else         { s_l += __expf(e - m_l); }
    }
#pragma unroll
    for (int d = 1; d <= 8; d <<= 1) {
        float m2 = __shfl_xor(m_l, d, 64);
        float s2 = __shfl_xor(s_l, d, 64);
        float nm = fmaxf(m_l, m2);
        s_l = (s_l > 0.f ? s_l * __expf(m_l - nm) : 0.f)
            + (s2  > 0.f ? s2  * __expf(m2  - nm) : 0.f);
        m_l = nm;
    }
    const float is_l = 1.f / s_l;

    // ---- Phase B: gather, 4 edges in flight (quarter-wave per edge)
    const int q = lane >> 4, l16 = lane & 15, f0 = l16 * 4, hA = l16 >> 3;
    const float mA  = __shfl(m_l,  hA * 16, 64);
    const float isA = __shfl(is_l, hA * 16, 64);
    const float mB  = __shfl(m_l,  (hA + 2) * 16, 64);
    const float isB = __shfl(is_l, (hA + 2) * 16, 64);
    const float erA = er[(size_t)v * 4 + hA];
    const float erB = er[(size_t)v * 4 + 2 + hA];

    float4 acc0 = make_float4(0.f, 0.f, 0.f, 0.f);
    float4 acc1 = make_float4(0.f, 0.f, 0.f, 0.f);

    for (int j = r0 + q; j < r1; j += 4) {
        int u = col[j];
        float eA = leaky02(el[(size_t)u * 4 + hA] + erA);
        float eB = leaky02(el[(size_t)u * 4 + 2 + hA] + erB);
        float aA = __expf(eA - mA) * isA;
        float aB = __expf(eB - mB) * isB;
        const float4 v0 = *reinterpret_cast<const float4*>(&h[(size_t)u * 128 + f0]);
        const float4 v1 = *reinterpret_cast<const float4*>(&h[(size_t)u * 128 + 64 + f0]);
        acc0.x += aA * v0.x; acc0.y += aA * v0.y;
        acc0.z += aA * v0.z; acc0.w += aA * v0.w;
        acc1.x += aB * v1.x; acc1.y += aB * v1.y;
        acc1.z += aB * v1.z; acc1.w += aB * v1.w;
    }

#pragma unroll
    for (int d = 16; d <= 32; d <<= 1) {
        acc0.x += __shfl_xor(acc0.x, d, 64);
        acc0.y += __shfl_xor(acc0.y, d, 64);
        acc0.z += __shfl_xor(acc0.z, d, 64);
        acc0.w += __shfl_xor(acc0.w, d, 64);
        acc1.x += __shfl_xor(acc1.x, d, 64);
        acc1.y += __shfl_xor(acc1.y, d, 64);
        acc1.z += __shfl_xor(acc1.z, d, 64);
        acc1.w += __shfl_xor(acc1.w, d, 64);
    }

    if (last) {
        float part = 0.f;
        if (lane < 16) {
            float4 b0 = *reinterpret_cast<const float4*>(&bias[f0]);
            float4 b1 = *reinterpret_cast<const float4*>(&bias[64 + f0]);
            float4 p0 = *reinterpret_cast<const float4*>(&pW[f0]);
            float4 p1 = *reinterpret_cast<const float4*>(&pW[64 + f0]);
            part = (acc0.x + b0.x) * p0.x + (acc0.y + b0.y) * p0.y
                 + (acc0.z + b0.z) * p0.z + (acc0.w + b0.w) * p0.w
                 + (acc1.x + b1.x) * p1.x + (acc1.y + b1.y) * p1.y
                 + (acc1.z + b1.z) * p1.z + (acc1.w + b1.w) * p1.w;
        }
#pragma unroll
        for (int d = 8; d >= 1; d >>= 1) part += __shfl_xor(part, d, 64);
        if (lane == 0) logits[v] = part + pb[0];
    } else {
        if (lane < 16) {
            float4 b0 = *reinterpret_cast<const float4*>(&bias[f0]);
            float4 b1 = *reinterpret_cast<const float4*>(&bias[64 + f0]);
            acc0.x += b0.x; acc0.y += b0.y; acc0.z += b0.z; acc0.w += b0.w;
            acc1.x += b1.x; acc1.y += b1.y; acc1.z += b1.z; acc1.w += b1.w;
            *reinterpret_cast<float4*>(&xout[(size_t)v * 128 + f0])      = acc0;
            *reinterpret_cast<float4*>(&xout[(size_t)v * 128 + 64 + f0]) = acc1;
        }
    }
}

// ---------------------------------------------------------------------------
extern "C" void kernel_launch(void* const* d_in, const int* in_sizes, int n_in,
                              void* d_out, int out_size, void* d_ws, size_t ws_size,
                              hipStream_t stream)
{
    const float* weights = (const float*)d_in[0];
    const float* lin_W   = (const float*)d_in[1];
    const float* lin_b   = (const float*)d_in[2];
    const float* fc_W    = (const float*)d_in[3];
    const float* attn_l  = (const float*)d_in[4];
    const float* attn_r  = (const float*)d_in[5];
    const float* conv_b  = (const float*)d_in[6];
    const float* pred_W  = (const float*)d_in[7];
    const float* pred_b  = (const float*)d_in[8];
    const int*   src     = (const int*)d_in[9];
    const int*   dst     = (const int*)d_in[10];

    const int N = in_sizes[0];
    const int E = in_sizes[9];
    const int NB = (N + SCAN_TILE - 1) / SCAN_TILE;

    // workspace layout (16B-aligned float4 sections first)
    float* x   = (float*)d_ws;                   // N*128
    float* h   = x + (size_t)N * 128;            // N*128
    float* el  = h + (size_t)N * 128;            // N*4
    float* er  = el + (size_t)N * 4;             // N*4
    float* c1  = er + (size_t)N * 4;             // 128
    float* c2  = c1 + 128;                       // 128
    float* prm = c2 + 128;                       // 16
    int*   deg  = (int*)(prm + 16);              // N
    int*   rowp = deg + N;                       // N+1
    int*   cur  = rowp + (N + 1);                // N
    int*   col  = cur + N;                       // E+N
    int*   bsum = col + (E + N);                 // NB
    int*   bpre = bsum + NB;                     // NB

    // CSR build (fresh every call: ws is re-poisoned)
    deg_init_kernel<<<(N + 255) / 256, 256, 0, stream>>>(deg, N);
    deg_count_kernel<<<(E + 255) / 256, 256, 0, stream>>>(dst, deg, E);
    scanA_kernel<<<NB, 256, 0, stream>>>(deg, bsum, N);
    scanB_kernel<<<1, 1024, 0, stream>>>(bsum, bpre, rowp, NB, N);
    scanC_kernel<<<NB, 256, 0, stream>>>(deg, bpre, rowp, cur, N);
    scatter_kernel<<<(E + N + 255) / 256, 256, 0, stream>>>(src, dst, cur, col, E, N);

    // Layer 0 via rank-1 identity
    rank1_prep_kernel<<<1, 128, 0, stream>>>(lin_W, lin_b, fc_W, attn_l, attn_r,
                                             c1, c2, prm);
    rank1_apply_kernel<<<((size_t)N * 32 + 255) / 256, 256, 0, stream>>>(
        weights, c1, c2, prm, h, el, er, N);
    agg_fused_kernel<<<(N + 3) / 4, 256, 0, stream>>>(
        h, el, er, rowp, col, conv_b, x, pred_W, pred_b, (float*)d_out, N, 0);

    // Layers 1, 2 (gemm with fused el/er epilogue)
    for (int l = 1; l < 3; ++l) {
        gemm_fused_kernel<<<(N + 63) / 64, 256, 0, stream>>>(
            x, fc_W + (size_t)l * 128 * 128,
            attn_l + l * 128, attn_r + l * 128,
            h, el, er, N);
        agg_fused_kernel<<<(N + 3) / 4, 256, 0, stream>>>(
            h, el, er, rowp, col, conv_b + l * 128, x, pred_W, pred_b,
            (float*)d_out, N, l == 2 ? 1 : 0);
    }
}

// Round 9
// 630.583 us; speedup vs baseline: 1.0472x; 1.0472x over previous
//
#include <hip/hip_runtime.h>
#include <hip/hip_bf16.h>
#include <math.h>

// Problem constants: N=100000, E=600000, D=128, H=4, F=32, L=3

__device__ __forceinline__ float leaky02(float x) {
    return x >= 0.f ? x : 0.2f * x;
}

// ---------------------------------------------------------------------------
// CSR build
__global__ __launch_bounds__(256) void deg_init_kernel(int* __restrict__ deg, int N)
{
    int i = blockIdx.x * 256 + threadIdx.x;
    if (i < N) deg[i] = 1;  // self loop
}

__global__ __launch_bounds__(256) void deg_count_kernel(
    const int* __restrict__ dst, int* __restrict__ deg, int E)
{
    int i = blockIdx.x * 256 + threadIdx.x;
    if (i < E) atomicAdd(&deg[dst[i]], 1);
}

#define SCAN_TILE 1024

__global__ __launch_bounds__(256) void scanA_kernel(
    const int* __restrict__ deg, int* __restrict__ bsum, int N)
{
    __shared__ int ws[4];
    int b = blockIdx.x, t = threadIdx.x;
    int base = b * SCAN_TILE + t * 4;
    int s = 0;
#pragma unroll
    for (int k = 0; k < 4; ++k) {
        int i = base + k;
        if (i < N) s += deg[i];
    }
#pragma unroll
    for (int m = 32; m >= 1; m >>= 1) s += __shfl_xor(s, m, 64);
    if ((t & 63) == 0) ws[t >> 6] = s;
    __syncthreads();
    if (t == 0) bsum[b] = ws[0] + ws[1] + ws[2] + ws[3];
}

__global__ __launch_bounds__(1024) void scanB_kernel(
    int* __restrict__ bsum, int* __restrict__ bpre, int* __restrict__ rowp,
    int NB, int N)
{
    __shared__ int sh[1024];
    int t = threadIdx.x;
    int v = (t < NB) ? bsum[t] : 0;
    sh[t] = v;
    __syncthreads();
    for (int off = 1; off < 1024; off <<= 1) {
        int u = (t >= off) ? sh[t - off] : 0;
        __syncthreads();
        sh[t] += u;
        __syncthreads();
    }
    if (t < NB) bpre[t] = sh[t] - v;          // exclusive prefix
    if (t == 1023) rowp[N] = sh[1023];        // total
}

__global__ __launch_bounds__(256) void scanC_kernel(
    const int* __restrict__ deg, const int* __restrict__ bpre,
    int* __restrict__ rowp, int* __restrict__ cur, int N)
{
    __shared__ int sh[256];
    int b = blockIdx.x, t = threadIdx.x;
    int base = b * SCAN_TILE + t * 4;
    int v[4];
#pragma unroll
    for (int k = 0; k < 4; ++k) {
        int i = base + k;
        v[k] = (i < N) ? deg[i] : 0;
    }
    int tsum = v[0] + v[1] + v[2] + v[3];
    sh[t] = tsum;
    __syncthreads();
    for (int off = 1; off < 256; off <<= 1) {
        int u = (t >= off) ? sh[t - off] : 0;
        __syncthreads();
        sh[t] += u;
        __syncthreads();
    }
    int pre = bpre[b] + sh[t] - tsum;
#pragma unroll
    for (int k = 0; k < 4; ++k) {
        int i = base + k;
        if (i < N) { rowp[i] = pre; cur[i] = pre; }
        pre += v[k];
    }
}

__global__ __launch_bounds__(256) void scatter_kernel(
    const int* __restrict__ src, const int* __restrict__ dst,
    int* __restrict__ cur, int* __restrict__ col, int E, int N)
{
    int i = blockIdx.x * 256 + threadIdx.x;
    if (i < E) {
        int p = atomicAdd(&cur[dst[i]], 1);
        col[p] = src[i];
    } else if (i < E + N) {
        int v = i - E;
        int p = atomicAdd(&cur[v], 1);
        col[p] = v;  // self loop
    }
}

// ---------------------------------------------------------------------------
// Layer-0 rank-1 precompute
__global__ __launch_bounds__(128) void rank1_prep_kernel(
    const float* __restrict__ lW, const float* __restrict__ lb,
    const float* __restrict__ W0, const float* __restrict__ al,
    const float* __restrict__ ar, float* __restrict__ c1,
    float* __restrict__ c2, float* __restrict__ prm)
{
    int j = threadIdx.x;
    float s1 = 0.f, s2 = 0.f;
    for (int d = 0; d < 128; ++d) {
        float wv = W0[j * 128 + d];
        s1 += lW[d] * wv;
        s2 += lb[d] * wv;
    }
    c1[j] = s1; c2[j] = s2;
    __shared__ float sh1[128], sh2[128], sh3[128], sh4[128];
    sh1[j] = s1 * al[j]; sh2[j] = s2 * al[j];
    sh3[j] = s1 * ar[j]; sh4[j] = s2 * ar[j];
    __syncthreads();
    if (j < 4) {
        float p = 0.f, q = 0.f, r = 0.f, s = 0.f;
        for (int f = 0; f < 32; ++f) {
            p += sh1[j * 32 + f]; q += sh2[j * 32 + f];
            r += sh3[j * 32 + f]; s += sh4[j * 32 + f];
        }
        prm[j] = p; prm[4 + j] = q; prm[8 + j] = r; prm[12 + j] = s;
    }
}

// h0[n,j] = w[n]*c1[j] + c2[j]; el0[n,h] = w[n]*pl[h]+ql[h]; er0 likewise.
__global__ __launch_bounds__(256) void rank1_apply_kernel(
    const float* __restrict__ w, const float* __restrict__ c1,
    const float* __restrict__ c2, const float* __restrict__ prm,
    float* __restrict__ h, float* __restrict__ el, float* __restrict__ er, int N)
{
    int i = blockIdx.x * 256 + threadIdx.x;
    int n = i >> 5, k = i & 31;
    if (n >= N) return;
    float wn = w[n];
    float4 a = *reinterpret_cast<const float4*>(&c1[k * 4]);
    float4 b = *reinterpret_cast<const float4*>(&c2[k * 4]);
    float4 o = make_float4(wn * a.x + b.x, wn * a.y + b.y,
                           wn * a.z + b.z, wn * a.w + b.w);
    *reinterpret_cast<float4*>(&h[(size_t)n * 128 + k * 4]) = o;
    if (k == 0) {
        float4 pl = *reinterpret_cast<const float4*>(&prm[0]);
        float4 ql = *reinterpret_cast<const float4*>(&prm[4]);
        float4 pr = *reinterpret_cast<const float4*>(&prm[8]);
        float4 qr = *reinterpret_cast<const float4*>(&prm[12]);
        float4 e1 = make_float4(wn * pl.x + ql.x, wn * pl.y + ql.y,
                                wn * pl.z + ql.z, wn * pl.w + ql.w);
        float4 e2 = make_float4(wn * pr.x + qr.x, wn * pr.y + qr.y,
                                wn * pr.z + qr.z, wn * pr.w + qr.w);
        *reinterpret_cast<float4*>(&el[(size_t)n * 4]) = e1;
        *reinterpret_cast<float4*>(&er[(size_t)n * 4]) = e2;
    }
}

// ---------------------------------------------------------------------------
// GEMM (layers 1,2): h[n,j] = sum_d leaky0.01(x[n,d]) * W[j,d]
// 64x128 tile, BK=32 pages, 256 threads, 4x8 register tile.
// LDS layout: float4 CHUNKS with XOR-swizzled low-3 index:
//   xs4[d4][row'], row' = (row&~7)|((row&7)^d4)   (d4 = K-chunk 0..7 in page)
//   ws4[d4][col'], col' = (col&~7)|((col&7)^d4)
// Staging writes: per wave, 8 lanes per bank-quad with distinct addresses
//   = exactly the b128 dense minimum (8 dw/bank) -> conflict-free.
// Compute reads: cols are STRIDED (tx+16c) so col&7 spans all 8 quads
//   (2 addrs/quad = free 2-way); x reads are 4-address broadcasts.
// Per d4-step/thread: 128 FMA vs 12 b128 LDS ops -> VALU-bound.
__global__ __launch_bounds__(256) void gemm_kernel(
    const float* __restrict__ x, const float* __restrict__ W,
    float* __restrict__ h, int N)
{
    __shared__ float4 xs4[8 * 64];    // 8 KB
    __shared__ float4 ws4[8 * 128];   // 16 KB
    const int tid = threadIdx.x;
    const int m0 = blockIdx.x * 64;
    const int tx = tid & 15;          // col base; cols = tx + 16c
    const int ty = tid >> 4;          // 0..15; rows = ty*4 + r

    float acc[4][8];
#pragma unroll
    for (int r = 0; r < 4; ++r)
#pragma unroll
        for (int c = 0; c < 8; ++c) acc[r][c] = 0.f;

    // staging decomposition
    const int xrow = tid >> 2;        // 0..63
    const int xq   = tid & 3;         // chunks xq and xq+4
    const int wcol = tid >> 1;        // 0..127
    const int wt2  = tid & 1;         // chunks wt2*4 + 0..3

    int gxrow = m0 + xrow; if (gxrow > N - 1) gxrow = N - 1;   // clamped load
    const float* xrp = x + (size_t)gxrow * 128;
    const float* wcp = W + (size_t)wcol * 128;

    for (int k0 = 0; k0 < 128; k0 += 32) {
        // ---- stage x (64 rows x 8 chunks), leaky(0.01)
        {
            float4 v0 = *reinterpret_cast<const float4*>(xrp + k0 + xq * 4);
            float4 v1 = *reinterpret_cast<const float4*>(xrp + k0 + (xq + 4) * 4);
            v0.x = v0.x >= 0.f ? v0.x : 0.01f * v0.x;
            v0.y = v0.y >= 0.f ? v0.y : 0.01f * v0.y;
            v0.z = v0.z >= 0.f ? v0.z : 0.01f * v0.z;
            v0.w = v0.w >= 0.f ? v0.w : 0.01f * v0.w;
            v1.x = v1.x >= 0.f ? v1.x : 0.01f * v1.x;
            v1.y = v1.y >= 0.f ? v1.y : 0.01f * v1.y;
            v1.z = v1.z >= 0.f ? v1.z : 0.01f * v1.z;
            v1.w = v1.w >= 0.f ? v1.w : 0.01f * v1.w;
            xs4[xq * 64 + ((xrow & ~7) | ((xrow & 7) ^ xq))] = v0;
            int q1 = xq + 4;
            xs4[q1 * 64 + ((xrow & ~7) | ((xrow & 7) ^ q1))] = v1;
        }
        // ---- stage W (128 cols x 8 chunks)
#pragma unroll
        for (int i = 0; i < 4; ++i) {
            int d4 = wt2 * 4 + i;
            float4 v = *reinterpret_cast<const float4*>(wcp + k0 + d4 * 4);
            ws4[d4 * 128 + ((wcol & ~7) | ((wcol & 7) ^ d4))] = v;
        }
        __syncthreads();

#pragma unroll
        for (int d4 = 0; d4 < 8; ++d4) {
            float4 b[8];
#pragma unroll
            for (int c = 0; c < 8; ++c) {
                int colj = tx + 16 * c;
                b[c] = ws4[d4 * 128 + ((colj & ~7) | ((colj & 7) ^ d4))];
            }
#pragma unroll
            for (int r = 0; r < 4; ++r) {
                int row = ty * 4 + r;
                const float4 a = xs4[d4 * 64 + ((row & ~7) | ((row & 7) ^ d4))];
#pragma unroll
                for (int c = 0; c < 8; ++c) {
                    acc[r][c] += a.x * b[c].x + a.y * b[c].y
                               + a.z * b[c].z + a.w * b[c].w;
                }
            }
        }
        __syncthreads();
    }

    // ---- store h (scalar stores; 64B-coalesced segments per (r,c))
#pragma unroll
    for (int r = 0; r < 4; ++r) {
        int row = m0 + ty * 4 + r;
        if (row < N) {
            float* hp = h + (size_t)row * 128 + tx;
#pragma unroll
            for (int c = 0; c < 8; ++c) hp[16 * c] = acc[r][c];
        }
    }
}

// ---------------------------------------------------------------------------
// el/er reduction (layers 1,2). One wave per node.
__global__ __launch_bounds__(256) void elr_kernel(
    const float* __restrict__ h, const float* __restrict__ al,
    const float* __restrict__ ar, float* __restrict__ el,
    float* __restrict__ er, int N)
{
    int node = blockIdx.x * 4 + (threadIdx.x >> 6);
    int lane = threadIdx.x & 63;
    if (node >= N) return;
    float v0 = h[(size_t)node * 128 + lane];
    float v1 = h[(size_t)node * 128 + 64 + lane];
    float sl0 = v0 * al[lane];
    float sl1 = v1 * al[64 + lane];
    float sr0 = v0 * ar[lane];
    float sr1 = v1 * ar[64 + lane];
#pragma unroll
    for (int m = 16; m >= 1; m >>= 1) {
        sl0 += __shfl_xor(sl0, m, 64);
        sl1 += __shfl_xor(sl1, m, 64);
        sr0 += __shfl_xor(sr0, m, 64);
        sr1 += __shfl_xor(sr1, m, 64);
    }
    if ((lane & 31) == 0) {
        int hb = lane >> 5;
        el[node * 4 + hb]     = sl0;
        el[node * 4 + hb + 2] = sl1;
        er[node * 4 + hb]     = sr0;
        er[node * 4 + hb + 2] = sr1;
    }
}

// ---------------------------------------------------------------------------
// Fused softmax-stats + gather + (optional) prediction epilogue.
// One wave per node (head-quartered Phase A, direct-load Phase B).
__global__ __launch_bounds__(256) void agg_fused_kernel(
    const float* __restrict__ h, const float* __restrict__ el,
    const float* __restrict__ er, const int* __restrict__ rowp,
    const int* __restrict__ col, const float* __restrict__ bias,
    float* __restrict__ xout, const float* __restrict__ pW,
    const float* __restrict__ pb, float* __restrict__ logits,
    int N, int last)
{
    int v = blockIdx.x * 4 + (threadIdx.x >> 6);
    int lane = threadIdx.x & 63;
    if (v >= N) return;
    const int r0 = rowp[v], r1 = rowp[v + 1];
    const int deg = r1 - r0;

    // ---- Phase A: per-head online softmax stats
    const int qh  = lane >> 4;
    const int j16 = lane & 15;
    const float erq = er[(size_t)v * 4 + qh];

    float m_l = -INFINITY, s_l = 0.f;
    for (int jj = j16; jj < deg; jj += 16) {
        int u = col[r0 + jj];
        float e = leaky02(el[(size_t)u * 4 + qh] + erq);
        if (e > m_l) { s_l = s_l * __expf(m_l - e) + 1.f; m_l = e; }
        else         { s_l += __expf(e - m_l); }
    }
#pragma unroll
    for (int d = 1; d <= 8; d <<= 1) {
        float m2 = __shfl_xor(m_l, d, 64);
        float s2 = __shfl_xor(s_l, d, 64);
        float nm = fmaxf(m_l, m2);
        s_l = (s_l > 0.f ? s_l * __expf(m_l - nm) : 0.f)
            + (s2  > 0.f ? s2  * __expf(m2  - nm) : 0.f);
        m_l = nm;
    }
    const float is_l = 1.f / s_l;

    // ---- Phase B: gather, 4 edges in flight (quarter-wave per edge)
    const int q = lane >> 4, l16 = lane & 15, f0 = l16 * 4, hA = l16 >> 3;
    const float mA  = __shfl(m_l,  hA * 16, 64);
    const float isA = __shfl(is_l, hA * 16, 64);
    const float mB  = __shfl(m_l,  (hA + 2) * 16, 64);
    const float isB = __shfl(is_l, (hA + 2) * 16, 64);
    const float erA = er[(size_t)v * 4 + hA];
    const float erB = er[(size_t)v * 4 + 2 + hA];

    float4 acc0 = make_float4(0.f, 0.f, 0.f, 0.f);
    float4 acc1 = make_float4(0.f, 0.f, 0.f, 0.f);

    for (int j = r0 + q; j < r1; j += 4) {
        int u = col[j];
        float eA = leaky02(el[(size_t)u * 4 + hA] + erA);
        float eB = leaky02(el[(size_t)u * 4 + 2 + hA] + erB);
        float aA = __expf(eA - mA) * isA;
        float aB = __expf(eB - mB) * isB;
        const float4 v0 = *reinterpret_cast<const float4*>(&h[(size_t)u * 128 + f0]);
        const float4 v1 = *reinterpret_cast<const float4*>(&h[(size_t)u * 128 + 64 + f0]);
        acc0.x += aA * v0.x; acc0.y += aA * v0.y;
        acc0.z += aA * v0.z; acc0.w += aA * v0.w;
        acc1.x += aB * v1.x; acc1.y += aB * v1.y;
        acc1.z += aB * v1.z; acc1.w += aB * v1.w;
    }

#pragma unroll
    for (int d = 16; d <= 32; d <<= 1) {
        acc0.x += __shfl_xor(acc0.x, d, 64);
        acc0.y += __shfl_xor(acc0.y, d, 64);
        acc0.z += __shfl_xor(acc0.z, d, 64);
        acc0.w += __shfl_xor(acc0.w, d, 64);
        acc1.x += __shfl_xor(acc1.x, d, 64);
        acc1.y += __shfl_xor(acc1.y, d, 64);
        acc1.z += __shfl_xor(acc1.z, d, 64);
        acc1.w += __shfl_xor(acc1.w, d, 64);
    }

    if (last) {
        float part = 0.f;
        if (lane < 16) {
            float4 b0 = *reinterpret_cast<const float4*>(&bias[f0]);
            float4 b1 = *reinterpret_cast<const float4*>(&bias[64 + f0]);
            float4 p0 = *reinterpret_cast<const float4*>(&pW[f0]);
            float4 p1 = *reinterpret_cast<const float4*>(&pW[64 + f0]);
            part = (acc0.x + b0.x) * p0.x + (acc0.y + b0.y) * p0.y
                 + (acc0.z + b0.z) * p0.z + (acc0.w + b0.w) * p0.w
                 + (acc1.x + b1.x) * p1.x + (acc1.y + b1.y) * p1.y
                 + (acc1.z + b1.z) * p1.z + (acc1.w + b1.w) * p1.w;
        }
#pragma unroll
        for (int d = 8; d >= 1; d >>= 1) part += __shfl_xor(part, d, 64);
        if (lane == 0) logits[v] = part + pb[0];
    } else {
        if (lane < 16) {
            float4 b0 = *reinterpret_cast<const float4*>(&bias[f0]);
            float4 b1 = *reinterpret_cast<const float4*>(&bias[64 + f0]);
            acc0.x += b0.x; acc0.y += b0.y; acc0.z += b0.z; acc0.w += b0.w;
            acc1.x += b1.x; acc1.y += b1.y; acc1.z += b1.z; acc1.w += b1.w;
            *reinterpret_cast<float4*>(&xout[(size_t)v * 128 + f0])      = acc0;
            *reinterpret_cast<float4*>(&xout[(size_t)v * 128 + 64 + f0]) = acc1;
        }
    }
}

// ---------------------------------------------------------------------------
extern "C" void kernel_launch(void* const* d_in, const int* in_sizes, int n_in,
                              void* d_out, int out_size, void* d_ws, size_t ws_size,
                              hipStream_t stream)
{
    const float* weights = (const float*)d_in[0];
    const float* lin_W   = (const float*)d_in[1];
    const float* lin_b   = (const float*)d_in[2];
    const float* fc_W    = (const float*)d_in[3];
    const float* attn_l  = (const float*)d_in[4];
    const float* attn_r  = (const float*)d_in[5];
    const float* conv_b  = (const float*)d_in[6];
    const float* pred_W  = (const float*)d_in[7];
    const float* pred_b  = (const float*)d_in[8];
    const int*   src     = (const int*)d_in[9];
    const int*   dst     = (const int*)d_in[10];

    const int N = in_sizes[0];
    const int E = in_sizes[9];
    const int NB = (N + SCAN_TILE - 1) / SCAN_TILE;

    // workspace layout (16B-aligned float4 sections first)
    float* x   = (float*)d_ws;                   // N*128
    float* h   = x + (size_t)N * 128;            // N*128
    float* el  = h + (size_t)N * 128;            // N*4
    float* er  = el + (size_t)N * 4;             // N*4
    float* c1  = er + (size_t)N * 4;             // 128
    float* c2  = c1 + 128;                       // 128
    float* prm = c2 + 128;                       // 16
    int*   deg  = (int*)(prm + 16);              // N
    int*   rowp = deg + N;                       // N+1
    int*   cur  = rowp + (N + 1);                // N
    int*   col  = cur + N;                       // E+N
    int*   bsum = col + (E + N);                 // NB
    int*   bpre = bsum + NB;                     // NB

    // CSR build (fresh every call: ws is re-poisoned)
    deg_init_kernel<<<(N + 255) / 256, 256, 0, stream>>>(deg, N);
    deg_count_kernel<<<(E + 255) / 256, 256, 0, stream>>>(dst, deg, E);
    scanA_kernel<<<NB, 256, 0, stream>>>(deg, bsum, N);
    scanB_kernel<<<1, 1024, 0, stream>>>(bsum, bpre, rowp, NB, N);
    scanC_kernel<<<NB, 256, 0, stream>>>(deg, bpre, rowp, cur, N);
    scatter_kernel<<<(E + N + 255) / 256, 256, 0, stream>>>(src, dst, cur, col, E, N);

    // Layer 0 via rank-1 identity
    rank1_prep_kernel<<<1, 128, 0, stream>>>(lin_W, lin_b, fc_W, attn_l, attn_r,
                                             c1, c2, prm);
    rank1_apply_kernel<<<((size_t)N * 32 + 255) / 256, 256, 0, stream>>>(
        weights, c1, c2, prm, h, el, er, N);
    agg_fused_kernel<<<(N + 3) / 4, 256, 0, stream>>>(
        h, el, er, rowp, col, conv_b, x, pred_W, pred_b, (float*)d_out, N, 0);

    // Layers 1, 2
    for (int l = 1; l < 3; ++l) {
        gemm_kernel<<<(N + 63) / 64, 256, 0, stream>>>(
            x, fc_W + (size_t)l * 128 * 128, h, N);
        elr_kernel<<<(N + 3) / 4, 256, 0, stream>>>(
            h, attn_l + l * 128, attn_r + l * 128, el, er, N);
        agg_fused_kernel<<<(N + 3) / 4, 256, 0, stream>>>(
            h, el, er, rowp, col, conv_b + l * 128, x, pred_W, pred_b,
            (float*)d_out, N, l == 2 ? 1 : 0);
    }
}

// Round 10
// 531.828 us; speedup vs baseline: 1.2416x; 1.1857x over previous
//
#include <hip/hip_runtime.h>
#include <hip/hip_bf16.h>
#include <math.h>

// Problem constants: N=100000, E=600000, D=128, H=4, F=32, L=3

__device__ __forceinline__ float leaky02(float x) {
    return x >= 0.f ? x : 0.2f * x;
}

// bf16 helpers (round-to-nearest-even)
__device__ __forceinline__ short f2bf(float f) {
    unsigned u = __float_as_uint(f);
    unsigned r = u + 0x7FFFu + ((u >> 16) & 1u);
    return (short)(r >> 16);
}
__device__ __forceinline__ float bf2f(short s) {
    return __uint_as_float(((unsigned)(unsigned short)s) << 16);
}

typedef __attribute__((ext_vector_type(8))) short bf16x8;
typedef __attribute__((ext_vector_type(4))) float f32x4;

// ---------------------------------------------------------------------------
// CSR build
__global__ __launch_bounds__(256) void deg_init_kernel(int* __restrict__ deg, int N)
{
    int i = blockIdx.x * 256 + threadIdx.x;
    if (i < N) deg[i] = 1;  // self loop
}

__global__ __launch_bounds__(256) void deg_count_kernel(
    const int* __restrict__ dst, int* __restrict__ deg, int E)
{
    int i = blockIdx.x * 256 + threadIdx.x;
    if (i < E) atomicAdd(&deg[dst[i]], 1);
}

#define SCAN_TILE 1024

__global__ __launch_bounds__(256) void scanA_kernel(
    const int* __restrict__ deg, int* __restrict__ bsum, int N)
{
    __shared__ int ws[4];
    int b = blockIdx.x, t = threadIdx.x;
    int base = b * SCAN_TILE + t * 4;
    int s = 0;
#pragma unroll
    for (int k = 0; k < 4; ++k) {
        int i = base + k;
        if (i < N) s += deg[i];
    }
#pragma unroll
    for (int m = 32; m >= 1; m >>= 1) s += __shfl_xor(s, m, 64);
    if ((t & 63) == 0) ws[t >> 6] = s;
    __syncthreads();
    if (t == 0) bsum[b] = ws[0] + ws[1] + ws[2] + ws[3];
}

__global__ __launch_bounds__(1024) void scanB_kernel(
    int* __restrict__ bsum, int* __restrict__ bpre, int* __restrict__ rowp,
    int NB, int N)
{
    __shared__ int sh[1024];
    int t = threadIdx.x;
    int v = (t < NB) ? bsum[t] : 0;
    sh[t] = v;
    __syncthreads();
    for (int off = 1; off < 1024; off <<= 1) {
        int u = (t >= off) ? sh[t - off] : 0;
        __syncthreads();
        sh[t] += u;
        __syncthreads();
    }
    if (t < NB) bpre[t] = sh[t] - v;          // exclusive prefix
    if (t == 1023) rowp[N] = sh[1023];        // total
}

__global__ __launch_bounds__(256) void scanC_kernel(
    const int* __restrict__ deg, const int* __restrict__ bpre,
    int* __restrict__ rowp, int* __restrict__ cur, int N)
{
    __shared__ int sh[256];
    int b = blockIdx.x, t = threadIdx.x;
    int base = b * SCAN_TILE + t * 4;
    int v[4];
#pragma unroll
    for (int k = 0; k < 4; ++k) {
        int i = base + k;
        v[k] = (i < N) ? deg[i] : 0;
    }
    int tsum = v[0] + v[1] + v[2] + v[3];
    sh[t] = tsum;
    __syncthreads();
    for (int off = 1; off < 256; off <<= 1) {
        int u = (t >= off) ? sh[t - off] : 0;
        __syncthreads();
        sh[t] += u;
        __syncthreads();
    }
    int pre = bpre[b] + sh[t] - tsum;
#pragma unroll
    for (int k = 0; k < 4; ++k) {
        int i = base + k;
        if (i < N) { rowp[i] = pre; cur[i] = pre; }
        pre += v[k];
    }
}

__global__ __launch_bounds__(256) void scatter_kernel(
    const int* __restrict__ src, const int* __restrict__ dst,
    int* __restrict__ cur, int* __restrict__ col, int E, int N)
{
    int i = blockIdx.x * 256 + threadIdx.x;
    if (i < E) {
        int p = atomicAdd(&cur[dst[i]], 1);
        col[p] = src[i];
    } else if (i < E + N) {
        int v = i - E;
        int p = atomicAdd(&cur[v], 1);
        col[p] = v;  // self loop
    }
}

// ---------------------------------------------------------------------------
// Layer-0 rank-1 precompute
__global__ __launch_bounds__(128) void rank1_prep_kernel(
    const float* __restrict__ lW, const float* __restrict__ lb,
    const float* __restrict__ W0, const float* __restrict__ al,
    const float* __restrict__ ar, float* __restrict__ c1,
    float* __restrict__ c2, float* __restrict__ prm)
{
    int j = threadIdx.x;
    float s1 = 0.f, s2 = 0.f;
    for (int d = 0; d < 128; ++d) {
        float wv = W0[j * 128 + d];
        s1 += lW[d] * wv;
        s2 += lb[d] * wv;
    }
    c1[j] = s1; c2[j] = s2;
    __shared__ float sh1[128], sh2[128], sh3[128], sh4[128];
    sh1[j] = s1 * al[j]; sh2[j] = s2 * al[j];
    sh3[j] = s1 * ar[j]; sh4[j] = s2 * ar[j];
    __syncthreads();
    if (j < 4) {
        float p = 0.f, q = 0.f, r = 0.f, s = 0.f;
        for (int f = 0; f < 32; ++f) {
            p += sh1[j * 32 + f]; q += sh2[j * 32 + f];
            r += sh3[j * 32 + f]; s += sh4[j * 32 + f];
        }
        prm[j] = p; prm[4 + j] = q; prm[8 + j] = r; prm[12 + j] = s;
    }
}

// h0[n,j] = w[n]*c1[j] + c2[j]; el0[n,h] = w[n]*pl[h]+ql[h]; er0 likewise.
__global__ __launch_bounds__(256) void rank1_apply_kernel(
    const float* __restrict__ w, const float* __restrict__ c1,
    const float* __restrict__ c2, const float* __restrict__ prm,
    float* __restrict__ h, float* __restrict__ el, float* __restrict__ er, int N)
{
    int i = blockIdx.x * 256 + threadIdx.x;
    int n = i >> 5, k = i & 31;
    if (n >= N) return;
    float wn = w[n];
    float4 a = *reinterpret_cast<const float4*>(&c1[k * 4]);
    float4 b = *reinterpret_cast<const float4*>(&c2[k * 4]);
    float4 o = make_float4(wn * a.x + b.x, wn * a.y + b.y,
                           wn * a.z + b.z, wn * a.w + b.w);
    *reinterpret_cast<float4*>(&h[(size_t)n * 128 + k * 4]) = o;
    if (k == 0) {
        float4 pl = *reinterpret_cast<const float4*>(&prm[0]);
        float4 ql = *reinterpret_cast<const float4*>(&prm[4]);
        float4 pr = *reinterpret_cast<const float4*>(&prm[8]);
        float4 qr = *reinterpret_cast<const float4*>(&prm[12]);
        float4 e1 = make_float4(wn * pl.x + ql.x, wn * pl.y + ql.y,
                                wn * pl.z + ql.z, wn * pl.w + ql.w);
        float4 e2 = make_float4(wn * pr.x + qr.x, wn * pr.y + qr.y,
                                wn * pr.z + qr.z, wn * pr.w + qr.w);
        *reinterpret_cast<float4*>(&el[(size_t)n * 4]) = e1;
        *reinterpret_cast<float4*>(&er[(size_t)n * 4]) = e2;
    }
}

// ---------------------------------------------------------------------------
// Split fc_W (layers 1,2) into bf16 hi/lo. n = 2*128*128 elements.
__global__ __launch_bounds__(256) void wsplit_kernel(
    const float* __restrict__ W, short* __restrict__ Wh,
    short* __restrict__ Wl, int n)
{
    int i = blockIdx.x * 256 + threadIdx.x;
    if (i < n) {
        float f = W[i];
        short hi = f2bf(f);
        float fh = bf2f(hi);
        Wh[i] = hi;
        Wl[i] = f2bf(f - fh);
    }
}

// ---------------------------------------------------------------------------
// MFMA split-bf16 GEMM (layers 1,2): h[n,j] = sum_d leaky0.01(x[n,d])*W[j,d]
// C = Ah*Wh + Al*Wh + Ah*Wl (Al*Wl dropped, ~2^-18 relative).
// mfma_f32_16x16x32_bf16 fragments (HW-verified layouts):
//   A[m=lane&15][k=quad*8+j], B[n=lane&15][k=quad*8+j]  (8 K-consecutive
//   elements/lane -> direct row-major global loads, NO LDS),
//   C/D: col=lane&15, row=quad*4+reg.
// Block = 256 thr = 4 waves; wave w owns rows m0+w*16..+15, all 128 cols.
__global__ __launch_bounds__(256) void gemm_mfma_kernel(
    const float* __restrict__ x, const short* __restrict__ Wh,
    const short* __restrict__ Wl, float* __restrict__ h, int N)
{
    const int lane = threadIdx.x & 63;
    const int wv   = threadIdx.x >> 6;
    const int m0   = blockIdx.x * 64 + wv * 16;
    const int mr   = lane & 15;
    const int quad = lane >> 4;

    int arow = m0 + mr; if (arow > N - 1) arow = N - 1;   // clamped load row
    const float* xp = x + (size_t)arow * 128 + quad * 8;

    f32x4 acc[8];
#pragma unroll
    for (int c = 0; c < 8; ++c) acc[c] = (f32x4){0.f, 0.f, 0.f, 0.f};

    for (int kk = 0; kk < 4; ++kk) {
        // load 8 K-consecutive x values, leaky, split into bf16 hi/lo frags
        float4 v0 = *reinterpret_cast<const float4*>(xp + kk * 32);
        float4 v1 = *reinterpret_cast<const float4*>(xp + kk * 32 + 4);
        float f[8] = {v0.x, v0.y, v0.z, v0.w, v1.x, v1.y, v1.z, v1.w};
        union { bf16x8 v; short s[8]; } ah, al;
#pragma unroll
        for (int j = 0; j < 8; ++j) {
            float t = f[j];
            t = t >= 0.f ? t : 0.01f * t;
            short hi = f2bf(t);
            ah.s[j] = hi;
            al.s[j] = f2bf(t - bf2f(hi));
        }
        const int kb = kk * 32 + quad * 8;
#pragma unroll
        for (int c = 0; c < 8; ++c) {
            const size_t wo = (size_t)(c * 16 + mr) * 128 + kb;
            bf16x8 bh = *reinterpret_cast<const bf16x8*>(Wh + wo);
            bf16x8 bl = *reinterpret_cast<const bf16x8*>(Wl + wo);
            acc[c] = __builtin_amdgcn_mfma_f32_16x16x32_bf16(ah.v, bh, acc[c], 0, 0, 0);
            acc[c] = __builtin_amdgcn_mfma_f32_16x16x32_bf16(al.v, bh, acc[c], 0, 0, 0);
            acc[c] = __builtin_amdgcn_mfma_f32_16x16x32_bf16(ah.v, bl, acc[c], 0, 0, 0);
        }
    }

    // store: D row = quad*4+i, col = c*16 + mr
#pragma unroll
    for (int i = 0; i < 4; ++i) {
        int row = m0 + quad * 4 + i;
        if (row < N) {
            float* hp = h + (size_t)row * 128 + mr;
#pragma unroll
            for (int c = 0; c < 8; ++c) hp[c * 16] = acc[c][i];
        }
    }
}

// ---------------------------------------------------------------------------
// el/er reduction (layers 1,2). One wave per node.
__global__ __launch_bounds__(256) void elr_kernel(
    const float* __restrict__ h, const float* __restrict__ al,
    const float* __restrict__ ar, float* __restrict__ el,
    float* __restrict__ er, int N)
{
    int node = blockIdx.x * 4 + (threadIdx.x >> 6);
    int lane = threadIdx.x & 63;
    if (node >= N) return;
    float v0 = h[(size_t)node * 128 + lane];
    float v1 = h[(size_t)node * 128 + 64 + lane];
    float sl0 = v0 * al[lane];
    float sl1 = v1 * al[64 + lane];
    float sr0 = v0 * ar[lane];
    float sr1 = v1 * ar[64 + lane];
#pragma unroll
    for (int m = 16; m >= 1; m >>= 1) {
        sl0 += __shfl_xor(sl0, m, 64);
        sl1 += __shfl_xor(sl1, m, 64);
        sr0 += __shfl_xor(sr0, m, 64);
        sr1 += __shfl_xor(sr1, m, 64);
    }
    if ((lane & 31) == 0) {
        int hb = lane >> 5;
        el[node * 4 + hb]     = sl0;
        el[node * 4 + hb + 2] = sl1;
        er[node * 4 + hb]     = sr0;
        er[node * 4 + hb + 2] = sr1;
    }
}

// ---------------------------------------------------------------------------
// Fused softmax-stats + gather + (optional) prediction epilogue.
// One wave per node (head-quartered Phase A, direct-load Phase B).
__global__ __launch_bounds__(256) void agg_fused_kernel(
    const float* __restrict__ h, const float* __restrict__ el,
    const float* __restrict__ er, const int* __restrict__ rowp,
    const int* __restrict__ col, const float* __restrict__ bias,
    float* __restrict__ xout, const float* __restrict__ pW,
    const float* __restrict__ pb, float* __restrict__ logits,
    int N, int last)
{
    int v = blockIdx.x * 4 + (threadIdx.x >> 6);
    int lane = threadIdx.x & 63;
    if (v >= N) return;
    const int r0 = rowp[v], r1 = rowp[v + 1];
    const int deg = r1 - r0;

    // ---- Phase A: per-head online softmax stats
    const int qh  = lane >> 4;
    const int j16 = lane & 15;
    const float erq = er[(size_t)v * 4 + qh];

    float m_l = -INFINITY, s_l = 0.f;
    for (int jj = j16; jj < deg; jj += 16) {
        int u = col[r0 + jj];
        float e = leaky02(el[(size_t)u * 4 + qh] + erq);
        if (e > m_l) { s_l = s_l * __expf(m_l - e) + 1.f; m_l = e; }
        else         { s_l += __expf(e - m_l); }
    }
#pragma unroll
    for (int d = 1; d <= 8; d <<= 1) {
        float m2 = __shfl_xor(m_l, d, 64);
        float s2 = __shfl_xor(s_l, d, 64);
        float nm = fmaxf(m_l, m2);
        s_l = (s_l > 0.f ? s_l * __expf(m_l - nm) : 0.f)
            + (s2  > 0.f ? s2  * __expf(m2  - nm) : 0.f);
        m_l = nm;
    }
    const float is_l = 1.f / s_l;

    // ---- Phase B: gather, 4 edges in flight (quarter-wave per edge)
    const int q = lane >> 4, l16 = lane & 15, f0 = l16 * 4, hA = l16 >> 3;
    const float mA  = __shfl(m_l,  hA * 16, 64);
    const float isA = __shfl(is_l, hA * 16, 64);
    const float mB  = __shfl(m_l,  (hA + 2) * 16, 64);
    const float isB = __shfl(is_l, (hA + 2) * 16, 64);
    const float erA = er[(size_t)v * 4 + hA];
    const float erB = er[(size_t)v * 4 + 2 + hA];

    float4 acc0 = make_float4(0.f, 0.f, 0.f, 0.f);
    float4 acc1 = make_float4(0.f, 0.f, 0.f, 0.f);

    for (int j = r0 + q; j < r1; j += 4) {
        int u = col[j];
        float eA = leaky02(el[(size_t)u * 4 + hA] + erA);
        float eB = leaky02(el[(size_t)u * 4 + 2 + hA] + erB);
        float aA = __expf(eA - mA) * isA;
        float aB = __expf(eB - mB) * isB;
        const float4 v0 = *reinterpret_cast<const float4*>(&h[(size_t)u * 128 + f0]);
        const float4 v1 = *reinterpret_cast<const float4*>(&h[(size_t)u * 128 + 64 + f0]);
        acc0.x += aA * v0.x; acc0.y += aA * v0.y;
        acc0.z += aA * v0.z; acc0.w += aA * v0.w;
        acc1.x += aB * v1.x; acc1.y += aB * v1.y;
        acc1.z += aB * v1.z; acc1.w += aB * v1.w;
    }

#pragma unroll
    for (int d = 16; d <= 32; d <<= 1) {
        acc0.x += __shfl_xor(acc0.x, d, 64);
        acc0.y += __shfl_xor(acc0.y, d, 64);
        acc0.z += __shfl_xor(acc0.z, d, 64);
        acc0.w += __shfl_xor(acc0.w, d, 64);
        acc1.x += __shfl_xor(acc1.x, d, 64);
        acc1.y += __shfl_xor(acc1.y, d, 64);
        acc1.z += __shfl_xor(acc1.z, d, 64);
        acc1.w += __shfl_xor(acc1.w, d, 64);
    }

    if (last) {
        float part = 0.f;
        if (lane < 16) {
            float4 b0 = *reinterpret_cast<const float4*>(&bias[f0]);
            float4 b1 = *reinterpret_cast<const float4*>(&bias[64 + f0]);
            float4 p0 = *reinterpret_cast<const float4*>(&pW[f0]);
            float4 p1 = *reinterpret_cast<const float4*>(&pW[64 + f0]);
            part = (acc0.x + b0.x) * p0.x + (acc0.y + b0.y) * p0.y
                 + (acc0.z + b0.z) * p0.z + (acc0.w + b0.w) * p0.w
                 + (acc1.x + b1.x) * p1.x + (acc1.y + b1.y) * p1.y
                 + (acc1.z + b1.z) * p1.z + (acc1.w + b1.w) * p1.w;
        }
#pragma unroll
        for (int d = 8; d >= 1; d >>= 1) part += __shfl_xor(part, d, 64);
        if (lane == 0) logits[v] = part + pb[0];
    } else {
        if (lane < 16) {
            float4 b0 = *reinterpret_cast<const float4*>(&bias[f0]);
            float4 b1 = *reinterpret_cast<const float4*>(&bias[64 + f0]);
            acc0.x += b0.x; acc0.y += b0.y; acc0.z += b0.z; acc0.w += b0.w;
            acc1.x += b1.x; acc1.y += b1.y; acc1.z += b1.z; acc1.w += b1.w;
            *reinterpret_cast<float4*>(&xout[(size_t)v * 128 + f0])      = acc0;
            *reinterpret_cast<float4*>(&xout[(size_t)v * 128 + 64 + f0]) = acc1;
        }
    }
}

// ---------------------------------------------------------------------------
extern "C" void kernel_launch(void* const* d_in, const int* in_sizes, int n_in,
                              void* d_out, int out_size, void* d_ws, size_t ws_size,
                              hipStream_t stream)
{
    const float* weights = (const float*)d_in[0];
    const float* lin_W   = (const float*)d_in[1];
    const float* lin_b   = (const float*)d_in[2];
    const float* fc_W    = (const float*)d_in[3];
    const float* attn_l  = (const float*)d_in[4];
    const float* attn_r  = (const float*)d_in[5];
    const float* conv_b  = (const float*)d_in[6];
    const float* pred_W  = (const float*)d_in[7];
    const float* pred_b  = (const float*)d_in[8];
    const int*   src     = (const int*)d_in[9];
    const int*   dst     = (const int*)d_in[10];

    const int N = in_sizes[0];
    const int E = in_sizes[9];
    const int NB = (N + SCAN_TILE - 1) / SCAN_TILE;

    // workspace layout (16B-aligned float4 sections first)
    float* x   = (float*)d_ws;                   // N*128
    float* h   = x + (size_t)N * 128;            // N*128
    float* el  = h + (size_t)N * 128;            // N*4
    float* er  = el + (size_t)N * 4;             // N*4
    float* c1  = er + (size_t)N * 4;             // 128
    float* c2  = c1 + 128;                       // 128
    float* prm = c2 + 128;                       // 16
    short* Whs = (short*)(prm + 16);             // 2*16384 bf16 (layers 1,2)
    short* Wls = Whs + 2 * 16384;                // 2*16384 bf16
    int*   deg  = (int*)(Wls + 2 * 16384);       // N
    int*   rowp = deg + N;                       // N+1
    int*   cur  = rowp + (N + 1);                // N
    int*   col  = cur + N;                       // E+N
    int*   bsum = col + (E + N);                 // NB
    int*   bpre = bsum + NB;                     // NB

    // CSR build (fresh every call: ws is re-poisoned)
    deg_init_kernel<<<(N + 255) / 256, 256, 0, stream>>>(deg, N);
    deg_count_kernel<<<(E + 255) / 256, 256, 0, stream>>>(dst, deg, E);
    scanA_kernel<<<NB, 256, 0, stream>>>(deg, bsum, N);
    scanB_kernel<<<1, 1024, 0, stream>>>(bsum, bpre, rowp, NB, N);
    scanC_kernel<<<NB, 256, 0, stream>>>(deg, bpre, rowp, cur, N);
    scatter_kernel<<<(E + N + 255) / 256, 256, 0, stream>>>(src, dst, cur, col, E, N);

    // Split W for layers 1,2 into bf16 hi/lo
    wsplit_kernel<<<(2 * 16384 + 255) / 256, 256, 0, stream>>>(
        fc_W + 16384, Whs, Wls, 2 * 16384);

    // Layer 0 via rank-1 identity
    rank1_prep_kernel<<<1, 128, 0, stream>>>(lin_W, lin_b, fc_W, attn_l, attn_r,
                                             c1, c2, prm);
    rank1_apply_kernel<<<((size_t)N * 32 + 255) / 256, 256, 0, stream>>>(
        weights, c1, c2, prm, h, el, er, N);
    agg_fused_kernel<<<(N + 3) / 4, 256, 0, stream>>>(
        h, el, er, rowp, col, conv_b, x, pred_W, pred_b, (float*)d_out, N, 0);

    // Layers 1, 2 (MFMA split-bf16 gemm)
    for (int l = 1; l < 3; ++l) {
        gemm_mfma_kernel<<<(N + 63) / 64, 256, 0, stream>>>(
            x, Whs + (size_t)(l - 1) * 16384, Wls + (size_t)(l - 1) * 16384, h, N);
        elr_kernel<<<(N + 3) / 4, 256, 0, stream>>>(
            h, attn_l + l * 128, attn_r + l * 128, el, er, N);
        agg_fused_kernel<<<(N + 3) / 4, 256, 0, stream>>>(
            h, el, er, rowp, col, conv_b + l * 128, x, pred_W, pred_b,
            (float*)d_out, N, l == 2 ? 1 : 0);
    }
}

// Round 11
// 507.680 us; speedup vs baseline: 1.3007x; 1.0476x over previous
//
#include <hip/hip_runtime.h>
#include <hip/hip_bf16.h>
#include <math.h>

// Problem constants: N=100000, E=600000, D=128, H=4, F=32, L=3

__device__ __forceinline__ float leaky02(float x) {
    return x >= 0.f ? x : 0.2f * x;
}

// bf16 helpers (round-to-nearest-even)
__device__ __forceinline__ short f2bf(float f) {
    unsigned u = __float_as_uint(f);
    unsigned r = u + 0x7FFFu + ((u >> 16) & 1u);
    return (short)(r >> 16);
}
__device__ __forceinline__ float bf2f(short s) {
    return __uint_as_float(((unsigned)(unsigned short)s) << 16);
}

typedef __attribute__((ext_vector_type(8))) short bf16x8;
typedef __attribute__((ext_vector_type(4))) float f32x4;

// ---------------------------------------------------------------------------
// CSR build
__global__ __launch_bounds__(256) void deg_init_kernel(int* __restrict__ deg, int N)
{
    int i = blockIdx.x * 256 + threadIdx.x;
    if (i < N) deg[i] = 1;  // self loop
}

__global__ __launch_bounds__(256) void deg_count_kernel(
    const int* __restrict__ dst, int* __restrict__ deg, int E)
{
    int i = blockIdx.x * 256 + threadIdx.x;
    if (i < E) atomicAdd(&deg[dst[i]], 1);
}

#define SCAN_TILE 1024

__global__ __launch_bounds__(256) void scanA_kernel(
    const int* __restrict__ deg, int* __restrict__ bsum, int N)
{
    __shared__ int ws[4];
    int b = blockIdx.x, t = threadIdx.x;
    int base = b * SCAN_TILE + t * 4;
    int s = 0;
#pragma unroll
    for (int k = 0; k < 4; ++k) {
        int i = base + k;
        if (i < N) s += deg[i];
    }
#pragma unroll
    for (int m = 32; m >= 1; m >>= 1) s += __shfl_xor(s, m, 64);
    if ((t & 63) == 0) ws[t >> 6] = s;
    __syncthreads();
    if (t == 0) bsum[b] = ws[0] + ws[1] + ws[2] + ws[3];
}

__global__ __launch_bounds__(1024) void scanB_kernel(
    int* __restrict__ bsum, int* __restrict__ bpre, int* __restrict__ rowp,
    int NB, int N)
{
    __shared__ int sh[1024];
    int t = threadIdx.x;
    int v = (t < NB) ? bsum[t] : 0;
    sh[t] = v;
    __syncthreads();
    for (int off = 1; off < 1024; off <<= 1) {
        int u = (t >= off) ? sh[t - off] : 0;
        __syncthreads();
        sh[t] += u;
        __syncthreads();
    }
    if (t < NB) bpre[t] = sh[t] - v;          // exclusive prefix
    if (t == 1023) rowp[N] = sh[1023];        // total
}

__global__ __launch_bounds__(256) void scanC_kernel(
    const int* __restrict__ deg, const int* __restrict__ bpre,
    int* __restrict__ rowp, int* __restrict__ cur, int N)
{
    __shared__ int sh[256];
    int b = blockIdx.x, t = threadIdx.x;
    int base = b * SCAN_TILE + t * 4;
    int v[4];
#pragma unroll
    for (int k = 0; k < 4; ++k) {
        int i = base + k;
        v[k] = (i < N) ? deg[i] : 0;
    }
    int tsum = v[0] + v[1] + v[2] + v[3];
    sh[t] = tsum;
    __syncthreads();
    for (int off = 1; off < 256; off <<= 1) {
        int u = (t >= off) ? sh[t - off] : 0;
        __syncthreads();
        sh[t] += u;
        __syncthreads();
    }
    int pre = bpre[b] + sh[t] - tsum;
#pragma unroll
    for (int k = 0; k < 4; ++k) {
        int i = base + k;
        if (i < N) { rowp[i] = pre; cur[i] = pre; }
        pre += v[k];
    }
}

__global__ __launch_bounds__(256) void scatter_kernel(
    const int* __restrict__ src, const int* __restrict__ dst,
    int* __restrict__ cur, int* __restrict__ col, int E, int N)
{
    int i = blockIdx.x * 256 + threadIdx.x;
    if (i < E) {
        int p = atomicAdd(&cur[dst[i]], 1);
        col[p] = src[i];
    } else if (i < E + N) {
        int v = i - E;
        int p = atomicAdd(&cur[v], 1);
        col[p] = v;  // self loop
    }
}

// ---------------------------------------------------------------------------
// Layer-0 rank-1 precompute
__global__ __launch_bounds__(128) void rank1_prep_kernel(
    const float* __restrict__ lW, const float* __restrict__ lb,
    const float* __restrict__ W0, const float* __restrict__ al,
    const float* __restrict__ ar, float* __restrict__ c1,
    float* __restrict__ c2, float* __restrict__ prm)
{
    int j = threadIdx.x;
    float s1 = 0.f, s2 = 0.f;
    for (int d = 0; d < 128; ++d) {
        float wv = W0[j * 128 + d];
        s1 += lW[d] * wv;
        s2 += lb[d] * wv;
    }
    c1[j] = s1; c2[j] = s2;
    __shared__ float sh1[128], sh2[128], sh3[128], sh4[128];
    sh1[j] = s1 * al[j]; sh2[j] = s2 * al[j];
    sh3[j] = s1 * ar[j]; sh4[j] = s2 * ar[j];
    __syncthreads();
    if (j < 4) {
        float p = 0.f, q = 0.f, r = 0.f, s = 0.f;
        for (int f = 0; f < 32; ++f) {
            p += sh1[j * 32 + f]; q += sh2[j * 32 + f];
            r += sh3[j * 32 + f]; s += sh4[j * 32 + f];
        }
        prm[j] = p; prm[4 + j] = q; prm[8 + j] = r; prm[12 + j] = s;
    }
}

// h0[n,j] = w[n]*c1[j] + c2[j]; el0[n,h] = w[n]*pl[h]+ql[h]; er0 likewise.
__global__ __launch_bounds__(256) void rank1_apply_kernel(
    const float* __restrict__ w, const float* __restrict__ c1,
    const float* __restrict__ c2, const float* __restrict__ prm,
    float* __restrict__ h, float* __restrict__ el, float* __restrict__ er, int N)
{
    int i = blockIdx.x * 256 + threadIdx.x;
    int n = i >> 5, k = i & 31;
    if (n >= N) return;
    float wn = w[n];
    float4 a = *reinterpret_cast<const float4*>(&c1[k * 4]);
    float4 b = *reinterpret_cast<const float4*>(&c2[k * 4]);
    float4 o = make_float4(wn * a.x + b.x, wn * a.y + b.y,
                           wn * a.z + b.z, wn * a.w + b.w);
    *reinterpret_cast<float4*>(&h[(size_t)n * 128 + k * 4]) = o;
    if (k == 0) {
        float4 pl = *reinterpret_cast<const float4*>(&prm[0]);
        float4 ql = *reinterpret_cast<const float4*>(&prm[4]);
        float4 pr = *reinterpret_cast<const float4*>(&prm[8]);
        float4 qr = *reinterpret_cast<const float4*>(&prm[12]);
        float4 e1 = make_float4(wn * pl.x + ql.x, wn * pl.y + ql.y,
                                wn * pl.z + ql.z, wn * pl.w + ql.w);
        float4 e2 = make_float4(wn * pr.x + qr.x, wn * pr.y + qr.y,
                                wn * pr.z + qr.z, wn * pr.w + qr.w);
        *reinterpret_cast<float4*>(&el[(size_t)n * 4]) = e1;
        *reinterpret_cast<float4*>(&er[(size_t)n * 4]) = e2;
    }
}

// ---------------------------------------------------------------------------
// Split fc_W (layers 1,2) into bf16 hi/lo. n = 2*128*128 elements.
__global__ __launch_bounds__(256) void wsplit_kernel(
    const float* __restrict__ W, short* __restrict__ Wh,
    short* __restrict__ Wl, int n)
{
    int i = blockIdx.x * 256 + threadIdx.x;
    if (i < n) {
        float f = W[i];
        short hi = f2bf(f);
        float fh = bf2f(hi);
        Wh[i] = hi;
        Wl[i] = f2bf(f - fh);
    }
}

// ---------------------------------------------------------------------------
// MFMA split-bf16 GEMM + fused el/er (layers 1,2).
// h[n,j] = sum_d leaky0.01(x[n,d])*W[j,d]; C = Ah*Wh + Al*Wh + Ah*Wl.
// mfma_f32_16x16x32_bf16 fragments: A/B = 8 K-consecutive elems/lane
// (direct row-major global loads, NO LDS); C/D: col=lane&15, row=quad*4+reg.
// Wave w: rows m0+w*16..+15, cols c*16+mr. Head of col c*16+mr = c>>1, so
// el/er per-head partials are register-local; reduce over the 16 mr lanes.
__global__ __launch_bounds__(256) void gemm_mfma_kernel(
    const float* __restrict__ x, const short* __restrict__ Wh,
    const short* __restrict__ Wl, const float* __restrict__ al,
    const float* __restrict__ ar, float* __restrict__ h,
    float* __restrict__ el, float* __restrict__ er, int N)
{
    const int lane = threadIdx.x & 63;
    const int wv   = threadIdx.x >> 6;
    const int m0   = blockIdx.x * 64 + wv * 16;
    const int mr   = lane & 15;
    const int quad = lane >> 4;

    int arow = m0 + mr; if (arow > N - 1) arow = N - 1;   // clamped load row
    const float* xp = x + (size_t)arow * 128 + quad * 8;

    f32x4 acc[8];
#pragma unroll
    for (int c = 0; c < 8; ++c) acc[c] = (f32x4){0.f, 0.f, 0.f, 0.f};

    for (int kk = 0; kk < 4; ++kk) {
        float4 v0 = *reinterpret_cast<const float4*>(xp + kk * 32);
        float4 v1 = *reinterpret_cast<const float4*>(xp + kk * 32 + 4);
        float f[8] = {v0.x, v0.y, v0.z, v0.w, v1.x, v1.y, v1.z, v1.w};
        union { bf16x8 v; short s[8]; } ah, alo;
#pragma unroll
        for (int j = 0; j < 8; ++j) {
            float t = f[j];
            t = t >= 0.f ? t : 0.01f * t;
            short hi = f2bf(t);
            ah.s[j] = hi;
            alo.s[j] = f2bf(t - bf2f(hi));
        }
        const int kb = kk * 32 + quad * 8;
#pragma unroll
        for (int c = 0; c < 8; ++c) {
            const size_t wo = (size_t)(c * 16 + mr) * 128 + kb;
            bf16x8 bh = *reinterpret_cast<const bf16x8*>(Wh + wo);
            bf16x8 bl = *reinterpret_cast<const bf16x8*>(Wl + wo);
            acc[c] = __builtin_amdgcn_mfma_f32_16x16x32_bf16(ah.v, bh, acc[c], 0, 0, 0);
            acc[c] = __builtin_amdgcn_mfma_f32_16x16x32_bf16(alo.v, bh, acc[c], 0, 0, 0);
            acc[c] = __builtin_amdgcn_mfma_f32_16x16x32_bf16(ah.v, bl, acc[c], 0, 0, 0);
        }
    }

    // attn vectors for this lane's cols
    float alv[8], arv[8];
#pragma unroll
    for (int c = 0; c < 8; ++c) {
        alv[c] = al[c * 16 + mr];
        arv[c] = ar[c * 16 + mr];
    }

    // store h + fused el/er: D row = quad*4+i, col = c*16+mr
#pragma unroll
    for (int i = 0; i < 4; ++i) {
        int row = m0 + quad * 4 + i;
        bool ok = row < N;
        if (ok) {
            float* hp = h + (size_t)row * 128 + mr;
#pragma unroll
            for (int c = 0; c < 8; ++c) hp[c * 16] = acc[c][i];
        }
#pragma unroll
        for (int hh = 0; hh < 4; ++hh) {
            float ep = acc[2 * hh][i] * alv[2 * hh] + acc[2 * hh + 1][i] * alv[2 * hh + 1];
            float fp = acc[2 * hh][i] * arv[2 * hh] + acc[2 * hh + 1][i] * arv[2 * hh + 1];
#pragma unroll
            for (int d = 1; d <= 8; d <<= 1) {
                ep += __shfl_xor(ep, d, 64);
                fp += __shfl_xor(fp, d, 64);
            }
            if (ok && mr == 0) {
                el[(size_t)row * 4 + hh] = ep;
                er[(size_t)row * 4 + hh] = fp;
            }
        }
    }
}

// ---------------------------------------------------------------------------
// Fused softmax-stats + gather + (optional) prediction epilogue.
// FOUR nodes per wave: each 16-lane quarter owns one node end-to-end.
// Phase A: within a quarter, lane = head(h4=l16>>2) x edge-slot(j4=l16&3);
//   per-lane serial online (m,s) over slots, 2-round butterfly over j4.
// Phase B: the quarter processes its node's edges one at a time (4 edges in
//   flight per wave across quarters); lane l16 covers features l16*4 (head
//   hA=l16>>3) and 64+l16*4 (head hA+2). NO cross-quarter reduction.
__global__ __launch_bounds__(256) void agg_fused_kernel(
    const float* __restrict__ h, const float* __restrict__ el,
    const float* __restrict__ er, const int* __restrict__ rowp,
    const int* __restrict__ col, const float* __restrict__ bias,
    float* __restrict__ xout, const float* __restrict__ pW,
    const float* __restrict__ pb, float* __restrict__ logits,
    int N, int last)
{
    const int lane = threadIdx.x & 63;
    const int q    = lane >> 4;
    const int l16  = lane & 15;
    const int v    = blockIdx.x * 16 + (threadIdx.x >> 6) * 4 + q;
    if (v >= N) return;   // no cross-quarter shuffles below -> safe

    const int r0 = rowp[v], r1 = rowp[v + 1];
    const int deg = r1 - r0;

    // ---- Phase A: per-head online softmax stats (4 heads x 4 slots)
    const int h4 = l16 >> 2;
    const int j4 = l16 & 3;
    const float erq = er[(size_t)v * 4 + h4];

    float m_l = -INFINITY, s_l = 0.f;
    for (int jj = j4; jj < deg; jj += 4) {
        int u = col[r0 + jj];
        float e = leaky02(el[(size_t)u * 4 + h4] + erq);
        if (e > m_l) { s_l = s_l * __expf(m_l - e) + 1.f; m_l = e; }
        else         { s_l += __expf(e - m_l); }
    }
#pragma unroll
    for (int d = 1; d <= 2; d <<= 1) {
        float m2 = __shfl_xor(m_l, d, 64);
        float s2 = __shfl_xor(s_l, d, 64);
        float nm = fmaxf(m_l, m2);
        s_l = (s_l > 0.f ? s_l * __expf(m_l - nm) : 0.f)
            + (s2  > 0.f ? s2  * __expf(m2  - nm) : 0.f);
        m_l = nm;
    }
    const float is_l = 1.f / s_l;

    // ---- broadcast stats + er for this lane's two head slots
    const int hA = l16 >> 3;
    const int srcA = q * 16 + hA * 4;
    const int srcB = q * 16 + (hA + 2) * 4;
    const float mA  = __shfl(m_l,  srcA, 64);
    const float isA = __shfl(is_l, srcA, 64);
    const float erA = __shfl(erq,  srcA, 64);
    const float mB  = __shfl(m_l,  srcB, 64);
    const float isB = __shfl(is_l, srcB, 64);
    const float erB = __shfl(erq,  srcB, 64);

    // ---- Phase B: gather (quarter-wave per edge, 1 edge/iter per node)
    const int f0 = l16 * 4;
    float4 acc0 = make_float4(0.f, 0.f, 0.f, 0.f);
    float4 acc1 = make_float4(0.f, 0.f, 0.f, 0.f);

    for (int j = r0; j < r1; ++j) {
        int u = col[j];
        float eA = leaky02(el[(size_t)u * 4 + hA] + erA);
        float eB = leaky02(el[(size_t)u * 4 + 2 + hA] + erB);
        float aA = __expf(eA - mA) * isA;
        float aB = __expf(eB - mB) * isB;
        const float4 v0 = *reinterpret_cast<const float4*>(&h[(size_t)u * 128 + f0]);
        const float4 v1 = *reinterpret_cast<const float4*>(&h[(size_t)u * 128 + 64 + f0]);
        acc0.x += aA * v0.x; acc0.y += aA * v0.y;
        acc0.z += aA * v0.z; acc0.w += aA * v0.w;
        acc1.x += aB * v1.x; acc1.y += aB * v1.y;
        acc1.z += aB * v1.z; acc1.w += aB * v1.w;
    }

    if (last) {
        float4 b0 = *reinterpret_cast<const float4*>(&bias[f0]);
        float4 b1 = *reinterpret_cast<const float4*>(&bias[64 + f0]);
        float4 p0 = *reinterpret_cast<const float4*>(&pW[f0]);
        float4 p1 = *reinterpret_cast<const float4*>(&pW[64 + f0]);
        float part = (acc0.x + b0.x) * p0.x + (acc0.y + b0.y) * p0.y
                   + (acc0.z + b0.z) * p0.z + (acc0.w + b0.w) * p0.w
                   + (acc1.x + b1.x) * p1.x + (acc1.y + b1.y) * p1.y
                   + (acc1.z + b1.z) * p1.z + (acc1.w + b1.w) * p1.w;
#pragma unroll
        for (int d = 1; d <= 8; d <<= 1) part += __shfl_xor(part, d, 64);
        if (l16 == 0) logits[v] = part + pb[0];
    } else {
        float4 b0 = *reinterpret_cast<const float4*>(&bias[f0]);
        float4 b1 = *reinterpret_cast<const float4*>(&bias[64 + f0]);
        acc0.x += b0.x; acc0.y += b0.y; acc0.z += b0.z; acc0.w += b0.w;
        acc1.x += b1.x; acc1.y += b1.y; acc1.z += b1.z; acc1.w += b1.w;
        *reinterpret_cast<float4*>(&xout[(size_t)v * 128 + f0])      = acc0;
        *reinterpret_cast<float4*>(&xout[(size_t)v * 128 + 64 + f0]) = acc1;
    }
}

// ---------------------------------------------------------------------------
extern "C" void kernel_launch(void* const* d_in, const int* in_sizes, int n_in,
                              void* d_out, int out_size, void* d_ws, size_t ws_size,
                              hipStream_t stream)
{
    const float* weights = (const float*)d_in[0];
    const float* lin_W   = (const float*)d_in[1];
    const float* lin_b   = (const float*)d_in[2];
    const float* fc_W    = (const float*)d_in[3];
    const float* attn_l  = (const float*)d_in[4];
    const float* attn_r  = (const float*)d_in[5];
    const float* conv_b  = (const float*)d_in[6];
    const float* pred_W  = (const float*)d_in[7];
    const float* pred_b  = (const float*)d_in[8];
    const int*   src     = (const int*)d_in[9];
    const int*   dst     = (const int*)d_in[10];

    const int N = in_sizes[0];
    const int E = in_sizes[9];
    const int NB = (N + SCAN_TILE - 1) / SCAN_TILE;

    // workspace layout (16B-aligned float4 sections first)
    float* x   = (float*)d_ws;                   // N*128
    float* h   = x + (size_t)N * 128;            // N*128
    float* el  = h + (size_t)N * 128;            // N*4
    float* er  = el + (size_t)N * 4;             // N*4
    float* c1  = er + (size_t)N * 4;             // 128
    float* c2  = c1 + 128;                       // 128
    float* prm = c2 + 128;                       // 16
    short* Whs = (short*)(prm + 16);             // 2*16384 bf16 (layers 1,2)
    short* Wls = Whs + 2 * 16384;                // 2*16384 bf16
    int*   deg  = (int*)(Wls + 2 * 16384);       // N
    int*   rowp = deg + N;                       // N+1
    int*   cur  = rowp + (N + 1);                // N
    int*   col  = cur + N;                       // E+N
    int*   bsum = col + (E + N);                 // NB
    int*   bpre = bsum + NB;                     // NB

    // CSR build (fresh every call: ws is re-poisoned)
    deg_init_kernel<<<(N + 255) / 256, 256, 0, stream>>>(deg, N);
    deg_count_kernel<<<(E + 255) / 256, 256, 0, stream>>>(dst, deg, E);
    scanA_kernel<<<NB, 256, 0, stream>>>(deg, bsum, N);
    scanB_kernel<<<1, 1024, 0, stream>>>(bsum, bpre, rowp, NB, N);
    scanC_kernel<<<NB, 256, 0, stream>>>(deg, bpre, rowp, cur, N);
    scatter_kernel<<<(E + N + 255) / 256, 256, 0, stream>>>(src, dst, cur, col, E, N);

    // Split W for layers 1,2 into bf16 hi/lo
    wsplit_kernel<<<(2 * 16384 + 255) / 256, 256, 0, stream>>>(
        fc_W + 16384, Whs, Wls, 2 * 16384);

    // Layer 0 via rank-1 identity
    rank1_prep_kernel<<<1, 128, 0, stream>>>(lin_W, lin_b, fc_W, attn_l, attn_r,
                                             c1, c2, prm);
    rank1_apply_kernel<<<((size_t)N * 32 + 255) / 256, 256, 0, stream>>>(
        weights, c1, c2, prm, h, el, er, N);
    agg_fused_kernel<<<(N + 15) / 16, 256, 0, stream>>>(
        h, el, er, rowp, col, conv_b, x, pred_W, pred_b, (float*)d_out, N, 0);

    // Layers 1, 2 (MFMA split-bf16 gemm with fused el/er)
    for (int l = 1; l < 3; ++l) {
        gemm_mfma_kernel<<<(N + 63) / 64, 256, 0, stream>>>(
            x, Whs + (size_t)(l - 1) * 16384, Wls + (size_t)(l - 1) * 16384,
            attn_l + l * 128, attn_r + l * 128, h, el, er, N);
        agg_fused_kernel<<<(N + 15) / 16, 256, 0, stream>>>(
            h, el, er, rowp, col, conv_b + l * 128, x, pred_W, pred_b,
            (float*)d_out, N, l == 2 ? 1 : 0);
    }
}

// Round 12
// 502.603 us; speedup vs baseline: 1.3138x; 1.0101x over previous
//
#include <hip/hip_runtime.h>
#include <hip/hip_bf16.h>
#include <math.h>

// Problem constants: N=100000, E=600000, D=128, H=4, F=32, L=3

__device__ __forceinline__ float leaky02(float x) {
    return x >= 0.f ? x : 0.2f * x;
}

// bf16 helpers (round-to-nearest-even)
__device__ __forceinline__ short f2bf(float f) {
    unsigned u = __float_as_uint(f);
    unsigned r = u + 0x7FFFu + ((u >> 16) & 1u);
    return (short)(r >> 16);
}
__device__ __forceinline__ float bf2f(short s) {
    return __uint_as_float(((unsigned)(unsigned short)s) << 16);
}

typedef __attribute__((ext_vector_type(8))) short bf16x8;
typedef __attribute__((ext_vector_type(4))) float f32x4;

// ---------------------------------------------------------------------------
// CSR build
__global__ __launch_bounds__(256) void deg_init_kernel(int* __restrict__ deg, int N)
{
    int i = blockIdx.x * 256 + threadIdx.x;
    if (i < N) deg[i] = 1;  // self loop
}

__global__ __launch_bounds__(256) void deg_count_kernel(
    const int* __restrict__ dst, int* __restrict__ deg, int E)
{
    int i = blockIdx.x * 256 + threadIdx.x;
    if (i < E) atomicAdd(&deg[dst[i]], 1);
}

#define SCAN_TILE 1024

__global__ __launch_bounds__(256) void scanA_kernel(
    const int* __restrict__ deg, int* __restrict__ bsum, int N)
{
    __shared__ int ws[4];
    int b = blockIdx.x, t = threadIdx.x;
    int base = b * SCAN_TILE + t * 4;
    int s = 0;
#pragma unroll
    for (int k = 0; k < 4; ++k) {
        int i = base + k;
        if (i < N) s += deg[i];
    }
#pragma unroll
    for (int m = 32; m >= 1; m >>= 1) s += __shfl_xor(s, m, 64);
    if ((t & 63) == 0) ws[t >> 6] = s;
    __syncthreads();
    if (t == 0) bsum[b] = ws[0] + ws[1] + ws[2] + ws[3];
}

__global__ __launch_bounds__(1024) void scanB_kernel(
    int* __restrict__ bsum, int* __restrict__ bpre, int* __restrict__ rowp,
    int NB, int N)
{
    __shared__ int sh[1024];
    int t = threadIdx.x;
    int v = (t < NB) ? bsum[t] : 0;
    sh[t] = v;
    __syncthreads();
    for (int off = 1; off < 1024; off <<= 1) {
        int u = (t >= off) ? sh[t - off] : 0;
        __syncthreads();
        sh[t] += u;
        __syncthreads();
    }
    if (t < NB) bpre[t] = sh[t] - v;          // exclusive prefix
    if (t == 1023) rowp[N] = sh[1023];        // total
}

__global__ __launch_bounds__(256) void scanC_kernel(
    const int* __restrict__ deg, const int* __restrict__ bpre,
    int* __restrict__ rowp, int* __restrict__ cur, int N)
{
    __shared__ int sh[256];
    int b = blockIdx.x, t = threadIdx.x;
    int base = b * SCAN_TILE + t * 4;
    int v[4];
#pragma unroll
    for (int k = 0; k < 4; ++k) {
        int i = base + k;
        v[k] = (i < N) ? deg[i] : 0;
    }
    int tsum = v[0] + v[1] + v[2] + v[3];
    sh[t] = tsum;
    __syncthreads();
    for (int off = 1; off < 256; off <<= 1) {
        int u = (t >= off) ? sh[t - off] : 0;
        __syncthreads();
        sh[t] += u;
        __syncthreads();
    }
    int pre = bpre[b] + sh[t] - tsum;
#pragma unroll
    for (int k = 0; k < 4; ++k) {
        int i = base + k;
        if (i < N) { rowp[i] = pre; cur[i] = pre; }
        pre += v[k];
    }
}

__global__ __launch_bounds__(256) void scatter_kernel(
    const int* __restrict__ src, const int* __restrict__ dst,
    int* __restrict__ cur, int* __restrict__ col, int E, int N)
{
    int i = blockIdx.x * 256 + threadIdx.x;
    if (i < E) {
        int p = atomicAdd(&cur[dst[i]], 1);
        col[p] = src[i];
    } else if (i < E + N) {
        int v = i - E;
        int p = atomicAdd(&cur[v], 1);
        col[p] = v;  // self loop
    }
}

// ---------------------------------------------------------------------------
// Layer-0 rank-1 precompute
__global__ __launch_bounds__(128) void rank1_prep_kernel(
    const float* __restrict__ lW, const float* __restrict__ lb,
    const float* __restrict__ W0, const float* __restrict__ al,
    const float* __restrict__ ar, float* __restrict__ c1,
    float* __restrict__ c2, float* __restrict__ prm)
{
    int j = threadIdx.x;
    float s1 = 0.f, s2 = 0.f;
    for (int d = 0; d < 128; ++d) {
        float wv = W0[j * 128 + d];
        s1 += lW[d] * wv;
        s2 += lb[d] * wv;
    }
    c1[j] = s1; c2[j] = s2;
    __shared__ float sh1[128], sh2[128], sh3[128], sh4[128];
    sh1[j] = s1 * al[j]; sh2[j] = s2 * al[j];
    sh3[j] = s1 * ar[j]; sh4[j] = s2 * ar[j];
    __syncthreads();
    if (j < 4) {
        float p = 0.f, q = 0.f, r = 0.f, s = 0.f;
        for (int f = 0; f < 32; ++f) {
            p += sh1[j * 32 + f]; q += sh2[j * 32 + f];
            r += sh3[j * 32 + f]; s += sh4[j * 32 + f];
        }
        prm[j] = p; prm[4 + j] = q; prm[8 + j] = r; prm[12 + j] = s;
    }
}

// h0[n,j] = w[n]*c1[j] + c2[j]; el0[n,h] = w[n]*pl[h]+ql[h]; er0 likewise.
__global__ __launch_bounds__(256) void rank1_apply_kernel(
    const float* __restrict__ w, const float* __restrict__ c1,
    const float* __restrict__ c2, const float* __restrict__ prm,
    float* __restrict__ h, float* __restrict__ el, float* __restrict__ er, int N)
{
    int i = blockIdx.x * 256 + threadIdx.x;
    int n = i >> 5, k = i & 31;
    if (n >= N) return;
    float wn = w[n];
    float4 a = *reinterpret_cast<const float4*>(&c1[k * 4]);
    float4 b = *reinterpret_cast<const float4*>(&c2[k * 4]);
    float4 o = make_float4(wn * a.x + b.x, wn * a.y + b.y,
                           wn * a.z + b.z, wn * a.w + b.w);
    *reinterpret_cast<float4*>(&h[(size_t)n * 128 + k * 4]) = o;
    if (k == 0) {
        float4 pl = *reinterpret_cast<const float4*>(&prm[0]);
        float4 ql = *reinterpret_cast<const float4*>(&prm[4]);
        float4 pr = *reinterpret_cast<const float4*>(&prm[8]);
        float4 qr = *reinterpret_cast<const float4*>(&prm[12]);
        float4 e1 = make_float4(wn * pl.x + ql.x, wn * pl.y + ql.y,
                                wn * pl.z + ql.z, wn * pl.w + ql.w);
        float4 e2 = make_float4(wn * pr.x + qr.x, wn * pr.y + qr.y,
                                wn * pr.z + qr.z, wn * pr.w + qr.w);
        *reinterpret_cast<float4*>(&el[(size_t)n * 4]) = e1;
        *reinterpret_cast<float4*>(&er[(size_t)n * 4]) = e2;
    }
}

// ---------------------------------------------------------------------------
// Split fc_W (layers 1,2) into bf16 hi/lo. n = 2*128*128 elements.
__global__ __launch_bounds__(256) void wsplit_kernel(
    const float* __restrict__ W, short* __restrict__ Wh,
    short* __restrict__ Wl, int n)
{
    int i = blockIdx.x * 256 + threadIdx.x;
    if (i < n) {
        float f = W[i];
        short hi = f2bf(f);
        float fh = bf2f(hi);
        Wh[i] = hi;
        Wl[i] = f2bf(f - fh);
    }
}

// ---------------------------------------------------------------------------
// MFMA split-bf16 GEMM (layers 1,2): h[n,j] = sum_d leaky0.01(x[n,d])*W[j,d]
// C = Ah*Wh + Al*Wh + Ah*Wl (Al*Wl dropped, ~2^-18 relative).
// 32 ROWS PER WAVE (2 A-fragments), 128 cols; W fragments for all 8 col
// groups HOISTED into bh[8]/bl[8] arrays per K-page so 16 loads are in
// flight before the MFMA burst (fixes R11's VGPR-48 load serialization).
// Fragments: A/B = 8 K-consecutive elems/lane (direct row-major global,
// no LDS); C/D: col=lane&15, row=quad*4+reg.
__global__ __launch_bounds__(256) void gemm_mfma_kernel(
    const float* __restrict__ x, const short* __restrict__ Wh,
    const short* __restrict__ Wl, float* __restrict__ h, int N)
{
    const int lane = threadIdx.x & 63;
    const int wv   = threadIdx.x >> 6;
    const int m0   = blockIdx.x * 128 + wv * 32;  // 32 rows per wave
    const int mr   = lane & 15;
    const int quad = lane >> 4;

    int r0 = m0 + mr;      if (r0 > N - 1) r0 = N - 1;   // clamped load rows
    int r1 = m0 + 16 + mr; if (r1 > N - 1) r1 = N - 1;
    const float* xp0 = x + (size_t)r0 * 128 + quad * 8;
    const float* xp1 = x + (size_t)r1 * 128 + quad * 8;

    f32x4 acc0[8], acc1[8];
#pragma unroll
    for (int c = 0; c < 8; ++c) {
        acc0[c] = (f32x4){0.f, 0.f, 0.f, 0.f};
        acc1[c] = (f32x4){0.f, 0.f, 0.f, 0.f};
    }

#pragma unroll
    for (int kk = 0; kk < 4; ++kk) {
        // A fragments for both row-sets (leaky + split)
        float4 u0 = *reinterpret_cast<const float4*>(xp0 + kk * 32);
        float4 u1 = *reinterpret_cast<const float4*>(xp0 + kk * 32 + 4);
        float4 w0 = *reinterpret_cast<const float4*>(xp1 + kk * 32);
        float4 w1 = *reinterpret_cast<const float4*>(xp1 + kk * 32 + 4);
        float fa[8] = {u0.x, u0.y, u0.z, u0.w, u1.x, u1.y, u1.z, u1.w};
        float fb[8] = {w0.x, w0.y, w0.z, w0.w, w1.x, w1.y, w1.z, w1.w};
        union { bf16x8 v; short s[8]; } ah0, al0, ah1, al1;
#pragma unroll
        for (int j = 0; j < 8; ++j) {
            float t0 = fa[j]; t0 = t0 >= 0.f ? t0 : 0.01f * t0;
            short h0s = f2bf(t0);
            ah0.s[j] = h0s; al0.s[j] = f2bf(t0 - bf2f(h0s));
            float t1 = fb[j]; t1 = t1 >= 0.f ? t1 : 0.01f * t1;
            short h1s = f2bf(t1);
            ah1.s[j] = h1s; al1.s[j] = f2bf(t1 - bf2f(h1s));
        }

        const int kb = kk * 32 + quad * 8;
        // hoist all W fragments for this K-page (16 independent loads)
        bf16x8 bh[8], bl[8];
#pragma unroll
        for (int c = 0; c < 8; ++c) {
            const size_t wo = (size_t)(c * 16 + mr) * 128 + kb;
            bh[c] = *reinterpret_cast<const bf16x8*>(Wh + wo);
            bl[c] = *reinterpret_cast<const bf16x8*>(Wl + wo);
        }
#pragma unroll
        for (int c = 0; c < 8; ++c) {
            acc0[c] = __builtin_amdgcn_mfma_f32_16x16x32_bf16(ah0.v, bh[c], acc0[c], 0, 0, 0);
            acc0[c] = __builtin_amdgcn_mfma_f32_16x16x32_bf16(al0.v, bh[c], acc0[c], 0, 0, 0);
            acc0[c] = __builtin_amdgcn_mfma_f32_16x16x32_bf16(ah0.v, bl[c], acc0[c], 0, 0, 0);
            acc1[c] = __builtin_amdgcn_mfma_f32_16x16x32_bf16(ah1.v, bh[c], acc1[c], 0, 0, 0);
            acc1[c] = __builtin_amdgcn_mfma_f32_16x16x32_bf16(al1.v, bh[c], acc1[c], 0, 0, 0);
            acc1[c] = __builtin_amdgcn_mfma_f32_16x16x32_bf16(ah1.v, bl[c], acc1[c], 0, 0, 0);
        }
    }

    // store: D row = quad*4+i (+16 for set 1), col = c*16 + mr
#pragma unroll
    for (int i = 0; i < 4; ++i) {
        int rowA = m0 + quad * 4 + i;
        if (rowA < N) {
            float* hp = h + (size_t)rowA * 128 + mr;
#pragma unroll
            for (int c = 0; c < 8; ++c) hp[c * 16] = acc0[c][i];
        }
        int rowB = m0 + 16 + quad * 4 + i;
        if (rowB < N) {
            float* hp = h + (size_t)rowB * 128 + mr;
#pragma unroll
            for (int c = 0; c < 8; ++c) hp[c * 16] = acc1[c][i];
        }
    }
}

// ---------------------------------------------------------------------------
// el/er reduction (layers 1,2). One wave per node.
__global__ __launch_bounds__(256) void elr_kernel(
    const float* __restrict__ h, const float* __restrict__ al,
    const float* __restrict__ ar, float* __restrict__ el,
    float* __restrict__ er, int N)
{
    int node = blockIdx.x * 4 + (threadIdx.x >> 6);
    int lane = threadIdx.x & 63;
    if (node >= N) return;
    float v0 = h[(size_t)node * 128 + lane];
    float v1 = h[(size_t)node * 128 + 64 + lane];
    float sl0 = v0 * al[lane];
    float sl1 = v1 * al[64 + lane];
    float sr0 = v0 * ar[lane];
    float sr1 = v1 * ar[64 + lane];
#pragma unroll
    for (int m = 16; m >= 1; m >>= 1) {
        sl0 += __shfl_xor(sl0, m, 64);
        sl1 += __shfl_xor(sl1, m, 64);
        sr0 += __shfl_xor(sr0, m, 64);
        sr1 += __shfl_xor(sr1, m, 64);
    }
    if ((lane & 31) == 0) {
        int hb = lane >> 5;
        el[node * 4 + hb]     = sl0;
        el[node * 4 + hb + 2] = sl1;
        er[node * 4 + hb]     = sr0;
        er[node * 4 + hb + 2] = sr1;
    }
}

// ---------------------------------------------------------------------------
// Fused softmax-stats + gather + (optional) prediction epilogue.
// FOUR nodes per wave: each 16-lane quarter owns one node end-to-end.
__global__ __launch_bounds__(256) void agg_fused_kernel(
    const float* __restrict__ h, const float* __restrict__ el,
    const float* __restrict__ er, const int* __restrict__ rowp,
    const int* __restrict__ col, const float* __restrict__ bias,
    float* __restrict__ xout, const float* __restrict__ pW,
    const float* __restrict__ pb, float* __restrict__ logits,
    int N, int last)
{
    const int lane = threadIdx.x & 63;
    const int q    = lane >> 4;
    const int l16  = lane & 15;
    const int v    = blockIdx.x * 16 + (threadIdx.x >> 6) * 4 + q;
    if (v >= N) return;   // no cross-quarter shuffles below -> safe

    const int r0 = rowp[v], r1 = rowp[v + 1];
    const int deg = r1 - r0;

    // ---- Phase A: per-head online softmax stats (4 heads x 4 slots)
    const int h4 = l16 >> 2;
    const int j4 = l16 & 3;
    const float erq = er[(size_t)v * 4 + h4];

    float m_l = -INFINITY, s_l = 0.f;
    for (int jj = j4; jj < deg; jj += 4) {
        int u = col[r0 + jj];
        float e = leaky02(el[(size_t)u * 4 + h4] + erq);
        if (e > m_l) { s_l = s_l * __expf(m_l - e) + 1.f; m_l = e; }
        else         { s_l += __expf(e - m_l); }
    }
#pragma unroll
    for (int d = 1; d <= 2; d <<= 1) {
        float m2 = __shfl_xor(m_l, d, 64);
        float s2 = __shfl_xor(s_l, d, 64);
        float nm = fmaxf(m_l, m2);
        s_l = (s_l > 0.f ? s_l * __expf(m_l - nm) : 0.f)
            + (s2  > 0.f ? s2  * __expf(m2  - nm) : 0.f);
        m_l = nm;
    }
    const float is_l = 1.f / s_l;

    // ---- broadcast stats + er for this lane's two head slots
    const int hA = l16 >> 3;
    const int srcA = q * 16 + hA * 4;
    const int srcB = q * 16 + (hA + 2) * 4;
    const float mA  = __shfl(m_l,  srcA, 64);
    const float isA = __shfl(is_l, srcA, 64);
    const float erA = __shfl(erq,  srcA, 64);
    const float mB  = __shfl(m_l,  srcB, 64);
    const float isB = __shfl(is_l, srcB, 64);
    const float erB = __shfl(erq,  srcB, 64);

    // ---- Phase B: gather (quarter-wave per edge, 1 edge/iter per node)
    const int f0 = l16 * 4;
    float4 acc0 = make_float4(0.f, 0.f, 0.f, 0.f);
    float4 acc1 = make_float4(0.f, 0.f, 0.f, 0.f);

    for (int j = r0; j < r1; ++j) {
        int u = col[j];
        float eA = leaky02(el[(size_t)u * 4 + hA] + erA);
        float eB = leaky02(el[(size_t)u * 4 + 2 + hA] + erB);
        float aA = __expf(eA - mA) * isA;
        float aB = __expf(eB - mB) * isB;
        const float4 v0 = *reinterpret_cast<const float4*>(&h[(size_t)u * 128 + f0]);
        const float4 v1 = *reinterpret_cast<const float4*>(&h[(size_t)u * 128 + 64 + f0]);
        acc0.x += aA * v0.x; acc0.y += aA * v0.y;
        acc0.z += aA * v0.z; acc0.w += aA * v0.w;
        acc1.x += aB * v1.x; acc1.y += aB * v1.y;
        acc1.z += aB * v1.z; acc1.w += aB * v1.w;
    }

    if (last) {
        float4 b0 = *reinterpret_cast<const float4*>(&bias[f0]);
        float4 b1 = *reinterpret_cast<const float4*>(&bias[64 + f0]);
        float4 p0 = *reinterpret_cast<const float4*>(&pW[f0]);
        float4 p1 = *reinterpret_cast<const float4*>(&pW[64 + f0]);
        float part = (acc0.x + b0.x) * p0.x + (acc0.y + b0.y) * p0.y
                   + (acc0.z + b0.z) * p0.z + (acc0.w + b0.w) * p0.w
                   + (acc1.x + b1.x) * p1.x + (acc1.y + b1.y) * p1.y
                   + (acc1.z + b1.z) * p1.z + (acc1.w + b1.w) * p1.w;
#pragma unroll
        for (int d = 1; d <= 8; d <<= 1) part += __shfl_xor(part, d, 64);
        if (l16 == 0) logits[v] = part + pb[0];
    } else {
        float4 b0 = *reinterpret_cast<const float4*>(&bias[f0]);
        float4 b1 = *reinterpret_cast<const float4*>(&bias[64 + f0]);
        acc0.x += b0.x; acc0.y += b0.y; acc0.z += b0.z; acc0.w += b0.w;
        acc1.x += b1.x; acc1.y += b1.y; acc1.z += b1.z; acc1.w += b1.w;
        *reinterpret_cast<float4*>(&xout[(size_t)v * 128 + f0])      = acc0;
        *reinterpret_cast<float4*>(&xout[(size_t)v * 128 + 64 + f0]) = acc1;
    }
}

// ---------------------------------------------------------------------------
extern "C" void kernel_launch(void* const* d_in, const int* in_sizes, int n_in,
                              void* d_out, int out_size, void* d_ws, size_t ws_size,
                              hipStream_t stream)
{
    const float* weights = (const float*)d_in[0];
    const float* lin_W   = (const float*)d_in[1];
    const float* lin_b   = (const float*)d_in[2];
    const float* fc_W    = (const float*)d_in[3];
    const float* attn_l  = (const float*)d_in[4];
    const float* attn_r  = (const float*)d_in[5];
    const float* conv_b  = (const float*)d_in[6];
    const float* pred_W  = (const float*)d_in[7];
    const float* pred_b  = (const float*)d_in[8];
    const int*   src     = (const int*)d_in[9];
    const int*   dst     = (const int*)d_in[10];

    const int N = in_sizes[0];
    const int E = in_sizes[9];
    const int NB = (N + SCAN_TILE - 1) / SCAN_TILE;

    // workspace layout (16B-aligned float4 sections first)
    float* x   = (float*)d_ws;                   // N*128
    float* h   = x + (size_t)N * 128;            // N*128
    float* el  = h + (size_t)N * 128;            // N*4
    float* er  = el + (size_t)N * 4;             // N*4
    float* c1  = er + (size_t)N * 4;             // 128
    float* c2  = c1 + 128;                       // 128
    float* prm = c2 + 128;                       // 16
    short* Whs = (short*)(prm + 16);             // 2*16384 bf16 (layers 1,2)
    short* Wls = Whs + 2 * 16384;                // 2*16384 bf16
    int*   deg  = (int*)(Wls + 2 * 16384);       // N
    int*   rowp = deg + N;                       // N+1
    int*   cur  = rowp + (N + 1);                // N
    int*   col  = cur + N;                       // E+N
    int*   bsum = col + (E + N);                 // NB
    int*   bpre = bsum + NB;                     // NB

    // CSR build (fresh every call: ws is re-poisoned)
    deg_init_kernel<<<(N + 255) / 256, 256, 0, stream>>>(deg, N);
    deg_count_kernel<<<(E + 255) / 256, 256, 0, stream>>>(dst, deg, E);
    scanA_kernel<<<NB, 256, 0, stream>>>(deg, bsum, N);
    scanB_kernel<<<1, 1024, 0, stream>>>(bsum, bpre, rowp, NB, N);
    scanC_kernel<<<NB, 256, 0, stream>>>(deg, bpre, rowp, cur, N);
    scatter_kernel<<<(E + N + 255) / 256, 256, 0, stream>>>(src, dst, cur, col, E, N);

    // Split W for layers 1,2 into bf16 hi/lo
    wsplit_kernel<<<(2 * 16384 + 255) / 256, 256, 0, stream>>>(
        fc_W + 16384, Whs, Wls, 2 * 16384);

    // Layer 0 via rank-1 identity
    rank1_prep_kernel<<<1, 128, 0, stream>>>(lin_W, lin_b, fc_W, attn_l, attn_r,
                                             c1, c2, prm);
    rank1_apply_kernel<<<((size_t)N * 32 + 255) / 256, 256, 0, stream>>>(
        weights, c1, c2, prm, h, el, er, N);
    agg_fused_kernel<<<(N + 15) / 16, 256, 0, stream>>>(
        h, el, er, rowp, col, conv_b, x, pred_W, pred_b, (float*)d_out, N, 0);

    // Layers 1, 2 (MFMA split-bf16 gemm, 32 rows/wave)
    for (int l = 1; l < 3; ++l) {
        gemm_mfma_kernel<<<(N + 127) / 128, 256, 0, stream>>>(
            x, Whs + (size_t)(l - 1) * 16384, Wls + (size_t)(l - 1) * 16384, h, N);
        elr_kernel<<<(N + 3) / 4, 256, 0, stream>>>(
            h, attn_l + l * 128, attn_r + l * 128, el, er, N);
        agg_fused_kernel<<<(N + 15) / 16, 256, 0, stream>>>(
            h, el, er, rowp, col, conv_b + l * 128, x, pred_W, pred_b,
            (float*)d_out, N, l == 2 ? 1 : 0);
    }
}

// Round 13
// 451.505 us; speedup vs baseline: 1.4625x; 1.1132x over previous
//
#include <hip/hip_runtime.h>
#include <hip/hip_bf16.h>
#include <math.h>

// Problem constants: N=100000, E=600000, D=128, H=4, F=32, L=3

__device__ __forceinline__ float leaky02(float x) {
    return x >= 0.f ? x : 0.2f * x;
}

// bf16 helpers (round-to-nearest-even)
__device__ __forceinline__ unsigned short f2bf(float f) {
    unsigned u = __float_as_uint(f);
    unsigned r = u + 0x7FFFu + ((u >> 16) & 1u);
    return (unsigned short)(r >> 16);
}
__device__ __forceinline__ float bf2f(unsigned short s) {
    return __uint_as_float(((unsigned)s) << 16);
}

typedef __attribute__((ext_vector_type(8))) short bf16x8;
typedef __attribute__((ext_vector_type(4))) float f32x4;

// ---------------------------------------------------------------------------
// CSR build
__global__ __launch_bounds__(256) void deg_init_kernel(int* __restrict__ deg, int N)
{
    int i = blockIdx.x * 256 + threadIdx.x;
    if (i < N) deg[i] = 1;  // self loop
}

__global__ __launch_bounds__(256) void deg_count_kernel(
    const int* __restrict__ dst, int* __restrict__ deg, int E)
{
    int i = blockIdx.x * 256 + threadIdx.x;
    if (i < E) atomicAdd(&deg[dst[i]], 1);
}

#define SCAN_TILE 1024

__global__ __launch_bounds__(256) void scanA_kernel(
    const int* __restrict__ deg, int* __restrict__ bsum, int N)
{
    __shared__ int ws[4];
    int b = blockIdx.x, t = threadIdx.x;
    int base = b * SCAN_TILE + t * 4;
    int s = 0;
#pragma unroll
    for (int k = 0; k < 4; ++k) {
        int i = base + k;
        if (i < N) s += deg[i];
    }
#pragma unroll
    for (int m = 32; m >= 1; m >>= 1) s += __shfl_xor(s, m, 64);
    if ((t & 63) == 0) ws[t >> 6] = s;
    __syncthreads();
    if (t == 0) bsum[b] = ws[0] + ws[1] + ws[2] + ws[3];
}

__global__ __launch_bounds__(1024) void scanB_kernel(
    int* __restrict__ bsum, int* __restrict__ bpre, int* __restrict__ rowp,
    int NB, int N)
{
    __shared__ int sh[1024];
    int t = threadIdx.x;
    int v = (t < NB) ? bsum[t] : 0;
    sh[t] = v;
    __syncthreads();
    for (int off = 1; off < 1024; off <<= 1) {
        int u = (t >= off) ? sh[t - off] : 0;
        __syncthreads();
        sh[t] += u;
        __syncthreads();
    }
    if (t < NB) bpre[t] = sh[t] - v;          // exclusive prefix
    if (t == 1023) rowp[N] = sh[1023];        // total
}

__global__ __launch_bounds__(256) void scanC_kernel(
    const int* __restrict__ deg, const int* __restrict__ bpre,
    int* __restrict__ rowp, int* __restrict__ cur, int N)
{
    __shared__ int sh[256];
    int b = blockIdx.x, t = threadIdx.x;
    int base = b * SCAN_TILE + t * 4;
    int v[4];
#pragma unroll
    for (int k = 0; k < 4; ++k) {
        int i = base + k;
        v[k] = (i < N) ? deg[i] : 0;
    }
    int tsum = v[0] + v[1] + v[2] + v[3];
    sh[t] = tsum;
    __syncthreads();
    for (int off = 1; off < 256; off <<= 1) {
        int u = (t >= off) ? sh[t - off] : 0;
        __syncthreads();
        sh[t] += u;
        __syncthreads();
    }
    int pre = bpre[b] + sh[t] - tsum;
#pragma unroll
    for (int k = 0; k < 4; ++k) {
        int i = base + k;
        if (i < N) { rowp[i] = pre; cur[i] = pre; }
        pre += v[k];
    }
}

__global__ __launch_bounds__(256) void scatter_kernel(
    const int* __restrict__ src, const int* __restrict__ dst,
    int* __restrict__ cur, int* __restrict__ col, int E, int N)
{
    int i = blockIdx.x * 256 + threadIdx.x;
    if (i < E) {
        int p = atomicAdd(&cur[dst[i]], 1);
        col[p] = src[i];
    } else if (i < E + N) {
        int v = i - E;
        int p = atomicAdd(&cur[v], 1);
        col[p] = v;  // self loop
    }
}

// ---------------------------------------------------------------------------
// Layer-0 rank-1 precompute
__global__ __launch_bounds__(128) void rank1_prep_kernel(
    const float* __restrict__ lW, const float* __restrict__ lb,
    const float* __restrict__ W0, const float* __restrict__ al,
    const float* __restrict__ ar, float* __restrict__ c1,
    float* __restrict__ c2, float* __restrict__ prm)
{
    int j = threadIdx.x;
    float s1 = 0.f, s2 = 0.f;
    for (int d = 0; d < 128; ++d) {
        float wv = W0[j * 128 + d];
        s1 += lW[d] * wv;
        s2 += lb[d] * wv;
    }
    c1[j] = s1; c2[j] = s2;
    __shared__ float sh1[128], sh2[128], sh3[128], sh4[128];
    sh1[j] = s1 * al[j]; sh2[j] = s2 * al[j];
    sh3[j] = s1 * ar[j]; sh4[j] = s2 * ar[j];
    __syncthreads();
    if (j < 4) {
        float p = 0.f, q = 0.f, r = 0.f, s = 0.f;
        for (int f = 0; f < 32; ++f) {
            p += sh1[j * 32 + f]; q += sh2[j * 32 + f];
            r += sh3[j * 32 + f]; s += sh4[j * 32 + f];
        }
        prm[j] = p; prm[4 + j] = q; prm[8 + j] = r; prm[12 + j] = s;
    }
}

// h0 (bf16) = w[n]*c1[j] + c2[j]; el0/er0 from rank-1 params.
__global__ __launch_bounds__(256) void rank1_apply_kernel(
    const float* __restrict__ w, const float* __restrict__ c1,
    const float* __restrict__ c2, const float* __restrict__ prm,
    unsigned short* __restrict__ hb, float* __restrict__ el,
    float* __restrict__ er, int N)
{
    int i = blockIdx.x * 256 + threadIdx.x;
    int n = i >> 5, k = i & 31;
    if (n >= N) return;
    float wn = w[n];
    float4 a = *reinterpret_cast<const float4*>(&c1[k * 4]);
    float4 b = *reinterpret_cast<const float4*>(&c2[k * 4]);
    ushort4 o;
    o.x = f2bf(wn * a.x + b.x);
    o.y = f2bf(wn * a.y + b.y);
    o.z = f2bf(wn * a.z + b.z);
    o.w = f2bf(wn * a.w + b.w);
    *reinterpret_cast<ushort4*>(&hb[(size_t)n * 128 + k * 4]) = o;
    if (k == 0) {
        float4 pl = *reinterpret_cast<const float4*>(&prm[0]);
        float4 ql = *reinterpret_cast<const float4*>(&prm[4]);
        float4 pr = *reinterpret_cast<const float4*>(&prm[8]);
        float4 qr = *reinterpret_cast<const float4*>(&prm[12]);
        float4 e1 = make_float4(wn * pl.x + ql.x, wn * pl.y + ql.y,
                                wn * pl.z + ql.z, wn * pl.w + ql.w);
        float4 e2 = make_float4(wn * pr.x + qr.x, wn * pr.y + qr.y,
                                wn * pr.z + qr.z, wn * pr.w + qr.w);
        *reinterpret_cast<float4*>(&el[(size_t)n * 4]) = e1;
        *reinterpret_cast<float4*>(&er[(size_t)n * 4]) = e2;
    }
}

// ---------------------------------------------------------------------------
// Split fc_W (layers 1,2) into bf16 hi/lo. n = 2*128*128 elements.
__global__ __launch_bounds__(256) void wsplit_kernel(
    const float* __restrict__ W, short* __restrict__ Wh,
    short* __restrict__ Wl, int n)
{
    int i = blockIdx.x * 256 + threadIdx.x;
    if (i < n) {
        float f = W[i];
        unsigned short hi = f2bf(f);
        float fh = bf2f(hi);
        Wh[i] = (short)hi;
        Wl[i] = (short)f2bf(f - fh);
    }
}

// ---------------------------------------------------------------------------
// MFMA split-bf16 GEMM (layers 1,2): h[n,j] = sum_d leaky0.01(x[n,d])*W[j,d]
// C = Ah*Wh + Al*Wh + Ah*Wl. 32 rows/wave, W fragments hoisted (R12).
// Output h stored BF16 (consumer paths are elr + agg gather).
__global__ __launch_bounds__(256) void gemm_mfma_kernel(
    const float* __restrict__ x, const short* __restrict__ Wh,
    const short* __restrict__ Wl, unsigned short* __restrict__ hb, int N)
{
    const int lane = threadIdx.x & 63;
    const int wv   = threadIdx.x >> 6;
    const int m0   = blockIdx.x * 128 + wv * 32;  // 32 rows per wave
    const int mr   = lane & 15;
    const int quad = lane >> 4;

    int r0 = m0 + mr;      if (r0 > N - 1) r0 = N - 1;   // clamped load rows
    int r1 = m0 + 16 + mr; if (r1 > N - 1) r1 = N - 1;
    const float* xp0 = x + (size_t)r0 * 128 + quad * 8;
    const float* xp1 = x + (size_t)r1 * 128 + quad * 8;

    f32x4 acc0[8], acc1[8];
#pragma unroll
    for (int c = 0; c < 8; ++c) {
        acc0[c] = (f32x4){0.f, 0.f, 0.f, 0.f};
        acc1[c] = (f32x4){0.f, 0.f, 0.f, 0.f};
    }

#pragma unroll
    for (int kk = 0; kk < 4; ++kk) {
        float4 u0 = *reinterpret_cast<const float4*>(xp0 + kk * 32);
        float4 u1 = *reinterpret_cast<const float4*>(xp0 + kk * 32 + 4);
        float4 w0 = *reinterpret_cast<const float4*>(xp1 + kk * 32);
        float4 w1 = *reinterpret_cast<const float4*>(xp1 + kk * 32 + 4);
        float fa[8] = {u0.x, u0.y, u0.z, u0.w, u1.x, u1.y, u1.z, u1.w};
        float fb[8] = {w0.x, w0.y, w0.z, w0.w, w1.x, w1.y, w1.z, w1.w};
        union { bf16x8 v; short s[8]; } ah0, al0, ah1, al1;
#pragma unroll
        for (int j = 0; j < 8; ++j) {
            float t0 = fa[j]; t0 = t0 >= 0.f ? t0 : 0.01f * t0;
            unsigned short h0s = f2bf(t0);
            ah0.s[j] = (short)h0s; al0.s[j] = (short)f2bf(t0 - bf2f(h0s));
            float t1 = fb[j]; t1 = t1 >= 0.f ? t1 : 0.01f * t1;
            unsigned short h1s = f2bf(t1);
            ah1.s[j] = (short)h1s; al1.s[j] = (short)f2bf(t1 - bf2f(h1s));
        }

        const int kb = kk * 32 + quad * 8;
        bf16x8 bh[8], bl[8];
#pragma unroll
        for (int c = 0; c < 8; ++c) {
            const size_t wo = (size_t)(c * 16 + mr) * 128 + kb;
            bh[c] = *reinterpret_cast<const bf16x8*>(Wh + wo);
            bl[c] = *reinterpret_cast<const bf16x8*>(Wl + wo);
        }
#pragma unroll
        for (int c = 0; c < 8; ++c) {
            acc0[c] = __builtin_amdgcn_mfma_f32_16x16x32_bf16(ah0.v, bh[c], acc0[c], 0, 0, 0);
            acc0[c] = __builtin_amdgcn_mfma_f32_16x16x32_bf16(al0.v, bh[c], acc0[c], 0, 0, 0);
            acc0[c] = __builtin_amdgcn_mfma_f32_16x16x32_bf16(ah0.v, bl[c], acc0[c], 0, 0, 0);
            acc1[c] = __builtin_amdgcn_mfma_f32_16x16x32_bf16(ah1.v, bh[c], acc1[c], 0, 0, 0);
            acc1[c] = __builtin_amdgcn_mfma_f32_16x16x32_bf16(al1.v, bh[c], acc1[c], 0, 0, 0);
            acc1[c] = __builtin_amdgcn_mfma_f32_16x16x32_bf16(ah1.v, bl[c], acc1[c], 0, 0, 0);
        }
    }

    // store (bf16): D row = quad*4+i (+16 for set 1), col = c*16 + mr
#pragma unroll
    for (int i = 0; i < 4; ++i) {
        int rowA = m0 + quad * 4 + i;
        if (rowA < N) {
            unsigned short* hp = hb + (size_t)rowA * 128 + mr;
#pragma unroll
            for (int c = 0; c < 8; ++c) hp[c * 16] = f2bf(acc0[c][i]);
        }
        int rowB = m0 + 16 + quad * 4 + i;
        if (rowB < N) {
            unsigned short* hp = hb + (size_t)rowB * 128 + mr;
#pragma unroll
            for (int c = 0; c < 8; ++c) hp[c * 16] = f2bf(acc1[c][i]);
        }
    }
}

// ---------------------------------------------------------------------------
// el/er reduction (layers 1,2), bf16 h input. One wave per node.
__global__ __launch_bounds__(256) void elr_kernel(
    const unsigned short* __restrict__ hb, const float* __restrict__ al,
    const float* __restrict__ ar, float* __restrict__ el,
    float* __restrict__ er, int N)
{
    int node = blockIdx.x * 4 + (threadIdx.x >> 6);
    int lane = threadIdx.x & 63;
    if (node >= N) return;
    float v0 = bf2f(hb[(size_t)node * 128 + lane]);
    float v1 = bf2f(hb[(size_t)node * 128 + 64 + lane]);
    float sl0 = v0 * al[lane];
    float sl1 = v1 * al[64 + lane];
    float sr0 = v0 * ar[lane];
    float sr1 = v1 * ar[64 + lane];
#pragma unroll
    for (int m = 16; m >= 1; m >>= 1) {
        sl0 += __shfl_xor(sl0, m, 64);
        sl1 += __shfl_xor(sl1, m, 64);
        sr0 += __shfl_xor(sr0, m, 64);
        sr1 += __shfl_xor(sr1, m, 64);
    }
    if ((lane & 31) == 0) {
        int hb2 = lane >> 5;
        el[node * 4 + hb2]     = sl0;
        el[node * 4 + hb2 + 2] = sl1;
        er[node * 4 + hb2]     = sr0;
        er[node * 4 + hb2 + 2] = sr1;
    }
}

// ---------------------------------------------------------------------------
// Fused softmax-stats + gather + (optional) prediction epilogue.
// FOUR nodes per wave: each 16-lane quarter owns one node end-to-end.
// h gathered in BF16 (256 B/row) — halves the random-gather traffic.
__global__ __launch_bounds__(256) void agg_fused_kernel(
    const unsigned short* __restrict__ hb, const float* __restrict__ el,
    const float* __restrict__ er, const int* __restrict__ rowp,
    const int* __restrict__ col, const float* __restrict__ bias,
    float* __restrict__ xout, const float* __restrict__ pW,
    const float* __restrict__ pb, float* __restrict__ logits,
    int N, int last)
{
    const int lane = threadIdx.x & 63;
    const int q    = lane >> 4;
    const int l16  = lane & 15;
    const int v    = blockIdx.x * 16 + (threadIdx.x >> 6) * 4 + q;
    if (v >= N) return;   // no cross-quarter shuffles below -> safe

    const int r0 = rowp[v], r1 = rowp[v + 1];
    const int deg = r1 - r0;

    // ---- Phase A: per-head online softmax stats (4 heads x 4 slots)
    const int h4 = l16 >> 2;
    const int j4 = l16 & 3;
    const float erq = er[(size_t)v * 4 + h4];

    float m_l = -INFINITY, s_l = 0.f;
    for (int jj = j4; jj < deg; jj += 4) {
        int u = col[r0 + jj];
        float e = leaky02(el[(size_t)u * 4 + h4] + erq);
        if (e > m_l) { s_l = s_l * __expf(m_l - e) + 1.f; m_l = e; }
        else         { s_l += __expf(e - m_l); }
    }
#pragma unroll
    for (int d = 1; d <= 2; d <<= 1) {
        float m2 = __shfl_xor(m_l, d, 64);
        float s2 = __shfl_xor(s_l, d, 64);
        float nm = fmaxf(m_l, m2);
        s_l = (s_l > 0.f ? s_l * __expf(m_l - nm) : 0.f)
            + (s2  > 0.f ? s2  * __expf(m2  - nm) : 0.f);
        m_l = nm;
    }
    const float is_l = 1.f / s_l;

    // ---- broadcast stats + er for this lane's two head slots
    const int hA = l16 >> 3;
    const int srcA = q * 16 + hA * 4;
    const int srcB = q * 16 + (hA + 2) * 4;
    const float mA  = __shfl(m_l,  srcA, 64);
    const float isA = __shfl(is_l, srcA, 64);
    const float erA = __shfl(erq,  srcA, 64);
    const float mB  = __shfl(m_l,  srcB, 64);
    const float isB = __shfl(is_l, srcB, 64);
    const float erB = __shfl(erq,  srcB, 64);

    // ---- Phase B: gather (quarter-wave per edge, 1 edge/iter per node)
    const int f0 = l16 * 4;
    float4 acc0 = make_float4(0.f, 0.f, 0.f, 0.f);
    float4 acc1 = make_float4(0.f, 0.f, 0.f, 0.f);

    for (int j = r0; j < r1; ++j) {
        int u = col[j];
        float eA = leaky02(el[(size_t)u * 4 + hA] + erA);
        float eB = leaky02(el[(size_t)u * 4 + 2 + hA] + erB);
        float aA = __expf(eA - mA) * isA;
        float aB = __expf(eB - mB) * isB;
        const ushort4 u0 = *reinterpret_cast<const ushort4*>(&hb[(size_t)u * 128 + f0]);
        const ushort4 u1 = *reinterpret_cast<const ushort4*>(&hb[(size_t)u * 128 + 64 + f0]);
        acc0.x += aA * bf2f(u0.x); acc0.y += aA * bf2f(u0.y);
        acc0.z += aA * bf2f(u0.z); acc0.w += aA * bf2f(u0.w);
        acc1.x += aB * bf2f(u1.x); acc1.y += aB * bf2f(u1.y);
        acc1.z += aB * bf2f(u1.z); acc1.w += aB * bf2f(u1.w);
    }

    if (last) {
        float4 b0 = *reinterpret_cast<const float4*>(&bias[f0]);
        float4 b1 = *reinterpret_cast<const float4*>(&bias[64 + f0]);
        float4 p0 = *reinterpret_cast<const float4*>(&pW[f0]);
        float4 p1 = *reinterpret_cast<const float4*>(&pW[64 + f0]);
        float part = (acc0.x + b0.x) * p0.x + (acc0.y + b0.y) * p0.y
                   + (acc0.z + b0.z) * p0.z + (acc0.w + b0.w) * p0.w
                   + (acc1.x + b1.x) * p1.x + (acc1.y + b1.y) * p1.y
                   + (acc1.z + b1.z) * p1.z + (acc1.w + b1.w) * p1.w;
#pragma unroll
        for (int d = 1; d <= 8; d <<= 1) part += __shfl_xor(part, d, 64);
        if (l16 == 0) logits[v] = part + pb[0];
    } else {
        float4 b0 = *reinterpret_cast<const float4*>(&bias[f0]);
        float4 b1 = *reinterpret_cast<const float4*>(&bias[64 + f0]);
        acc0.x += b0.x; acc0.y += b0.y; acc0.z += b0.z; acc0.w += b0.w;
        acc1.x += b1.x; acc1.y += b1.y; acc1.z += b1.z; acc1.w += b1.w;
        *reinterpret_cast<float4*>(&xout[(size_t)v * 128 + f0])      = acc0;
        *reinterpret_cast<float4*>(&xout[(size_t)v * 128 + 64 + f0]) = acc1;
    }
}

// ---------------------------------------------------------------------------
extern "C" void kernel_launch(void* const* d_in, const int* in_sizes, int n_in,
                              void* d_out, int out_size, void* d_ws, size_t ws_size,
                              hipStream_t stream)
{
    const float* weights = (const float*)d_in[0];
    const float* lin_W   = (const float*)d_in[1];
    const float* lin_b   = (const float*)d_in[2];
    const float* fc_W    = (const float*)d_in[3];
    const float* attn_l  = (const float*)d_in[4];
    const float* attn_r  = (const float*)d_in[5];
    const float* conv_b  = (const float*)d_in[6];
    const float* pred_W  = (const float*)d_in[7];
    const float* pred_b  = (const float*)d_in[8];
    const int*   src     = (const int*)d_in[9];
    const int*   dst     = (const int*)d_in[10];

    const int N = in_sizes[0];
    const int E = in_sizes[9];
    const int NB = (N + SCAN_TILE - 1) / SCAN_TILE;

    // workspace layout (16B-aligned sections)
    float*          x  = (float*)d_ws;                    // N*128 f32
    unsigned short* hb = (unsigned short*)(x + (size_t)N * 128);  // N*128 bf16
    float* el  = (float*)(hb + (size_t)N * 128);          // N*4
    float* er  = el + (size_t)N * 4;                      // N*4
    float* c1  = er + (size_t)N * 4;                      // 128
    float* c2  = c1 + 128;                                // 128
    float* prm = c2 + 128;                                // 16
    short* Whs = (short*)(prm + 16);                      // 2*16384 bf16
    short* Wls = Whs + 2 * 16384;                         // 2*16384 bf16
    int*   deg  = (int*)(Wls + 2 * 16384);                // N
    int*   rowp = deg + N;                                // N+1
    int*   cur  = rowp + (N + 1);                         // N
    int*   col  = cur + N;                                // E+N
    int*   bsum = col + (E + N);                          // NB
    int*   bpre = bsum + NB;                              // NB

    // CSR build (fresh every call: ws is re-poisoned)
    deg_init_kernel<<<(N + 255) / 256, 256, 0, stream>>>(deg, N);
    deg_count_kernel<<<(E + 255) / 256, 256, 0, stream>>>(dst, deg, E);
    scanA_kernel<<<NB, 256, 0, stream>>>(deg, bsum, N);
    scanB_kernel<<<1, 1024, 0, stream>>>(bsum, bpre, rowp, NB, N);
    scanC_kernel<<<NB, 256, 0, stream>>>(deg, bpre, rowp, cur, N);
    scatter_kernel<<<(E + N + 255) / 256, 256, 0, stream>>>(src, dst, cur, col, E, N);

    // Split W for layers 1,2 into bf16 hi/lo
    wsplit_kernel<<<(2 * 16384 + 255) / 256, 256, 0, stream>>>(
        fc_W + 16384, Whs, Wls, 2 * 16384);

    // Layer 0 via rank-1 identity
    rank1_prep_kernel<<<1, 128, 0, stream>>>(lin_W, lin_b, fc_W, attn_l, attn_r,
                                             c1, c2, prm);
    rank1_apply_kernel<<<((size_t)N * 32 + 255) / 256, 256, 0, stream>>>(
        weights, c1, c2, prm, hb, el, er, N);
    agg_fused_kernel<<<(N + 15) / 16, 256, 0, stream>>>(
        hb, el, er, rowp, col, conv_b, x, pred_W, pred_b, (float*)d_out, N, 0);

    // Layers 1, 2 (MFMA split-bf16 gemm, 32 rows/wave, bf16 h out)
    for (int l = 1; l < 3; ++l) {
        gemm_mfma_kernel<<<(N + 127) / 128, 256, 0, stream>>>(
            x, Whs + (size_t)(l - 1) * 16384, Wls + (size_t)(l - 1) * 16384, hb, N);
        elr_kernel<<<(N + 3) / 4, 256, 0, stream>>>(
            hb, attn_l + l * 128, attn_r + l * 128, el, er, N);
        agg_fused_kernel<<<(N + 15) / 16, 256, 0, stream>>>(
            hb, el, er, rowp, col, conv_b + l * 128, x, pred_W, pred_b,
            (float*)d_out, N, l == 2 ? 1 : 0);
    }
}

// Round 14
// 443.086 us; speedup vs baseline: 1.4903x; 1.0190x over previous
//
#include <hip/hip_runtime.h>
#include <hip/hip_bf16.h>
#include <math.h>

// Problem constants: N=100000, E=600000, D=128, H=4, F=32, L=3

__device__ __forceinline__ float leaky02(float x) {
    return x >= 0.f ? x : 0.2f * x;
}
__device__ __forceinline__ float leaky01(float x) {
    return x >= 0.f ? x : 0.01f * x;
}

// bf16 helpers (round-to-nearest-even)
__device__ __forceinline__ unsigned short f2bf(float f) {
    unsigned u = __float_as_uint(f);
    unsigned r = u + 0x7FFFu + ((u >> 16) & 1u);
    return (unsigned short)(r >> 16);
}
__device__ __forceinline__ float bf2f(unsigned short s) {
    return __uint_as_float(((unsigned)s) << 16);
}

typedef __attribute__((ext_vector_type(8))) short bf16x8;
typedef __attribute__((ext_vector_type(4))) float f32x4;

// ---------------------------------------------------------------------------
// CSR build
__global__ __launch_bounds__(256) void deg_init_kernel(int* __restrict__ deg, int N)
{
    int i = blockIdx.x * 256 + threadIdx.x;
    if (i < N) deg[i] = 1;  // self loop
}

__global__ __launch_bounds__(256) void deg_count_kernel(
    const int* __restrict__ dst, int* __restrict__ deg, int E)
{
    int i = blockIdx.x * 256 + threadIdx.x;
    if (i < E) atomicAdd(&deg[dst[i]], 1);
}

#define SCAN_TILE 1024

__global__ __launch_bounds__(256) void scanA_kernel(
    const int* __restrict__ deg, int* __restrict__ bsum, int N)
{
    __shared__ int ws[4];
    int b = blockIdx.x, t = threadIdx.x;
    int base = b * SCAN_TILE + t * 4;
    int s = 0;
#pragma unroll
    for (int k = 0; k < 4; ++k) {
        int i = base + k;
        if (i < N) s += deg[i];
    }
#pragma unroll
    for (int m = 32; m >= 1; m >>= 1) s += __shfl_xor(s, m, 64);
    if ((t & 63) == 0) ws[t >> 6] = s;
    __syncthreads();
    if (t == 0) bsum[b] = ws[0] + ws[1] + ws[2] + ws[3];
}

__global__ __launch_bounds__(1024) void scanB_kernel(
    int* __restrict__ bsum, int* __restrict__ bpre, int* __restrict__ rowp,
    int NB, int N)
{
    __shared__ int sh[1024];
    int t = threadIdx.x;
    int v = (t < NB) ? bsum[t] : 0;
    sh[t] = v;
    __syncthreads();
    for (int off = 1; off < 1024; off <<= 1) {
        int u = (t >= off) ? sh[t - off] : 0;
        __syncthreads();
        sh[t] += u;
        __syncthreads();
    }
    if (t < NB) bpre[t] = sh[t] - v;          // exclusive prefix
    if (t == 1023) rowp[N] = sh[1023];        // total
}

__global__ __launch_bounds__(256) void scanC_kernel(
    const int* __restrict__ deg, const int* __restrict__ bpre,
    int* __restrict__ rowp, int* __restrict__ cur, int N)
{
    __shared__ int sh[256];
    int b = blockIdx.x, t = threadIdx.x;
    int base = b * SCAN_TILE + t * 4;
    int v[4];
#pragma unroll
    for (int k = 0; k < 4; ++k) {
        int i = base + k;
        v[k] = (i < N) ? deg[i] : 0;
    }
    int tsum = v[0] + v[1] + v[2] + v[3];
    sh[t] = tsum;
    __syncthreads();
    for (int off = 1; off < 256; off <<= 1) {
        int u = (t >= off) ? sh[t - off] : 0;
        __syncthreads();
        sh[t] += u;
        __syncthreads();
    }
    int pre = bpre[b] + sh[t] - tsum;
#pragma unroll
    for (int k = 0; k < 4; ++k) {
        int i = base + k;
        if (i < N) { rowp[i] = pre; cur[i] = pre; }
        pre += v[k];
    }
}

__global__ __launch_bounds__(256) void scatter_kernel(
    const int* __restrict__ src, const int* __restrict__ dst,
    int* __restrict__ cur, int* __restrict__ col, int E, int N)
{
    int i = blockIdx.x * 256 + threadIdx.x;
    if (i < E) {
        int p = atomicAdd(&cur[dst[i]], 1);
        col[p] = src[i];
    } else if (i < E + N) {
        int v = i - E;
        int p = atomicAdd(&cur[v], 1);
        col[p] = v;  // self loop
    }
}

// ---------------------------------------------------------------------------
// Layer-0 rank-1 precompute
__global__ __launch_bounds__(128) void rank1_prep_kernel(
    const float* __restrict__ lW, const float* __restrict__ lb,
    const float* __restrict__ W0, const float* __restrict__ al,
    const float* __restrict__ ar, float* __restrict__ c1,
    float* __restrict__ c2, float* __restrict__ prm)
{
    int j = threadIdx.x;
    float s1 = 0.f, s2 = 0.f;
    for (int d = 0; d < 128; ++d) {
        float wv = W0[j * 128 + d];
        s1 += lW[d] * wv;
        s2 += lb[d] * wv;
    }
    c1[j] = s1; c2[j] = s2;
    __shared__ float sh1[128], sh2[128], sh3[128], sh4[128];
    sh1[j] = s1 * al[j]; sh2[j] = s2 * al[j];
    sh3[j] = s1 * ar[j]; sh4[j] = s2 * ar[j];
    __syncthreads();
    if (j < 4) {
        float p = 0.f, q = 0.f, r = 0.f, s = 0.f;
        for (int f = 0; f < 32; ++f) {
            p += sh1[j * 32 + f]; q += sh2[j * 32 + f];
            r += sh3[j * 32 + f]; s += sh4[j * 32 + f];
        }
        prm[j] = p; prm[4 + j] = q; prm[8 + j] = r; prm[12 + j] = s;
    }
}

// h0 (bf16) = w[n]*c1[j] + c2[j]; el0/er0 from rank-1 params.
__global__ __launch_bounds__(256) void rank1_apply_kernel(
    const float* __restrict__ w, const float* __restrict__ c1,
    const float* __restrict__ c2, const float* __restrict__ prm,
    unsigned short* __restrict__ hb, float* __restrict__ el,
    float* __restrict__ er, int N)
{
    int i = blockIdx.x * 256 + threadIdx.x;
    int n = i >> 5, k = i & 31;
    if (n >= N) return;
    float wn = w[n];
    float4 a = *reinterpret_cast<const float4*>(&c1[k * 4]);
    float4 b = *reinterpret_cast<const float4*>(&c2[k * 4]);
    ushort4 o;
    o.x = f2bf(wn * a.x + b.x);
    o.y = f2bf(wn * a.y + b.y);
    o.z = f2bf(wn * a.z + b.z);
    o.w = f2bf(wn * a.w + b.w);
    *reinterpret_cast<ushort4*>(&hb[(size_t)n * 128 + k * 4]) = o;
    if (k == 0) {
        float4 pl = *reinterpret_cast<const float4*>(&prm[0]);
        float4 ql = *reinterpret_cast<const float4*>(&prm[4]);
        float4 pr = *reinterpret_cast<const float4*>(&prm[8]);
        float4 qr = *reinterpret_cast<const float4*>(&prm[12]);
        float4 e1 = make_float4(wn * pl.x + ql.x, wn * pl.y + ql.y,
                                wn * pl.z + ql.z, wn * pl.w + ql.w);
        float4 e2 = make_float4(wn * pr.x + qr.x, wn * pr.y + qr.y,
                                wn * pr.z + qr.z, wn * pr.w + qr.w);
        *reinterpret_cast<float4*>(&el[(size_t)n * 4]) = e1;
        *reinterpret_cast<float4*>(&er[(size_t)n * 4]) = e2;
    }
}

// ---------------------------------------------------------------------------
// Split fc_W (layers 1,2) into bf16 hi/lo. n = 2*128*128 elements.
__global__ __launch_bounds__(256) void wsplit_kernel(
    const float* __restrict__ W, short* __restrict__ Wh,
    short* __restrict__ Wl, int n)
{
    int i = blockIdx.x * 256 + threadIdx.x;
    if (i < n) {
        float f = W[i];
        unsigned short hi = f2bf(f);
        float fh = bf2f(hi);
        Wh[i] = (short)hi;
        Wl[i] = (short)f2bf(f - fh);
    }
}

// ---------------------------------------------------------------------------
// MFMA bf16 GEMM (layers 1,2): h[n,j] = sum_d x_bf16[n,d]*W[j,d]
// x is PRE-ACTIVATED bf16 (leaky applied at the producer) -> A fragment is a
// direct bf16x8 load, zero conversion VALU. C = A*Wh + A*Wl (W split kept:
// only the already-present x-rounding error remains).
// 32 rows/wave, 128 cols; W fragments hoisted (16 loads in flight, R12 fix).
// Fragments: A/B = 8 K-consecutive elems/lane; C/D: col=lane&15, row=quad*4+reg.
__global__ __launch_bounds__(256) void gemm_mfma_kernel(
    const unsigned short* __restrict__ xb, const short* __restrict__ Wh,
    const short* __restrict__ Wl, unsigned short* __restrict__ hb, int N)
{
    const int lane = threadIdx.x & 63;
    const int wv   = threadIdx.x >> 6;
    const int m0   = blockIdx.x * 128 + wv * 32;  // 32 rows per wave
    const int mr   = lane & 15;
    const int quad = lane >> 4;

    int r0 = m0 + mr;      if (r0 > N - 1) r0 = N - 1;   // clamped load rows
    int r1 = m0 + 16 + mr; if (r1 > N - 1) r1 = N - 1;
    const unsigned short* xp0 = xb + (size_t)r0 * 128 + quad * 8;
    const unsigned short* xp1 = xb + (size_t)r1 * 128 + quad * 8;

    f32x4 acc0[8], acc1[8];
#pragma unroll
    for (int c = 0; c < 8; ++c) {
        acc0[c] = (f32x4){0.f, 0.f, 0.f, 0.f};
        acc1[c] = (f32x4){0.f, 0.f, 0.f, 0.f};
    }

#pragma unroll
    for (int kk = 0; kk < 4; ++kk) {
        // A fragments: direct bf16 loads (pre-activated x)
        bf16x8 a0 = *reinterpret_cast<const bf16x8*>(xp0 + kk * 32);
        bf16x8 a1 = *reinterpret_cast<const bf16x8*>(xp1 + kk * 32);

        const int kb = kk * 32 + quad * 8;
        // hoist all W fragments for this K-page (16 independent loads)
        bf16x8 bh[8], bl[8];
#pragma unroll
        for (int c = 0; c < 8; ++c) {
            const size_t wo = (size_t)(c * 16 + mr) * 128 + kb;
            bh[c] = *reinterpret_cast<const bf16x8*>(Wh + wo);
            bl[c] = *reinterpret_cast<const bf16x8*>(Wl + wo);
        }
#pragma unroll
        for (int c = 0; c < 8; ++c) {
            acc0[c] = __builtin_amdgcn_mfma_f32_16x16x32_bf16(a0, bh[c], acc0[c], 0, 0, 0);
            acc0[c] = __builtin_amdgcn_mfma_f32_16x16x32_bf16(a0, bl[c], acc0[c], 0, 0, 0);
            acc1[c] = __builtin_amdgcn_mfma_f32_16x16x32_bf16(a1, bh[c], acc1[c], 0, 0, 0);
            acc1[c] = __builtin_amdgcn_mfma_f32_16x16x32_bf16(a1, bl[c], acc1[c], 0, 0, 0);
        }
    }

    // store (bf16): D row = quad*4+i (+16 for set 1), col = c*16 + mr
#pragma unroll
    for (int i = 0; i < 4; ++i) {
        int rowA = m0 + quad * 4 + i;
        if (rowA < N) {
            unsigned short* hp = hb + (size_t)rowA * 128 + mr;
#pragma unroll
            for (int c = 0; c < 8; ++c) hp[c * 16] = f2bf(acc0[c][i]);
        }
        int rowB = m0 + 16 + quad * 4 + i;
        if (rowB < N) {
            unsigned short* hp = hb + (size_t)rowB * 128 + mr;
#pragma unroll
            for (int c = 0; c < 8; ++c) hp[c * 16] = f2bf(acc1[c][i]);
        }
    }
}

// ---------------------------------------------------------------------------
// el/er reduction (layers 1,2), bf16 h input. One wave per node.
__global__ __launch_bounds__(256) void elr_kernel(
    const unsigned short* __restrict__ hb, const float* __restrict__ al,
    const float* __restrict__ ar, float* __restrict__ el,
    float* __restrict__ er, int N)
{
    int node = blockIdx.x * 4 + (threadIdx.x >> 6);
    int lane = threadIdx.x & 63;
    if (node >= N) return;
    float v0 = bf2f(hb[(size_t)node * 128 + lane]);
    float v1 = bf2f(hb[(size_t)node * 128 + 64 + lane]);
    float sl0 = v0 * al[lane];
    float sl1 = v1 * al[64 + lane];
    float sr0 = v0 * ar[lane];
    float sr1 = v1 * ar[64 + lane];
#pragma unroll
    for (int m = 16; m >= 1; m >>= 1) {
        sl0 += __shfl_xor(sl0, m, 64);
        sl1 += __shfl_xor(sl1, m, 64);
        sr0 += __shfl_xor(sr0, m, 64);
        sr1 += __shfl_xor(sr1, m, 64);
    }
    if ((lane & 31) == 0) {
        int hb2 = lane >> 5;
        el[node * 4 + hb2]     = sl0;
        el[node * 4 + hb2 + 2] = sl1;
        er[node * 4 + hb2]     = sr0;
        er[node * 4 + hb2 + 2] = sr1;
    }
}

// ---------------------------------------------------------------------------
// Fused softmax-stats + gather + epilogue.
// FOUR nodes per wave: each 16-lane quarter owns one node end-to-end.
// h gathered in BF16. last=0: store x = bf16(leaky01(acc+bias)) — the next
// gemm consumes pre-activated bf16 directly. last=1: fused prediction.
__global__ __launch_bounds__(256) void agg_fused_kernel(
    const unsigned short* __restrict__ hb, const float* __restrict__ el,
    const float* __restrict__ er, const int* __restrict__ rowp,
    const int* __restrict__ col, const float* __restrict__ bias,
    unsigned short* __restrict__ xout, const float* __restrict__ pW,
    const float* __restrict__ pb, float* __restrict__ logits,
    int N, int last)
{
    const int lane = threadIdx.x & 63;
    const int q    = lane >> 4;
    const int l16  = lane & 15;
    const int v    = blockIdx.x * 16 + (threadIdx.x >> 6) * 4 + q;
    if (v >= N) return;   // no cross-quarter shuffles below -> safe

    const int r0 = rowp[v], r1 = rowp[v + 1];
    const int deg = r1 - r0;

    // ---- Phase A: per-head online softmax stats (4 heads x 4 slots)
    const int h4 = l16 >> 2;
    const int j4 = l16 & 3;
    const float erq = er[(size_t)v * 4 + h4];

    float m_l = -INFINITY, s_l = 0.f;
    for (int jj = j4; jj < deg; jj += 4) {
        int u = col[r0 + jj];
        float e = leaky02(el[(size_t)u * 4 + h4] + erq);
        if (e > m_l) { s_l = s_l * __expf(m_l - e) + 1.f; m_l = e; }
        else         { s_l += __expf(e - m_l); }
    }
#pragma unroll
    for (int d = 1; d <= 2; d <<= 1) {
        float m2 = __shfl_xor(m_l, d, 64);
        float s2 = __shfl_xor(s_l, d, 64);
        float nm = fmaxf(m_l, m2);
        s_l = (s_l > 0.f ? s_l * __expf(m_l - nm) : 0.f)
            + (s2  > 0.f ? s2  * __expf(m2  - nm) : 0.f);
        m_l = nm;
    }
    const float is_l = 1.f / s_l;

    // ---- broadcast stats + er for this lane's two head slots
    const int hA = l16 >> 3;
    const int srcA = q * 16 + hA * 4;
    const int srcB = q * 16 + (hA + 2) * 4;
    const float mA  = __shfl(m_l,  srcA, 64);
    const float isA = __shfl(is_l, srcA, 64);
    const float erA = __shfl(erq,  srcA, 64);
    const float mB  = __shfl(m_l,  srcB, 64);
    const float isB = __shfl(is_l, srcB, 64);
    const float erB = __shfl(erq,  srcB, 64);

    // ---- Phase B: gather (quarter-wave per edge, 1 edge/iter per node)
    const int f0 = l16 * 4;
    float4 acc0 = make_float4(0.f, 0.f, 0.f, 0.f);
    float4 acc1 = make_float4(0.f, 0.f, 0.f, 0.f);

    for (int j = r0; j < r1; ++j) {
        int u = col[j];
        float eA = leaky02(el[(size_t)u * 4 + hA] + erA);
        float eB = leaky02(el[(size_t)u * 4 + 2 + hA] + erB);
        float aA = __expf(eA - mA) * isA;
        float aB = __expf(eB - mB) * isB;
        const ushort4 u0 = *reinterpret_cast<const ushort4*>(&hb[(size_t)u * 128 + f0]);
        const ushort4 u1 = *reinterpret_cast<const ushort4*>(&hb[(size_t)u * 128 + 64 + f0]);
        acc0.x += aA * bf2f(u0.x); acc0.y += aA * bf2f(u0.y);
        acc0.z += aA * bf2f(u0.z); acc0.w += aA * bf2f(u0.w);
        acc1.x += aB * bf2f(u1.x); acc1.y += aB * bf2f(u1.y);
        acc1.z += aB * bf2f(u1.z); acc1.w += aB * bf2f(u1.w);
    }

    float4 b0 = *reinterpret_cast<const float4*>(&bias[f0]);
    float4 b1 = *reinterpret_cast<const float4*>(&bias[64 + f0]);
    if (last) {
        float4 p0 = *reinterpret_cast<const float4*>(&pW[f0]);
        float4 p1 = *reinterpret_cast<const float4*>(&pW[64 + f0]);
        float part = (acc0.x + b0.x) * p0.x + (acc0.y + b0.y) * p0.y
                   + (acc0.z + b0.z) * p0.z + (acc0.w + b0.w) * p0.w
                   + (acc1.x + b1.x) * p1.x + (acc1.y + b1.y) * p1.y
                   + (acc1.z + b1.z) * p1.z + (acc1.w + b1.w) * p1.w;
#pragma unroll
        for (int d = 1; d <= 8; d <<= 1) part += __shfl_xor(part, d, 64);
        if (l16 == 0) logits[v] = part + pb[0];
    } else {
        // pre-activate for the next layer's gemm, store bf16
        ushort4 o0, o1;
        o0.x = f2bf(leaky01(acc0.x + b0.x));
        o0.y = f2bf(leaky01(acc0.y + b0.y));
        o0.z = f2bf(leaky01(acc0.z + b0.z));
        o0.w = f2bf(leaky01(acc0.w + b0.w));
        o1.x = f2bf(leaky01(acc1.x + b1.x));
        o1.y = f2bf(leaky01(acc1.y + b1.y));
        o1.z = f2bf(leaky01(acc1.z + b1.z));
        o1.w = f2bf(leaky01(acc1.w + b1.w));
        *reinterpret_cast<ushort4*>(&xout[(size_t)v * 128 + f0])      = o0;
        *reinterpret_cast<ushort4*>(&xout[(size_t)v * 128 + 64 + f0]) = o1;
    }
}

// ---------------------------------------------------------------------------
extern "C" void kernel_launch(void* const* d_in, const int* in_sizes, int n_in,
                              void* d_out, int out_size, void* d_ws, size_t ws_size,
                              hipStream_t stream)
{
    const float* weights = (const float*)d_in[0];
    const float* lin_W   = (const float*)d_in[1];
    const float* lin_b   = (const float*)d_in[2];
    const float* fc_W    = (const float*)d_in[3];
    const float* attn_l  = (const float*)d_in[4];
    const float* attn_r  = (const float*)d_in[5];
    const float* conv_b  = (const float*)d_in[6];
    const float* pred_W  = (const float*)d_in[7];
    const float* pred_b  = (const float*)d_in[8];
    const int*   src     = (const int*)d_in[9];
    const int*   dst     = (const int*)d_in[10];

    const int N = in_sizes[0];
    const int E = in_sizes[9];
    const int NB = (N + SCAN_TILE - 1) / SCAN_TILE;

    // workspace layout (16B-aligned sections)
    unsigned short* xb = (unsigned short*)d_ws;                    // N*128 bf16 (pre-activated)
    unsigned short* hb = xb + (size_t)N * 128;                     // N*128 bf16
    float* el  = (float*)(hb + (size_t)N * 128);                   // N*4
    float* er  = el + (size_t)N * 4;                               // N*4
    float* c1  = er + (size_t)N * 4;                               // 128
    float* c2  = c1 + 128;                                         // 128
    float* prm = c2 + 128;                                         // 16
    short* Whs = (short*)(prm + 16);                               // 2*16384 bf16
    short* Wls = Whs + 2 * 16384;                                  // 2*16384 bf16
    int*   deg  = (int*)(Wls + 2 * 16384);                         // N
    int*   rowp = deg + N;                                         // N+1
    int*   cur  = rowp + (N + 1);                                  // N
    int*   col  = cur + N;                                         // E+N
    int*   bsum = col + (E + N);                                   // NB
    int*   bpre = bsum + NB;                                       // NB

    // CSR build (fresh every call: ws is re-poisoned)
    deg_init_kernel<<<(N + 255) / 256, 256, 0, stream>>>(deg, N);
    deg_count_kernel<<<(E + 255) / 256, 256, 0, stream>>>(dst, deg, E);
    scanA_kernel<<<NB, 256, 0, stream>>>(deg, bsum, N);
    scanB_kernel<<<1, 1024, 0, stream>>>(bsum, bpre, rowp, NB, N);
    scanC_kernel<<<NB, 256, 0, stream>>>(deg, bpre, rowp, cur, N);
    scatter_kernel<<<(E + N + 255) / 256, 256, 0, stream>>>(src, dst, cur, col, E, N);

    // Split W for layers 1,2 into bf16 hi/lo
    wsplit_kernel<<<(2 * 16384 + 255) / 256, 256, 0, stream>>>(
        fc_W + 16384, Whs, Wls, 2 * 16384);

    // Layer 0 via rank-1 identity
    rank1_prep_kernel<<<1, 128, 0, stream>>>(lin_W, lin_b, fc_W, attn_l, attn_r,
                                             c1, c2, prm);
    rank1_apply_kernel<<<((size_t)N * 32 + 255) / 256, 256, 0, stream>>>(
        weights, c1, c2, prm, hb, el, er, N);
    agg_fused_kernel<<<(N + 15) / 16, 256, 0, stream>>>(
        hb, el, er, rowp, col, conv_b, xb, pred_W, pred_b, (float*)d_out, N, 0);

    // Layers 1, 2 (MFMA bf16 gemm on pre-activated bf16 x)
    for (int l = 1; l < 3; ++l) {
        gemm_mfma_kernel<<<(N + 127) / 128, 256, 0, stream>>>(
            xb, Whs + (size_t)(l - 1) * 16384, Wls + (size_t)(l - 1) * 16384, hb, N);
        elr_kernel<<<(N + 3) / 4, 256, 0, stream>>>(
            hb, attn_l + l * 128, attn_r + l * 128, el, er, N);
        agg_fused_kernel<<<(N + 15) / 16, 256, 0, stream>>>(
            hb, el, er, rowp, col, conv_b + l * 128, xb, pred_W, pred_b,
            (float*)d_out, N, l == 2 ? 1 : 0);
    }
}

// Round 15
// 410.065 us; speedup vs baseline: 1.6103x; 1.0805x over previous
//
#include <hip/hip_runtime.h>
#include <hip/hip_bf16.h>
#include <math.h>

// Problem constants: N=100000, E=600000, D=128, H=4, F=32, L=3

__device__ __forceinline__ float leaky02(float x) {
    return x >= 0.f ? x : 0.2f * x;
}
__device__ __forceinline__ float leaky01(float x) {
    return x >= 0.f ? x : 0.01f * x;
}

// bf16 helpers (round-to-nearest-even)
__device__ __forceinline__ unsigned short f2bf(float f) {
    unsigned u = __float_as_uint(f);
    unsigned r = u + 0x7FFFu + ((u >> 16) & 1u);
    return (unsigned short)(r >> 16);
}
__device__ __forceinline__ float bf2f(unsigned short s) {
    return __uint_as_float(((unsigned)s) << 16);
}

typedef __attribute__((ext_vector_type(8))) short bf16x8;
typedef __attribute__((ext_vector_type(8))) unsigned short u16x8;
typedef __attribute__((ext_vector_type(4))) float f32x4;

// ---------------------------------------------------------------------------
// CSR build
__global__ __launch_bounds__(256) void deg_init_kernel(int* __restrict__ deg, int N)
{
    int i = blockIdx.x * 256 + threadIdx.x;
    if (i < N) deg[i] = 1;  // self loop
}

__global__ __launch_bounds__(256) void deg_count_kernel(
    const int* __restrict__ dst, int* __restrict__ deg, int E)
{
    int i = blockIdx.x * 256 + threadIdx.x;
    if (i < E) atomicAdd(&deg[dst[i]], 1);
}

#define SCAN_TILE 1024

__global__ __launch_bounds__(256) void scanA_kernel(
    const int* __restrict__ deg, int* __restrict__ bsum, int N)
{
    __shared__ int ws[4];
    int b = blockIdx.x, t = threadIdx.x;
    int base = b * SCAN_TILE + t * 4;
    int s = 0;
#pragma unroll
    for (int k = 0; k < 4; ++k) {
        int i = base + k;
        if (i < N) s += deg[i];
    }
#pragma unroll
    for (int m = 32; m >= 1; m >>= 1) s += __shfl_xor(s, m, 64);
    if ((t & 63) == 0) ws[t >> 6] = s;
    __syncthreads();
    if (t == 0) bsum[b] = ws[0] + ws[1] + ws[2] + ws[3];
}

__global__ __launch_bounds__(1024) void scanB_kernel(
    int* __restrict__ bsum, int* __restrict__ bpre, int* __restrict__ rowp,
    int NB, int N)
{
    __shared__ int sh[1024];
    int t = threadIdx.x;
    int v = (t < NB) ? bsum[t] : 0;
    sh[t] = v;
    __syncthreads();
    for (int off = 1; off < 1024; off <<= 1) {
        int u = (t >= off) ? sh[t - off] : 0;
        __syncthreads();
        sh[t] += u;
        __syncthreads();
    }
    if (t < NB) bpre[t] = sh[t] - v;          // exclusive prefix
    if (t == 1023) rowp[N] = sh[1023];        // total
}

__global__ __launch_bounds__(256) void scanC_kernel(
    const int* __restrict__ deg, const int* __restrict__ bpre,
    int* __restrict__ rowp, int* __restrict__ cur, int N)
{
    __shared__ int sh[256];
    int b = blockIdx.x, t = threadIdx.x;
    int base = b * SCAN_TILE + t * 4;
    int v[4];
#pragma unroll
    for (int k = 0; k < 4; ++k) {
        int i = base + k;
        v[k] = (i < N) ? deg[i] : 0;
    }
    int tsum = v[0] + v[1] + v[2] + v[3];
    sh[t] = tsum;
    __syncthreads();
    for (int off = 1; off < 256; off <<= 1) {
        int u = (t >= off) ? sh[t - off] : 0;
        __syncthreads();
        sh[t] += u;
        __syncthreads();
    }
    int pre = bpre[b] + sh[t] - tsum;
#pragma unroll
    for (int k = 0; k < 4; ++k) {
        int i = base + k;
        if (i < N) { rowp[i] = pre; cur[i] = pre; }
        pre += v[k];
    }
}

__global__ __launch_bounds__(256) void scatter_kernel(
    const int* __restrict__ src, const int* __restrict__ dst,
    int* __restrict__ cur, int* __restrict__ col, int E, int N)
{
    int i = blockIdx.x * 256 + threadIdx.x;
    if (i < E) {
        int p = atomicAdd(&cur[dst[i]], 1);
        col[p] = src[i];
    } else if (i < E + N) {
        int v = i - E;
        int p = atomicAdd(&cur[v], 1);
        col[p] = v;  // self loop
    }
}

// ---------------------------------------------------------------------------
// Layer-0 rank-1 precompute
__global__ __launch_bounds__(128) void rank1_prep_kernel(
    const float* __restrict__ lW, const float* __restrict__ lb,
    const float* __restrict__ W0, const float* __restrict__ al,
    const float* __restrict__ ar, float* __restrict__ c1,
    float* __restrict__ c2, float* __restrict__ prm)
{
    int j = threadIdx.x;
    float s1 = 0.f, s2 = 0.f;
    for (int d = 0; d < 128; ++d) {
        float wv = W0[j * 128 + d];
        s1 += lW[d] * wv;
        s2 += lb[d] * wv;
    }
    c1[j] = s1; c2[j] = s2;
    __shared__ float sh1[128], sh2[128], sh3[128], sh4[128];
    sh1[j] = s1 * al[j]; sh2[j] = s2 * al[j];
    sh3[j] = s1 * ar[j]; sh4[j] = s2 * ar[j];
    __syncthreads();
    if (j < 4) {
        float p = 0.f, q = 0.f, r = 0.f, s = 0.f;
        for (int f = 0; f < 32; ++f) {
            p += sh1[j * 32 + f]; q += sh2[j * 32 + f];
            r += sh3[j * 32 + f]; s += sh4[j * 32 + f];
        }
        prm[j] = p; prm[4 + j] = q; prm[8 + j] = r; prm[12 + j] = s;
    }
}

// h0 (bf16) = w[n]*c1[j] + c2[j]; el0/er0 from rank-1 params.
__global__ __launch_bounds__(256) void rank1_apply_kernel(
    const float* __restrict__ w, const float* __restrict__ c1,
    const float* __restrict__ c2, const float* __restrict__ prm,
    unsigned short* __restrict__ hb, float* __restrict__ el,
    float* __restrict__ er, int N)
{
    int i = blockIdx.x * 256 + threadIdx.x;
    int n = i >> 5, k = i & 31;
    if (n >= N) return;
    float wn = w[n];
    float4 a = *reinterpret_cast<const float4*>(&c1[k * 4]);
    float4 b = *reinterpret_cast<const float4*>(&c2[k * 4]);
    ushort4 o;
    o.x = f2bf(wn * a.x + b.x);
    o.y = f2bf(wn * a.y + b.y);
    o.z = f2bf(wn * a.z + b.z);
    o.w = f2bf(wn * a.w + b.w);
    *reinterpret_cast<ushort4*>(&hb[(size_t)n * 128 + k * 4]) = o;
    if (k == 0) {
        float4 pl = *reinterpret_cast<const float4*>(&prm[0]);
        float4 ql = *reinterpret_cast<const float4*>(&prm[4]);
        float4 pr = *reinterpret_cast<const float4*>(&prm[8]);
        float4 qr = *reinterpret_cast<const float4*>(&prm[12]);
        float4 e1 = make_float4(wn * pl.x + ql.x, wn * pl.y + ql.y,
                                wn * pl.z + ql.z, wn * pl.w + ql.w);
        float4 e2 = make_float4(wn * pr.x + qr.x, wn * pr.y + qr.y,
                                wn * pr.z + qr.z, wn * pr.w + qr.w);
        *reinterpret_cast<float4*>(&el[(size_t)n * 4]) = e1;
        *reinterpret_cast<float4*>(&er[(size_t)n * 4]) = e2;
    }
}

// ---------------------------------------------------------------------------
// Split fc_W (layers 1,2) into bf16 hi/lo. n = 2*128*128 elements.
__global__ __launch_bounds__(256) void wsplit_kernel(
    const float* __restrict__ W, short* __restrict__ Wh,
    short* __restrict__ Wl, int n)
{
    int i = blockIdx.x * 256 + threadIdx.x;
    if (i < n) {
        float f = W[i];
        unsigned short hi = f2bf(f);
        float fh = bf2f(hi);
        Wh[i] = (short)hi;
        Wl[i] = (short)f2bf(f - fh);
    }
}

// ---------------------------------------------------------------------------
// MFMA bf16 GEMM (layers 1,2): h[n,j] = sum_d x_bf16[n,d]*W[j,d]
// x is PRE-ACTIVATED bf16 -> A fragment is a direct bf16x8 load.
// C = A*Wh + A*Wl. 32 rows/wave, W fragments hoisted (R12 fix).
__global__ __launch_bounds__(256) void gemm_mfma_kernel(
    const unsigned short* __restrict__ xb, const short* __restrict__ Wh,
    const short* __restrict__ Wl, unsigned short* __restrict__ hb, int N)
{
    const int lane = threadIdx.x & 63;
    const int wv   = threadIdx.x >> 6;
    const int m0   = blockIdx.x * 128 + wv * 32;  // 32 rows per wave
    const int mr   = lane & 15;
    const int quad = lane >> 4;

    int r0 = m0 + mr;      if (r0 > N - 1) r0 = N - 1;   // clamped load rows
    int r1 = m0 + 16 + mr; if (r1 > N - 1) r1 = N - 1;
    const unsigned short* xp0 = xb + (size_t)r0 * 128 + quad * 8;
    const unsigned short* xp1 = xb + (size_t)r1 * 128 + quad * 8;

    f32x4 acc0[8], acc1[8];
#pragma unroll
    for (int c = 0; c < 8; ++c) {
        acc0[c] = (f32x4){0.f, 0.f, 0.f, 0.f};
        acc1[c] = (f32x4){0.f, 0.f, 0.f, 0.f};
    }

#pragma unroll
    for (int kk = 0; kk < 4; ++kk) {
        bf16x8 a0 = *reinterpret_cast<const bf16x8*>(xp0 + kk * 32);
        bf16x8 a1 = *reinterpret_cast<const bf16x8*>(xp1 + kk * 32);

        const int kb = kk * 32 + quad * 8;
        bf16x8 bh[8], bl[8];
#pragma unroll
        for (int c = 0; c < 8; ++c) {
            const size_t wo = (size_t)(c * 16 + mr) * 128 + kb;
            bh[c] = *reinterpret_cast<const bf16x8*>(Wh + wo);
            bl[c] = *reinterpret_cast<const bf16x8*>(Wl + wo);
        }
#pragma unroll
        for (int c = 0; c < 8; ++c) {
            acc0[c] = __builtin_amdgcn_mfma_f32_16x16x32_bf16(a0, bh[c], acc0[c], 0, 0, 0);
            acc0[c] = __builtin_amdgcn_mfma_f32_16x16x32_bf16(a0, bl[c], acc0[c], 0, 0, 0);
            acc1[c] = __builtin_amdgcn_mfma_f32_16x16x32_bf16(a1, bh[c], acc1[c], 0, 0, 0);
            acc1[c] = __builtin_amdgcn_mfma_f32_16x16x32_bf16(a1, bl[c], acc1[c], 0, 0, 0);
        }
    }

#pragma unroll
    for (int i = 0; i < 4; ++i) {
        int rowA = m0 + quad * 4 + i;
        if (rowA < N) {
            unsigned short* hp = hb + (size_t)rowA * 128 + mr;
#pragma unroll
            for (int c = 0; c < 8; ++c) hp[c * 16] = f2bf(acc0[c][i]);
        }
        int rowB = m0 + 16 + quad * 4 + i;
        if (rowB < N) {
            unsigned short* hp = hb + (size_t)rowB * 128 + mr;
#pragma unroll
            for (int c = 0; c < 8; ++c) hp[c * 16] = f2bf(acc1[c][i]);
        }
    }
}

// ---------------------------------------------------------------------------
// el/er reduction (layers 1,2), bf16 h input. One wave per node.
__global__ __launch_bounds__(256) void elr_kernel(
    const unsigned short* __restrict__ hb, const float* __restrict__ al,
    const float* __restrict__ ar, float* __restrict__ el,
    float* __restrict__ er, int N)
{
    int node = blockIdx.x * 4 + (threadIdx.x >> 6);
    int lane = threadIdx.x & 63;
    if (node >= N) return;
    float v0 = bf2f(hb[(size_t)node * 128 + lane]);
    float v1 = bf2f(hb[(size_t)node * 128 + 64 + lane]);
    float sl0 = v0 * al[lane];
    float sl1 = v1 * al[64 + lane];
    float sr0 = v0 * ar[lane];
    float sr1 = v1 * ar[64 + lane];
#pragma unroll
    for (int m = 16; m >= 1; m >>= 1) {
        sl0 += __shfl_xor(sl0, m, 64);
        sl1 += __shfl_xor(sl1, m, 64);
        sr0 += __shfl_xor(sr0, m, 64);
        sr1 += __shfl_xor(sr1, m, 64);
    }
    if ((lane & 31) == 0) {
        int hb2 = lane >> 5;
        el[node * 4 + hb2]     = sl0;
        el[node * 4 + hb2 + 2] = sl1;
        er[node * 4 + hb2]     = sr0;
        er[node * 4 + hb2 + 2] = sr1;
    }
}

// ---------------------------------------------------------------------------
// SINGLE-PASS fused online-softmax aggregation + epilogue.
// FOUR nodes per wave; each 16-lane quarter owns one node.
// Lane l16 covers 8 contiguous features f0=l16*8 (ONE head = l16>>2):
//   - one ushort8 (16B) h load per edge per lane
//   - one leaky+exp per edge per lane
//   - flash-style rescale of (m, s, acc[8]) on new max — no Phase A,
//     no stats shuffles; col/el read ONCE.
// last=0: xout = bf16(leaky01(acc/s + bias)); last=1: fused prediction.
__global__ __launch_bounds__(256) void agg_fused_kernel(
    const unsigned short* __restrict__ hb, const float* __restrict__ el,
    const float* __restrict__ er, const int* __restrict__ rowp,
    const int* __restrict__ col, const float* __restrict__ bias,
    unsigned short* __restrict__ xout, const float* __restrict__ pW,
    const float* __restrict__ pb, float* __restrict__ logits,
    int N, int last)
{
    const int lane = threadIdx.x & 63;
    const int q    = lane >> 4;
    const int l16  = lane & 15;
    const int v    = blockIdx.x * 16 + (threadIdx.x >> 6) * 4 + q;
    if (v >= N) return;   // reductions below stay within the 16-lane quarter

    const int r0 = rowp[v], r1 = rowp[v + 1];
    const int head = l16 >> 2;       // head for this lane's 8 features
    const int f0   = l16 * 8;        // feature base 0..120
    const float erq = er[(size_t)v * 4 + head];

    float m = -INFINITY, s = 0.f;
    float acc[8];
#pragma unroll
    for (int k = 0; k < 8; ++k) acc[k] = 0.f;

    int u = (r0 < r1) ? col[r0] : 0;
    for (int j = r0; j < r1; ++j) {
        int u_next = (j + 1 < r1) ? col[j + 1] : u;   // prefetch next src
        float e = leaky02(el[(size_t)u * 4 + head] + erq);
        u16x8 hv = *reinterpret_cast<const u16x8*>(&hb[(size_t)u * 128 + f0]);
        if (e > m) {
            float sc = __expf(m - e);   // exp(-inf)=0 handles first edge
            s = s * sc + 1.f;
#pragma unroll
            for (int k = 0; k < 8; ++k) acc[k] = acc[k] * sc + bf2f(hv[k]);
            m = e;
        } else {
            float p = __expf(e - m);
            s += p;
#pragma unroll
            for (int k = 0; k < 8; ++k) acc[k] += p * bf2f(hv[k]);
        }
        u = u_next;
    }
    const float is = 1.f / s;

    float4 b0 = *reinterpret_cast<const float4*>(&bias[f0]);
    float4 b1 = *reinterpret_cast<const float4*>(&bias[f0 + 4]);
    const float bb[8] = {b0.x, b0.y, b0.z, b0.w, b1.x, b1.y, b1.z, b1.w};

    if (last) {
        float4 p0 = *reinterpret_cast<const float4*>(&pW[f0]);
        float4 p1 = *reinterpret_cast<const float4*>(&pW[f0 + 4]);
        const float pp[8] = {p0.x, p0.y, p0.z, p0.w, p1.x, p1.y, p1.z, p1.w};
        float part = 0.f;
#pragma unroll
        for (int k = 0; k < 8; ++k) part += (acc[k] * is + bb[k]) * pp[k];
#pragma unroll
        for (int d = 1; d <= 8; d <<= 1) part += __shfl_xor(part, d, 64);
        if (l16 == 0) logits[v] = part + pb[0];
    } else {
        u16x8 o;
#pragma unroll
        for (int k = 0; k < 8; ++k) o[k] = f2bf(leaky01(acc[k] * is + bb[k]));
        *reinterpret_cast<u16x8*>(&xout[(size_t)v * 128 + f0]) = o;
    }
}

// ---------------------------------------------------------------------------
extern "C" void kernel_launch(void* const* d_in, const int* in_sizes, int n_in,
                              void* d_out, int out_size, void* d_ws, size_t ws_size,
                              hipStream_t stream)
{
    const float* weights = (const float*)d_in[0];
    const float* lin_W   = (const float*)d_in[1];
    const float* lin_b   = (const float*)d_in[2];
    const float* fc_W    = (const float*)d_in[3];
    const float* attn_l  = (const float*)d_in[4];
    const float* attn_r  = (const float*)d_in[5];
    const float* conv_b  = (const float*)d_in[6];
    const float* pred_W  = (const float*)d_in[7];
    const float* pred_b  = (const float*)d_in[8];
    const int*   src     = (const int*)d_in[9];
    const int*   dst     = (const int*)d_in[10];

    const int N = in_sizes[0];
    const int E = in_sizes[9];
    const int NB = (N + SCAN_TILE - 1) / SCAN_TILE;

    // workspace layout (16B-aligned sections)
    unsigned short* xb = (unsigned short*)d_ws;                    // N*128 bf16 (pre-activated)
    unsigned short* hb = xb + (size_t)N * 128;                     // N*128 bf16
    float* el  = (float*)(hb + (size_t)N * 128);                   // N*4
    float* er  = el + (size_t)N * 4;                               // N*4
    float* c1  = er + (size_t)N * 4;                               // 128
    float* c2  = c1 + 128;                                         // 128
    float* prm = c2 + 128;                                         // 16
    short* Whs = (short*)(prm + 16);                               // 2*16384 bf16
    short* Wls = Whs + 2 * 16384;                                  // 2*16384 bf16
    int*   deg  = (int*)(Wls + 2 * 16384);                         // N
    int*   rowp = deg + N;                                         // N+1
    int*   cur  = rowp + (N + 1);                                  // N
    int*   col  = cur + N;                                         // E+N
    int*   bsum = col + (E + N);                                   // NB
    int*   bpre = bsum + NB;                                       // NB

    // CSR build (fresh every call: ws is re-poisoned)
    deg_init_kernel<<<(N + 255) / 256, 256, 0, stream>>>(deg, N);
    deg_count_kernel<<<(E + 255) / 256, 256, 0, stream>>>(dst, deg, E);
    scanA_kernel<<<NB, 256, 0, stream>>>(deg, bsum, N);
    scanB_kernel<<<1, 1024, 0, stream>>>(bsum, bpre, rowp, NB, N);
    scanC_kernel<<<NB, 256, 0, stream>>>(deg, bpre, rowp, cur, N);
    scatter_kernel<<<(E + N + 255) / 256, 256, 0, stream>>>(src, dst, cur, col, E, N);

    // Split W for layers 1,2 into bf16 hi/lo
    wsplit_kernel<<<(2 * 16384 + 255) / 256, 256, 0, stream>>>(
        fc_W + 16384, Whs, Wls, 2 * 16384);

    // Layer 0 via rank-1 identity
    rank1_prep_kernel<<<1, 128, 0, stream>>>(lin_W, lin_b, fc_W, attn_l, attn_r,
                                             c1, c2, prm);
    rank1_apply_kernel<<<((size_t)N * 32 + 255) / 256, 256, 0, stream>>>(
        weights, c1, c2, prm, hb, el, er, N);
    agg_fused_kernel<<<(N + 15) / 16, 256, 0, stream>>>(
        hb, el, er, rowp, col, conv_b, xb, pred_W, pred_b, (float*)d_out, N, 0);

    // Layers 1, 2 (MFMA bf16 gemm on pre-activated bf16 x)
    for (int l = 1; l < 3; ++l) {
        gemm_mfma_kernel<<<(N + 127) / 128, 256, 0, stream>>>(
            xb, Whs + (size_t)(l - 1) * 16384, Wls + (size_t)(l - 1) * 16384, hb, N);
        elr_kernel<<<(N + 3) / 4, 256, 0, stream>>>(
            hb, attn_l + l * 128, attn_r + l * 128, el, er, N);
        agg_fused_kernel<<<(N + 15) / 16, 256, 0, stream>>>(
            hb, el, er, rowp, col, conv_b + l * 128, xb, pred_W, pred_b,
            (float*)d_out, N, l == 2 ? 1 : 0);
    }
}

// Round 16
// 380.366 us; speedup vs baseline: 1.7360x; 1.0781x over previous
//
#include <hip/hip_runtime.h>
#include <hip/hip_bf16.h>
#include <math.h>

// Problem constants: N=100000, E=600000, D=128, H=4, F=32, L=3

__device__ __forceinline__ float leaky02(float x) {
    return x >= 0.f ? x : 0.2f * x;
}
__device__ __forceinline__ float leaky01(float x) {
    return x >= 0.f ? x : 0.01f * x;
}

// bf16 helpers (round-to-nearest-even)
__device__ __forceinline__ unsigned short f2bf(float f) {
    unsigned u = __float_as_uint(f);
    unsigned r = u + 0x7FFFu + ((u >> 16) & 1u);
    return (unsigned short)(r >> 16);
}
__device__ __forceinline__ float bf2f(unsigned short s) {
    return __uint_as_float(((unsigned)s) << 16);
}

typedef __attribute__((ext_vector_type(8))) short bf16x8;
typedef __attribute__((ext_vector_type(8))) unsigned short u16x8;
typedef __attribute__((ext_vector_type(4))) float f32x4;

// ---------------------------------------------------------------------------
// CSR build (single-atomic: slot recorded during degree count)
__global__ __launch_bounds__(256) void deg_init_kernel(int* __restrict__ deg, int N)
{
    int i = blockIdx.x * 256 + threadIdx.x;
    if (i < N) deg[i] = 1;  // self loop reserves slot 0
}

// slot[i] = old count (>=1 because self loop holds slot 0)
__global__ __launch_bounds__(256) void deg_count_slot_kernel(
    const int* __restrict__ dst, int* __restrict__ deg,
    int* __restrict__ slot, int E)
{
    int i = blockIdx.x * 256 + threadIdx.x;
    if (i < E) slot[i] = atomicAdd(&deg[dst[i]], 1);
}

#define SCAN_TILE 1024

__global__ __launch_bounds__(256) void scanA_kernel(
    const int* __restrict__ deg, int* __restrict__ bsum, int N)
{
    __shared__ int ws[4];
    int b = blockIdx.x, t = threadIdx.x;
    int base = b * SCAN_TILE + t * 4;
    int s = 0;
#pragma unroll
    for (int k = 0; k < 4; ++k) {
        int i = base + k;
        if (i < N) s += deg[i];
    }
#pragma unroll
    for (int m = 32; m >= 1; m >>= 1) s += __shfl_xor(s, m, 64);
    if ((t & 63) == 0) ws[t >> 6] = s;
    __syncthreads();
    if (t == 0) bsum[b] = ws[0] + ws[1] + ws[2] + ws[3];
}

__global__ __launch_bounds__(1024) void scanB_kernel(
    int* __restrict__ bsum, int* __restrict__ bpre, int* __restrict__ rowp,
    int NB, int N)
{
    __shared__ int sh[1024];
    int t = threadIdx.x;
    int v = (t < NB) ? bsum[t] : 0;
    sh[t] = v;
    __syncthreads();
    for (int off = 1; off < 1024; off <<= 1) {
        int u = (t >= off) ? sh[t - off] : 0;
        __syncthreads();
        sh[t] += u;
        __syncthreads();
    }
    if (t < NB) bpre[t] = sh[t] - v;          // exclusive prefix
    if (t == 1023) rowp[N] = sh[1023];        // total
}

// scanC also writes the self-loop entry: col[rowp[i]] = i (slot 0).
__global__ __launch_bounds__(256) void scanC_kernel(
    const int* __restrict__ deg, const int* __restrict__ bpre,
    int* __restrict__ rowp, int* __restrict__ col, int N)
{
    __shared__ int sh[256];
    int b = blockIdx.x, t = threadIdx.x;
    int base = b * SCAN_TILE + t * 4;
    int v[4];
#pragma unroll
    for (int k = 0; k < 4; ++k) {
        int i = base + k;
        v[k] = (i < N) ? deg[i] : 0;
    }
    int tsum = v[0] + v[1] + v[2] + v[3];
    sh[t] = tsum;
    __syncthreads();
    for (int off = 1; off < 256; off <<= 1) {
        int u = (t >= off) ? sh[t - off] : 0;
        __syncthreads();
        sh[t] += u;
        __syncthreads();
    }
    int pre = bpre[b] + sh[t] - tsum;
#pragma unroll
    for (int k = 0; k < 4; ++k) {
        int i = base + k;
        if (i < N) {
            rowp[i] = pre;
            col[pre] = i;   // self loop at slot 0
        }
        pre += v[k];
    }
}

// atomic-free scatter: position fully determined by rowp + recorded slot
__global__ __launch_bounds__(256) void scatter2_kernel(
    const int* __restrict__ src, const int* __restrict__ dst,
    const int* __restrict__ slot, const int* __restrict__ rowp,
    int* __restrict__ col, int E)
{
    int i = blockIdx.x * 256 + threadIdx.x;
    if (i < E) col[rowp[dst[i]] + slot[i]] = src[i];
}

// ---------------------------------------------------------------------------
// Layer-0 rank-1 precompute
__global__ __launch_bounds__(128) void rank1_prep_kernel(
    const float* __restrict__ lW, const float* __restrict__ lb,
    const float* __restrict__ W0, const float* __restrict__ al,
    const float* __restrict__ ar, float* __restrict__ c1,
    float* __restrict__ c2, float* __restrict__ prm)
{
    int j = threadIdx.x;
    float s1 = 0.f, s2 = 0.f;
    for (int d = 0; d < 128; ++d) {
        float wv = W0[j * 128 + d];
        s1 += lW[d] * wv;
        s2 += lb[d] * wv;
    }
    c1[j] = s1; c2[j] = s2;
    __shared__ float sh1[128], sh2[128], sh3[128], sh4[128];
    sh1[j] = s1 * al[j]; sh2[j] = s2 * al[j];
    sh3[j] = s1 * ar[j]; sh4[j] = s2 * ar[j];
    __syncthreads();
    if (j < 4) {
        float p = 0.f, q = 0.f, r = 0.f, s = 0.f;
        for (int f = 0; f < 32; ++f) {
            p += sh1[j * 32 + f]; q += sh2[j * 32 + f];
            r += sh3[j * 32 + f]; s += sh4[j * 32 + f];
        }
        prm[j] = p; prm[4 + j] = q; prm[8 + j] = r; prm[12 + j] = s;
    }
}

// h0 (bf16) = w[n]*c1[j] + c2[j]; el0/er0 from rank-1 params.
__global__ __launch_bounds__(256) void rank1_apply_kernel(
    const float* __restrict__ w, const float* __restrict__ c1,
    const float* __restrict__ c2, const float* __restrict__ prm,
    unsigned short* __restrict__ hb, float* __restrict__ el,
    float* __restrict__ er, int N)
{
    int i = blockIdx.x * 256 + threadIdx.x;
    int n = i >> 5, k = i & 31;
    if (n >= N) return;
    float wn = w[n];
    float4 a = *reinterpret_cast<const float4*>(&c1[k * 4]);
    float4 b = *reinterpret_cast<const float4*>(&c2[k * 4]);
    ushort4 o;
    o.x = f2bf(wn * a.x + b.x);
    o.y = f2bf(wn * a.y + b.y);
    o.z = f2bf(wn * a.z + b.z);
    o.w = f2bf(wn * a.w + b.w);
    *reinterpret_cast<ushort4*>(&hb[(size_t)n * 128 + k * 4]) = o;
    if (k == 0) {
        float4 pl = *reinterpret_cast<const float4*>(&prm[0]);
        float4 ql = *reinterpret_cast<const float4*>(&prm[4]);
        float4 pr = *reinterpret_cast<const float4*>(&prm[8]);
        float4 qr = *reinterpret_cast<const float4*>(&prm[12]);
        float4 e1 = make_float4(wn * pl.x + ql.x, wn * pl.y + ql.y,
                                wn * pl.z + ql.z, wn * pl.w + ql.w);
        float4 e2 = make_float4(wn * pr.x + qr.x, wn * pr.y + qr.y,
                                wn * pr.z + qr.z, wn * pr.w + qr.w);
        *reinterpret_cast<float4*>(&el[(size_t)n * 4]) = e1;
        *reinterpret_cast<float4*>(&er[(size_t)n * 4]) = e2;
    }
}

// ---------------------------------------------------------------------------
// Split fc_W (layers 1,2) into bf16 hi/lo. n = 2*128*128 elements.
__global__ __launch_bounds__(256) void wsplit_kernel(
    const float* __restrict__ W, short* __restrict__ Wh,
    short* __restrict__ Wl, int n)
{
    int i = blockIdx.x * 256 + threadIdx.x;
    if (i < n) {
        float f = W[i];
        unsigned short hi = f2bf(f);
        float fh = bf2f(hi);
        Wh[i] = (short)hi;
        Wl[i] = (short)f2bf(f - fh);
    }
}

// ---------------------------------------------------------------------------
// MFMA bf16 GEMM (layers 1,2): h[n,j] = sum_d x_bf16[n,d]*W[j,d]
// x is PRE-ACTIVATED bf16 -> A fragment is a direct bf16x8 load.
// C = A*Wh + A*Wl. 32 rows/wave, W fragments hoisted (R12 fix).
__global__ __launch_bounds__(256) void gemm_mfma_kernel(
    const unsigned short* __restrict__ xb, const short* __restrict__ Wh,
    const short* __restrict__ Wl, unsigned short* __restrict__ hb, int N)
{
    const int lane = threadIdx.x & 63;
    const int wv   = threadIdx.x >> 6;
    const int m0   = blockIdx.x * 128 + wv * 32;  // 32 rows per wave
    const int mr   = lane & 15;
    const int quad = lane >> 4;

    int r0 = m0 + mr;      if (r0 > N - 1) r0 = N - 1;   // clamped load rows
    int r1 = m0 + 16 + mr; if (r1 > N - 1) r1 = N - 1;
    const unsigned short* xp0 = xb + (size_t)r0 * 128 + quad * 8;
    const unsigned short* xp1 = xb + (size_t)r1 * 128 + quad * 8;

    f32x4 acc0[8], acc1[8];
#pragma unroll
    for (int c = 0; c < 8; ++c) {
        acc0[c] = (f32x4){0.f, 0.f, 0.f, 0.f};
        acc1[c] = (f32x4){0.f, 0.f, 0.f, 0.f};
    }

#pragma unroll
    for (int kk = 0; kk < 4; ++kk) {
        bf16x8 a0 = *reinterpret_cast<const bf16x8*>(xp0 + kk * 32);
        bf16x8 a1 = *reinterpret_cast<const bf16x8*>(xp1 + kk * 32);

        const int kb = kk * 32 + quad * 8;
        bf16x8 bh[8], bl[8];
#pragma unroll
        for (int c = 0; c < 8; ++c) {
            const size_t wo = (size_t)(c * 16 + mr) * 128 + kb;
            bh[c] = *reinterpret_cast<const bf16x8*>(Wh + wo);
            bl[c] = *reinterpret_cast<const bf16x8*>(Wl + wo);
        }
#pragma unroll
        for (int c = 0; c < 8; ++c) {
            acc0[c] = __builtin_amdgcn_mfma_f32_16x16x32_bf16(a0, bh[c], acc0[c], 0, 0, 0);
            acc0[c] = __builtin_amdgcn_mfma_f32_16x16x32_bf16(a0, bl[c], acc0[c], 0, 0, 0);
            acc1[c] = __builtin_amdgcn_mfma_f32_16x16x32_bf16(a1, bh[c], acc1[c], 0, 0, 0);
            acc1[c] = __builtin_amdgcn_mfma_f32_16x16x32_bf16(a1, bl[c], acc1[c], 0, 0, 0);
        }
    }

#pragma unroll
    for (int i = 0; i < 4; ++i) {
        int rowA = m0 + quad * 4 + i;
        if (rowA < N) {
            unsigned short* hp = hb + (size_t)rowA * 128 + mr;
#pragma unroll
            for (int c = 0; c < 8; ++c) hp[c * 16] = f2bf(acc0[c][i]);
        }
        int rowB = m0 + 16 + quad * 4 + i;
        if (rowB < N) {
            unsigned short* hp = hb + (size_t)rowB * 128 + mr;
#pragma unroll
            for (int c = 0; c < 8; ++c) hp[c * 16] = f2bf(acc1[c][i]);
        }
    }
}

// ---------------------------------------------------------------------------
// el/er reduction (layers 1,2), bf16 h input. One wave per node.
__global__ __launch_bounds__(256) void elr_kernel(
    const unsigned short* __restrict__ hb, const float* __restrict__ al,
    const float* __restrict__ ar, float* __restrict__ el,
    float* __restrict__ er, int N)
{
    int node = blockIdx.x * 4 + (threadIdx.x >> 6);
    int lane = threadIdx.x & 63;
    if (node >= N) return;
    float v0 = bf2f(hb[(size_t)node * 128 + lane]);
    float v1 = bf2f(hb[(size_t)node * 128 + 64 + lane]);
    float sl0 = v0 * al[lane];
    float sl1 = v1 * al[64 + lane];
    float sr0 = v0 * ar[lane];
    float sr1 = v1 * ar[64 + lane];
#pragma unroll
    for (int m = 16; m >= 1; m >>= 1) {
        sl0 += __shfl_xor(sl0, m, 64);
        sl1 += __shfl_xor(sl1, m, 64);
        sr0 += __shfl_xor(sr0, m, 64);
        sr1 += __shfl_xor(sr1, m, 64);
    }
    if ((lane & 31) == 0) {
        int hb2 = lane >> 5;
        el[node * 4 + hb2]     = sl0;
        el[node * 4 + hb2 + 2] = sl1;
        er[node * 4 + hb2]     = sr0;
        er[node * 4 + hb2 + 2] = sr1;
    }
}

// ---------------------------------------------------------------------------
// SINGLE-PASS fused online-softmax aggregation + epilogue (R15 structure).
__global__ __launch_bounds__(256) void agg_fused_kernel(
    const unsigned short* __restrict__ hb, const float* __restrict__ el,
    const float* __restrict__ er, const int* __restrict__ rowp,
    const int* __restrict__ col, const float* __restrict__ bias,
    unsigned short* __restrict__ xout, const float* __restrict__ pW,
    const float* __restrict__ pb, float* __restrict__ logits,
    int N, int last)
{
    const int lane = threadIdx.x & 63;
    const int q    = lane >> 4;
    const int l16  = lane & 15;
    const int v    = blockIdx.x * 16 + (threadIdx.x >> 6) * 4 + q;
    if (v >= N) return;   // reductions below stay within the 16-lane quarter

    const int r0 = rowp[v], r1 = rowp[v + 1];
    const int head = l16 >> 2;       // head for this lane's 8 features
    const int f0   = l16 * 8;        // feature base 0..120
    const float erq = er[(size_t)v * 4 + head];

    float m = -INFINITY, s = 0.f;
    float acc[8];
#pragma unroll
    for (int k = 0; k < 8; ++k) acc[k] = 0.f;

    int u = (r0 < r1) ? col[r0] : 0;
    for (int j = r0; j < r1; ++j) {
        int u_next = (j + 1 < r1) ? col[j + 1] : u;   // prefetch next src
        float e = leaky02(el[(size_t)u * 4 + head] + erq);
        u16x8 hv = *reinterpret_cast<const u16x8*>(&hb[(size_t)u * 128 + f0]);
        if (e > m) {
            float sc = __expf(m - e);   // exp(-inf)=0 handles first edge
            s = s * sc + 1.f;
#pragma unroll
            for (int k = 0; k < 8; ++k) acc[k] = acc[k] * sc + bf2f(hv[k]);
            m = e;
        } else {
            float p = __expf(e - m);
            s += p;
#pragma unroll
            for (int k = 0; k < 8; ++k) acc[k] += p * bf2f(hv[k]);
        }
        u = u_next;
    }
    const float is = 1.f / s;

    float4 b0 = *reinterpret_cast<const float4*>(&bias[f0]);
    float4 b1 = *reinterpret_cast<const float4*>(&bias[f0 + 4]);
    const float bb[8] = {b0.x, b0.y, b0.z, b0.w, b1.x, b1.y, b1.z, b1.w};

    if (last) {
        float4 p0 = *reinterpret_cast<const float4*>(&pW[f0]);
        float4 p1 = *reinterpret_cast<const float4*>(&pW[f0 + 4]);
        const float pp[8] = {p0.x, p0.y, p0.z, p0.w, p1.x, p1.y, p1.z, p1.w};
        float part = 0.f;
#pragma unroll
        for (int k = 0; k < 8; ++k) part += (acc[k] * is + bb[k]) * pp[k];
#pragma unroll
        for (int d = 1; d <= 8; d <<= 1) part += __shfl_xor(part, d, 64);
        if (l16 == 0) logits[v] = part + pb[0];
    } else {
        u16x8 o;
#pragma unroll
        for (int k = 0; k < 8; ++k) o[k] = f2bf(leaky01(acc[k] * is + bb[k]));
        *reinterpret_cast<u16x8*>(&xout[(size_t)v * 128 + f0]) = o;
    }
}

// ---------------------------------------------------------------------------
extern "C" void kernel_launch(void* const* d_in, const int* in_sizes, int n_in,
                              void* d_out, int out_size, void* d_ws, size_t ws_size,
                              hipStream_t stream)
{
    const float* weights = (const float*)d_in[0];
    const float* lin_W   = (const float*)d_in[1];
    const float* lin_b   = (const float*)d_in[2];
    const float* fc_W    = (const float*)d_in[3];
    const float* attn_l  = (const float*)d_in[4];
    const float* attn_r  = (const float*)d_in[5];
    const float* conv_b  = (const float*)d_in[6];
    const float* pred_W  = (const float*)d_in[7];
    const float* pred_b  = (const float*)d_in[8];
    const int*   src     = (const int*)d_in[9];
    const int*   dst     = (const int*)d_in[10];

    const int N = in_sizes[0];
    const int E = in_sizes[9];
    const int NB = (N + SCAN_TILE - 1) / SCAN_TILE;

    // workspace layout (16B-aligned sections)
    unsigned short* xb = (unsigned short*)d_ws;                    // N*128 bf16 (pre-activated)
    unsigned short* hb = xb + (size_t)N * 128;                     // N*128 bf16
    float* el  = (float*)(hb + (size_t)N * 128);                   // N*4
    float* er  = el + (size_t)N * 4;                               // N*4
    float* c1  = er + (size_t)N * 4;                               // 128
    float* c2  = c1 + 128;                                         // 128
    float* prm = c2 + 128;                                         // 16
    short* Whs = (short*)(prm + 16);                               // 2*16384 bf16
    short* Wls = Whs + 2 * 16384;                                  // 2*16384 bf16
    int*   deg  = (int*)(Wls + 2 * 16384);                         // N
    int*   rowp = deg + N;                                         // N+1
    int*   slot = rowp + (N + 1);                                  // E
    int*   col  = slot + E;                                        // E+N
    int*   bsum = col + (E + N);                                   // NB
    int*   bpre = bsum + NB;                                       // NB

    // CSR build — single atomic pass (fresh every call: ws is re-poisoned)
    deg_init_kernel<<<(N + 255) / 256, 256, 0, stream>>>(deg, N);
    deg_count_slot_kernel<<<(E + 255) / 256, 256, 0, stream>>>(dst, deg, slot, E);
    scanA_kernel<<<NB, 256, 0, stream>>>(deg, bsum, N);
    scanB_kernel<<<1, 1024, 0, stream>>>(bsum, bpre, rowp, NB, N);
    scanC_kernel<<<NB, 256, 0, stream>>>(deg, bpre, rowp, col, N);
    scatter2_kernel<<<(E + 255) / 256, 256, 0, stream>>>(src, dst, slot, rowp, col, E);

    // Split W for layers 1,2 into bf16 hi/lo
    wsplit_kernel<<<(2 * 16384 + 255) / 256, 256, 0, stream>>>(
        fc_W + 16384, Whs, Wls, 2 * 16384);

    // Layer 0 via rank-1 identity
    rank1_prep_kernel<<<1, 128, 0, stream>>>(lin_W, lin_b, fc_W, attn_l, attn_r,
                                             c1, c2, prm);
    rank1_apply_kernel<<<((size_t)N * 32 + 255) / 256, 256, 0, stream>>>(
        weights, c1, c2, prm, hb, el, er, N);
    agg_fused_kernel<<<(N + 15) / 16, 256, 0, stream>>>(
        hb, el, er, rowp, col, conv_b, xb, pred_W, pred_b, (float*)d_out, N, 0);

    // Layers 1, 2 (MFMA bf16 gemm on pre-activated bf16 x)
    for (int l = 1; l < 3; ++l) {
        gemm_mfma_kernel<<<(N + 127) / 128, 256, 0, stream>>>(
            xb, Whs + (size_t)(l - 1) * 16384, Wls + (size_t)(l - 1) * 16384, hb, N);
        elr_kernel<<<(N + 3) / 4, 256, 0, stream>>>(
            hb, attn_l + l * 128, attn_r + l * 128, el, er, N);
        agg_fused_kernel<<<(N + 15) / 16, 256, 0, stream>>>(
            hb, el, er, rowp, col, conv_b + l * 128, xb, pred_W, pred_b,
            (float*)d_out, N, l == 2 ? 1 : 0);
    }
}

// Round 17
// 377.829 us; speedup vs baseline: 1.7477x; 1.0067x over previous
//
#include <hip/hip_runtime.h>
#include <hip/hip_bf16.h>
#include <math.h>

// Problem constants: N=100000, E=600000, D=128, H=4, F=32, L=3

__device__ __forceinline__ float leaky02(float x) {
    return x >= 0.f ? x : 0.2f * x;
}
__device__ __forceinline__ float leaky01(float x) {
    return x >= 0.f ? x : 0.01f * x;
}

// bf16 helpers (round-to-nearest-even)
__device__ __forceinline__ unsigned short f2bf(float f) {
    unsigned u = __float_as_uint(f);
    unsigned r = u + 0x7FFFu + ((u >> 16) & 1u);
    return (unsigned short)(r >> 16);
}
__device__ __forceinline__ float bf2f(unsigned short s) {
    return __uint_as_float(((unsigned)s) << 16);
}

typedef __attribute__((ext_vector_type(8))) short bf16x8;
typedef __attribute__((ext_vector_type(8))) unsigned short u16x8;
typedef __attribute__((ext_vector_type(4))) float f32x4;

// ---------------------------------------------------------------------------
// Fused init: deg[i]=1 (self-loop slot 0) + W bf16 hi/lo split (independent).
__global__ __launch_bounds__(256) void init_split_kernel(
    int* __restrict__ deg, int N, const float* __restrict__ W,
    short* __restrict__ Wh, short* __restrict__ Wl, int n)
{
    int i = blockIdx.x * 256 + threadIdx.x;
    if (i < N) deg[i] = 1;
    if (i < n) {
        float f = W[i];
        unsigned short hi = f2bf(f);
        Wh[i] = (short)hi;
        Wl[i] = (short)f2bf(f - bf2f(hi));
    }
}

// slot[i] = old count (>=1 because self loop holds slot 0)
__global__ __launch_bounds__(256) void deg_count_slot_kernel(
    const int* __restrict__ dst, int* __restrict__ deg,
    int* __restrict__ slot, int E)
{
    int i = blockIdx.x * 256 + threadIdx.x;
    if (i < E) slot[i] = atomicAdd(&deg[dst[i]], 1);
}

#define SCAN_TILE 1024

__global__ __launch_bounds__(256) void scanA_kernel(
    const int* __restrict__ deg, int* __restrict__ bsum, int N)
{
    __shared__ int ws[4];
    int b = blockIdx.x, t = threadIdx.x;
    int base = b * SCAN_TILE + t * 4;
    int s = 0;
#pragma unroll
    for (int k = 0; k < 4; ++k) {
        int i = base + k;
        if (i < N) s += deg[i];
    }
#pragma unroll
    for (int m = 32; m >= 1; m >>= 1) s += __shfl_xor(s, m, 64);
    if ((t & 63) == 0) ws[t >> 6] = s;
    __syncthreads();
    if (t == 0) bsum[b] = ws[0] + ws[1] + ws[2] + ws[3];
}

__global__ __launch_bounds__(1024) void scanB_kernel(
    int* __restrict__ bsum, int* __restrict__ bpre, int* __restrict__ rowp,
    int NB, int N)
{
    __shared__ int sh[1024];
    int t = threadIdx.x;
    int v = (t < NB) ? bsum[t] : 0;
    sh[t] = v;
    __syncthreads();
    for (int off = 1; off < 1024; off <<= 1) {
        int u = (t >= off) ? sh[t - off] : 0;
        __syncthreads();
        sh[t] += u;
        __syncthreads();
    }
    if (t < NB) bpre[t] = sh[t] - v;          // exclusive prefix
    if (t == 1023) rowp[N] = sh[1023];        // total
}

// scanC also writes the self-loop entry: col[rowp[i]] = i (slot 0).
__global__ __launch_bounds__(256) void scanC_kernel(
    const int* __restrict__ deg, const int* __restrict__ bpre,
    int* __restrict__ rowp, int* __restrict__ col, int N)
{
    __shared__ int sh[256];
    int b = blockIdx.x, t = threadIdx.x;
    int base = b * SCAN_TILE + t * 4;
    int v[4];
#pragma unroll
    for (int k = 0; k < 4; ++k) {
        int i = base + k;
        v[k] = (i < N) ? deg[i] : 0;
    }
    int tsum = v[0] + v[1] + v[2] + v[3];
    sh[t] = tsum;
    __syncthreads();
    for (int off = 1; off < 256; off <<= 1) {
        int u = (t >= off) ? sh[t - off] : 0;
        __syncthreads();
        sh[t] += u;
        __syncthreads();
    }
    int pre = bpre[b] + sh[t] - tsum;
#pragma unroll
    for (int k = 0; k < 4; ++k) {
        int i = base + k;
        if (i < N) {
            rowp[i] = pre;
            col[pre] = i;   // self loop at slot 0
        }
        pre += v[k];
    }
}

// atomic-free scatter: position fully determined by rowp + recorded slot
__global__ __launch_bounds__(256) void scatter2_kernel(
    const int* __restrict__ src, const int* __restrict__ dst,
    const int* __restrict__ slot, const int* __restrict__ rowp,
    int* __restrict__ col, int E)
{
    int i = blockIdx.x * 256 + threadIdx.x;
    if (i < E) col[rowp[dst[i]] + slot[i]] = src[i];
}

// ---------------------------------------------------------------------------
// Layer-0 rank-1 precompute
__global__ __launch_bounds__(128) void rank1_prep_kernel(
    const float* __restrict__ lW, const float* __restrict__ lb,
    const float* __restrict__ W0, const float* __restrict__ al,
    const float* __restrict__ ar, float* __restrict__ c1,
    float* __restrict__ c2, float* __restrict__ prm)
{
    int j = threadIdx.x;
    float s1 = 0.f, s2 = 0.f;
    for (int d = 0; d < 128; ++d) {
        float wv = W0[j * 128 + d];
        s1 += lW[d] * wv;
        s2 += lb[d] * wv;
    }
    c1[j] = s1; c2[j] = s2;
    __shared__ float sh1[128], sh2[128], sh3[128], sh4[128];
    sh1[j] = s1 * al[j]; sh2[j] = s2 * al[j];
    sh3[j] = s1 * ar[j]; sh4[j] = s2 * ar[j];
    __syncthreads();
    if (j < 4) {
        float p = 0.f, q = 0.f, r = 0.f, s = 0.f;
        for (int f = 0; f < 32; ++f) {
            p += sh1[j * 32 + f]; q += sh2[j * 32 + f];
            r += sh3[j * 32 + f]; s += sh4[j * 32 + f];
        }
        prm[j] = p; prm[4 + j] = q; prm[8 + j] = r; prm[12 + j] = s;
    }
}

// h0 (bf16) = w[n]*c1[j] + c2[j]; el0/er0 from rank-1 params.
__global__ __launch_bounds__(256) void rank1_apply_kernel(
    const float* __restrict__ w, const float* __restrict__ c1,
    const float* __restrict__ c2, const float* __restrict__ prm,
    unsigned short* __restrict__ hb, float* __restrict__ el,
    float* __restrict__ er, int N)
{
    int i = blockIdx.x * 256 + threadIdx.x;
    int n = i >> 5, k = i & 31;
    if (n >= N) return;
    float wn = w[n];
    float4 a = *reinterpret_cast<const float4*>(&c1[k * 4]);
    float4 b = *reinterpret_cast<const float4*>(&c2[k * 4]);
    ushort4 o;
    o.x = f2bf(wn * a.x + b.x);
    o.y = f2bf(wn * a.y + b.y);
    o.z = f2bf(wn * a.z + b.z);
    o.w = f2bf(wn * a.w + b.w);
    *reinterpret_cast<ushort4*>(&hb[(size_t)n * 128 + k * 4]) = o;
    if (k == 0) {
        float4 pl = *reinterpret_cast<const float4*>(&prm[0]);
        float4 ql = *reinterpret_cast<const float4*>(&prm[4]);
        float4 pr = *reinterpret_cast<const float4*>(&prm[8]);
        float4 qr = *reinterpret_cast<const float4*>(&prm[12]);
        float4 e1 = make_float4(wn * pl.x + ql.x, wn * pl.y + ql.y,
                                wn * pl.z + ql.z, wn * pl.w + ql.w);
        float4 e2 = make_float4(wn * pr.x + qr.x, wn * pr.y + qr.y,
                                wn * pr.z + qr.z, wn * pr.w + qr.w);
        *reinterpret_cast<float4*>(&el[(size_t)n * 4]) = e1;
        *reinterpret_cast<float4*>(&er[(size_t)n * 4]) = e2;
    }
}

// ---------------------------------------------------------------------------
// MFMA bf16 GEMM (layers 1,2): h[n,j] = sum_d x_bf16[n,d]*W[j,d]
// x is PRE-ACTIVATED bf16 -> A fragment is a direct bf16x8 load.
// C = A*Wh + A*Wl. 32 rows/wave, W fragments hoisted (R12 fix).
__global__ __launch_bounds__(256) void gemm_mfma_kernel(
    const unsigned short* __restrict__ xb, const short* __restrict__ Wh,
    const short* __restrict__ Wl, unsigned short* __restrict__ hb, int N)
{
    const int lane = threadIdx.x & 63;
    const int wv   = threadIdx.x >> 6;
    const int m0   = blockIdx.x * 128 + wv * 32;  // 32 rows per wave
    const int mr   = lane & 15;
    const int quad = lane >> 4;

    int r0 = m0 + mr;      if (r0 > N - 1) r0 = N - 1;   // clamped load rows
    int r1 = m0 + 16 + mr; if (r1 > N - 1) r1 = N - 1;
    const unsigned short* xp0 = xb + (size_t)r0 * 128 + quad * 8;
    const unsigned short* xp1 = xb + (size_t)r1 * 128 + quad * 8;

    f32x4 acc0[8], acc1[8];
#pragma unroll
    for (int c = 0; c < 8; ++c) {
        acc0[c] = (f32x4){0.f, 0.f, 0.f, 0.f};
        acc1[c] = (f32x4){0.f, 0.f, 0.f, 0.f};
    }

#pragma unroll
    for (int kk = 0; kk < 4; ++kk) {
        bf16x8 a0 = *reinterpret_cast<const bf16x8*>(xp0 + kk * 32);
        bf16x8 a1 = *reinterpret_cast<const bf16x8*>(xp1 + kk * 32);

        const int kb = kk * 32 + quad * 8;
        bf16x8 bh[8], bl[8];
#pragma unroll
        for (int c = 0; c < 8; ++c) {
            const size_t wo = (size_t)(c * 16 + mr) * 128 + kb;
            bh[c] = *reinterpret_cast<const bf16x8*>(Wh + wo);
            bl[c] = *reinterpret_cast<const bf16x8*>(Wl + wo);
        }
#pragma unroll
        for (int c = 0; c < 8; ++c) {
            acc0[c] = __builtin_amdgcn_mfma_f32_16x16x32_bf16(a0, bh[c], acc0[c], 0, 0, 0);
            acc0[c] = __builtin_amdgcn_mfma_f32_16x16x32_bf16(a0, bl[c], acc0[c], 0, 0, 0);
            acc1[c] = __builtin_amdgcn_mfma_f32_16x16x32_bf16(a1, bh[c], acc1[c], 0, 0, 0);
            acc1[c] = __builtin_amdgcn_mfma_f32_16x16x32_bf16(a1, bl[c], acc1[c], 0, 0, 0);
        }
    }

#pragma unroll
    for (int i = 0; i < 4; ++i) {
        int rowA = m0 + quad * 4 + i;
        if (rowA < N) {
            unsigned short* hp = hb + (size_t)rowA * 128 + mr;
#pragma unroll
            for (int c = 0; c < 8; ++c) hp[c * 16] = f2bf(acc0[c][i]);
        }
        int rowB = m0 + 16 + quad * 4 + i;
        if (rowB < N) {
            unsigned short* hp = hb + (size_t)rowB * 128 + mr;
#pragma unroll
            for (int c = 0; c < 8; ++c) hp[c * 16] = f2bf(acc1[c][i]);
        }
    }
}

// ---------------------------------------------------------------------------
// el/er reduction (layers 1,2), bf16 h input. One wave per node.
__global__ __launch_bounds__(256) void elr_kernel(
    const unsigned short* __restrict__ hb, const float* __restrict__ al,
    const float* __restrict__ ar, float* __restrict__ el,
    float* __restrict__ er, int N)
{
    int node = blockIdx.x * 4 + (threadIdx.x >> 6);
    int lane = threadIdx.x & 63;
    if (node >= N) return;
    float v0 = bf2f(hb[(size_t)node * 128 + lane]);
    float v1 = bf2f(hb[(size_t)node * 128 + 64 + lane]);
    float sl0 = v0 * al[lane];
    float sl1 = v1 * al[64 + lane];
    float sr0 = v0 * ar[lane];
    float sr1 = v1 * ar[64 + lane];
#pragma unroll
    for (int m = 16; m >= 1; m >>= 1) {
        sl0 += __shfl_xor(sl0, m, 64);
        sl1 += __shfl_xor(sl1, m, 64);
        sr0 += __shfl_xor(sr0, m, 64);
        sr1 += __shfl_xor(sr1, m, 64);
    }
    if ((lane & 31) == 0) {
        int hb2 = lane >> 5;
        el[node * 4 + hb2]     = sl0;
        el[node * 4 + hb2 + 2] = sl1;
        er[node * 4 + hb2]     = sr0;
        er[node * 4 + hb2 + 2] = sr1;
    }
}

// ---------------------------------------------------------------------------
// SINGLE-PASS fused online-softmax aggregation + epilogue.
// FOUR nodes per wave; each 16-lane quarter owns one node.
// This round: (a) full software pipeline — col/el/hv for edge j+1 are loaded
// before the j compute, overlapping the ~200-cyc gather latency with exp/FMA;
// (b) BRANCHLESS online rescale (nm/sc/p always computed) — the old
// `if (e>m)` diverged between head-groups within a quarter, executing both
// paths anyway. exp(-inf)=0 handles the first edge.
__global__ __launch_bounds__(256) void agg_fused_kernel(
    const unsigned short* __restrict__ hb, const float* __restrict__ el,
    const float* __restrict__ er, const int* __restrict__ rowp,
    const int* __restrict__ col, const float* __restrict__ bias,
    unsigned short* __restrict__ xout, const float* __restrict__ pW,
    const float* __restrict__ pb, float* __restrict__ logits,
    int N, int last)
{
    const int lane = threadIdx.x & 63;
    const int q    = lane >> 4;
    const int l16  = lane & 15;
    const int v    = blockIdx.x * 16 + (threadIdx.x >> 6) * 4 + q;
    if (v >= N) return;   // reductions below stay within the 16-lane quarter

    const int r0 = rowp[v], r1 = rowp[v + 1];   // r1 > r0 (self loop)
    const int head = l16 >> 2;       // head for this lane's 8 features
    const int f0   = l16 * 8;        // feature base 0..120
    const float erq = er[(size_t)v * 4 + head];

    float m = -INFINITY, s = 0.f;
    float acc[8];
#pragma unroll
    for (int k = 0; k < 8; ++k) acc[k] = 0.f;

    // prime the pipeline with edge r0
    int   u_cur  = col[r0];
    float el_cur = el[(size_t)u_cur * 4 + head];
    u16x8 hv_cur = *reinterpret_cast<const u16x8*>(&hb[(size_t)u_cur * 128 + f0]);

    for (int j = r0; j < r1; ++j) {
        // issue next edge's loads before this edge's compute
        int jn = (j + 1 < r1) ? (j + 1) : j;
        int   u_nxt  = col[jn];
        float el_nxt = el[(size_t)u_nxt * 4 + head];
        u16x8 hv_nxt = *reinterpret_cast<const u16x8*>(&hb[(size_t)u_nxt * 128 + f0]);

        float e  = leaky02(el_cur + erq);
        float nm = fmaxf(m, e);
        float sc = __expf(m - nm);   // 0 on first edge (m=-inf)
        float p  = __expf(e - nm);
        s = s * sc + p;
#pragma unroll
        for (int k = 0; k < 8; ++k) acc[k] = acc[k] * sc + p * bf2f(hv_cur[k]);
        m = nm;

        u_cur = u_nxt; el_cur = el_nxt; hv_cur = hv_nxt;
    }
    const float is = 1.f / s;

    float4 b0 = *reinterpret_cast<const float4*>(&bias[f0]);
    float4 b1 = *reinterpret_cast<const float4*>(&bias[f0 + 4]);
    const float bb[8] = {b0.x, b0.y, b0.z, b0.w, b1.x, b1.y, b1.z, b1.w};

    if (last) {
        float4 p0 = *reinterpret_cast<const float4*>(&pW[f0]);
        float4 p1 = *reinterpret_cast<const float4*>(&pW[f0 + 4]);
        const float pp[8] = {p0.x, p0.y, p0.z, p0.w, p1.x, p1.y, p1.z, p1.w};
        float part = 0.f;
#pragma unroll
        for (int k = 0; k < 8; ++k) part += (acc[k] * is + bb[k]) * pp[k];
#pragma unroll
        for (int d = 1; d <= 8; d <<= 1) part += __shfl_xor(part, d, 64);
        if (l16 == 0) logits[v] = part + pb[0];
    } else {
        u16x8 o;
#pragma unroll
        for (int k = 0; k < 8; ++k) o[k] = f2bf(leaky01(acc[k] * is + bb[k]));
        *reinterpret_cast<u16x8*>(&xout[(size_t)v * 128 + f0]) = o;
    }
}

// ---------------------------------------------------------------------------
extern "C" void kernel_launch(void* const* d_in, const int* in_sizes, int n_in,
                              void* d_out, int out_size, void* d_ws, size_t ws_size,
                              hipStream_t stream)
{
    const float* weights = (const float*)d_in[0];
    const float* lin_W   = (const float*)d_in[1];
    const float* lin_b   = (const float*)d_in[2];
    const float* fc_W    = (const float*)d_in[3];
    const float* attn_l  = (const float*)d_in[4];
    const float* attn_r  = (const float*)d_in[5];
    const float* conv_b  = (const float*)d_in[6];
    const float* pred_W  = (const float*)d_in[7];
    const float* pred_b  = (const float*)d_in[8];
    const int*   src     = (const int*)d_in[9];
    const int*   dst     = (const int*)d_in[10];

    const int N = in_sizes[0];
    const int E = in_sizes[9];
    const int NB = (N + SCAN_TILE - 1) / SCAN_TILE;

    // workspace layout (16B-aligned sections)
    unsigned short* xb = (unsigned short*)d_ws;                    // N*128 bf16 (pre-activated)
    unsigned short* hb = xb + (size_t)N * 128;                     // N*128 bf16
    float* el  = (float*)(hb + (size_t)N * 128);                   // N*4
    float* er  = el + (size_t)N * 4;                               // N*4
    float* c1  = er + (size_t)N * 4;                               // 128
    float* c2  = c1 + 128;                                         // 128
    float* prm = c2 + 128;                                         // 16
    short* Whs = (short*)(prm + 16);                               // 2*16384 bf16
    short* Wls = Whs + 2 * 16384;                                  // 2*16384 bf16
    int*   deg  = (int*)(Wls + 2 * 16384);                         // N
    int*   rowp = deg + N;                                         // N+1
    int*   slot = rowp + (N + 1);                                  // E
    int*   col  = slot + E;                                        // E+N
    int*   bsum = col + (E + N);                                   // NB
    int*   bpre = bsum + NB;                                       // NB

    // CSR build + W split (fresh every call: ws is re-poisoned)
    init_split_kernel<<<(N + 255) / 256, 256, 0, stream>>>(
        deg, N, fc_W + 16384, Whs, Wls, 2 * 16384);
    deg_count_slot_kernel<<<(E + 255) / 256, 256, 0, stream>>>(dst, deg, slot, E);
    scanA_kernel<<<NB, 256, 0, stream>>>(deg, bsum, N);
    scanB_kernel<<<1, 1024, 0, stream>>>(bsum, bpre, rowp, NB, N);
    scanC_kernel<<<NB, 256, 0, stream>>>(deg, bpre, rowp, col, N);
    scatter2_kernel<<<(E + 255) / 256, 256, 0, stream>>>(src, dst, slot, rowp, col, E);

    // Layer 0 via rank-1 identity
    rank1_prep_kernel<<<1, 128, 0, stream>>>(lin_W, lin_b, fc_W, attn_l, attn_r,
                                             c1, c2, prm);
    rank1_apply_kernel<<<((size_t)N * 32 + 255) / 256, 256, 0, stream>>>(
        weights, c1, c2, prm, hb, el, er, N);
    agg_fused_kernel<<<(N + 15) / 16, 256, 0, stream>>>(
        hb, el, er, rowp, col, conv_b, xb, pred_W, pred_b, (float*)d_out, N, 0);

    // Layers 1, 2 (MFMA bf16 gemm on pre-activated bf16 x)
    for (int l = 1; l < 3; ++l) {
        gemm_mfma_kernel<<<(N + 127) / 128, 256, 0, stream>>>(
            xb, Whs + (size_t)(l - 1) * 16384, Wls + (size_t)(l - 1) * 16384, hb, N);
        elr_kernel<<<(N + 3) / 4, 256, 0, stream>>>(
            hb, attn_l + l * 128, attn_r + l * 128, el, er, N);
        agg_fused_kernel<<<(N + 15) / 16, 256, 0, stream>>>(
            hb, el, er, rowp, col, conv_b + l * 128, xb, pred_W, pred_b,
            (float*)d_out, N, l == 2 ? 1 : 0);
    }
}